// Round 4
// baseline (1828.041 us; speedup 1.0000x reference)
//
#include <hip/hip_runtime.h>
#include <math.h>

#define NN 50000
#define NE 400000
#define NG 512
#define EPS 1e-5f
#define NSLOT 256  // stats replica slots (atomic contention spreading)

typedef unsigned int u32;
typedef unsigned short u16;

__device__ __forceinline__ float b2f(u16 h) { return __uint_as_float(((u32)h) << 16); }
__device__ __forceinline__ u16 f2b(float f) {
    u32 x = __float_as_uint(f);
    u32 r = x + 0x7fffu + ((x >> 16) & 1u);
    return (u16)(r >> 16);
}
struct alignas(16) U16x8 { u16 s[8]; };
struct alignas(8) U16x4 { u16 s[4]; };
struct alignas(4) U16x2 { u16 s[2]; };

__device__ __forceinline__ u32 fenc(float f) {
    u32 u = __float_as_uint(f);
    return (u & 0x80000000u) ? ~u : (u | 0x80000000u);
}
__device__ __forceinline__ float fdec(u32 e) {
    u32 u = (e & 0x80000000u) ? (e ^ 0x80000000u) : ~e;
    return __uint_as_float(u);
}
__device__ __forceinline__ void f4add(float4& a, const float4 b) {
    a.x += b.x; a.y += b.y; a.z += b.z; a.w += b.w;
}

// ---------------- setup: fold rotation matrices into ee_W1 (fp32) ----------------
__global__ void setup_kernel(const float* __restrict__ ang_rot, const float* __restrict__ ang_ref,
                             const float* __restrict__ W1, float* __restrict__ RWrot,
                             float* __restrict__ RWref) {
    int c = threadIdx.x;  // 64
    for (int which = 0; which < 2; ++which) {
        const float* a = which ? ang_ref : ang_rot;
        float t = a[0], p = a[1], q = a[2];
        float ct = cosf(t), st = sinf(t);
        float cp = cosf(p), sp = sinf(p);
        float cq = cosf(q), sq = sinf(q);
        float Rt[3][3] = {{ct, -st, 0.f}, {st, ct, 0.f}, {0.f, 0.f, 1.f}};
        float Rp[3][3] = {{cp, 0.f, -sp}, {0.f, 1.f, 0.f}, {sp, 0.f, cp}};
        float Rq[3][3] = {{1.f, 0.f, 0.f}, {0.f, cq, -sq}, {0.f, sq, cq}};
        float Rtp[3][3], R[3][3];
        for (int i = 0; i < 3; ++i)
            for (int j = 0; j < 3; ++j) {
                float s = 0.f;
                for (int k = 0; k < 3; ++k) s += Rt[i][k] * Rp[k][j];
                Rtp[i][j] = s;
            }
        for (int i = 0; i < 3; ++i)
            for (int j = 0; j < 3; ++j) {
                float s = 0.f;
                for (int k = 0; k < 3; ++k) s += Rtp[i][k] * Rq[k][j];
                R[i][j] = s;
            }
        float sgn = which ? -1.f : 1.f;  // R_ref = -rotmat(angles_ref)
        float* RW = which ? RWref : RWrot;
        if (c < 64) {
            for (int j = 0; j < 3; ++j) {
                float s = 0.f;
                for (int m = 0; m < 3; ++m) s += sgn * R[j][m] * W1[m * 64 + c];
                RW[j * 64 + c] = s;  // RW = R @ W1  (3 x 64)
            }
        }
    }
}

// ---------------- embedding gather: fp32 table -> bf16 out ----------------
__global__ __launch_bounds__(256) void gather_emb_kernel(const int* __restrict__ ntype,
                                                         const float* __restrict__ emb,
                                                         u16* __restrict__ out, int n) {
    long i = (long)blockIdx.x * 256 + threadIdx.x;  // over n*8
    long e = i >> 3;
    if (e >= n) return;
    int c0 = (int)(i & 7) * 8;
    int t = ntype[e];
    float4 a = *(const float4*)&emb[(long)t * 64 + c0];
    float4 b = *(const float4*)&emb[(long)t * 64 + c0 + 4];
    U16x8 o;
    o.s[0] = f2b(a.x); o.s[1] = f2b(a.y); o.s[2] = f2b(a.z); o.s[3] = f2b(a.w);
    o.s[4] = f2b(b.x); o.s[5] = f2b(b.y); o.s[6] = f2b(b.z); o.s[7] = f2b(b.w);
    *(U16x8*)&out[e * 64 + c0] = o;
}

// ---------------- efeats second moments: 9 scalars -> replica slots ----------------
__global__ __launch_bounds__(256) void efstats_kernel(const float* __restrict__ ef, int E,
                                                      float* __restrict__ raw) {
    int tid = threadIdx.x;
    float a[9];
#pragma unroll
    for (int j = 0; j < 9; ++j) a[j] = 0.f;
    for (long e = (long)blockIdx.x * 256 + tid; e < E; e += (long)gridDim.x * 256) {
        float f0 = ef[e * 3 + 0], f1 = ef[e * 3 + 1], f2 = ef[e * 3 + 2];
        a[0] += f0; a[1] += f1; a[2] += f2;
        a[3] += f0 * f0; a[4] += f1 * f1; a[5] += f2 * f2;
        a[6] += f0 * f1; a[7] += f0 * f2; a[8] += f1 * f2;
    }
#pragma unroll
    for (int off = 1; off < 64; off <<= 1)
#pragma unroll
        for (int j = 0; j < 9; ++j) a[j] += __shfl_xor(a[j], off, 64);
    __shared__ float sred[4][9];
    int wv = tid >> 6, ln = tid & 63;
    if (ln == 0)
#pragma unroll
        for (int j = 0; j < 9; ++j) sred[wv][j] = a[j];
    __syncthreads();
    if (tid < 9) {
        float v = sred[0][tid] + sred[1][tid] + sred[2][tid] + sred[3][tid];
        atomicAdd(&raw[(size_t)(blockIdx.x & (NSLOT - 1)) * 16 + tid], v);
    }
}

// ---------------- analytic T1 column stats for both branches ----------------
// T1 = ef@RW + b1;  sum_c = m.w_c + E*b_c;  ss_c = w'Mw + 2b(m.w) + E b^2
__global__ void ee_stats_kernel(const float* __restrict__ efraw, const float* __restrict__ RWrot,
                                const float* __restrict__ RWref, const float* __restrict__ b1,
                                float* __restrict__ S_rot, float* __restrict__ S_ref, int E) {
    __shared__ float m[9];
    int t = threadIdx.x;  // 128
    if (t < 9) {
        float s = 0.f;
        for (int r = 0; r < NSLOT; ++r) s += efraw[r * 16 + t];
        m[t] = s;
    }
    __syncthreads();
    int br = t >> 6, c = t & 63;
    const float* RW = br ? RWref : RWrot;
    float* S = br ? S_ref : S_rot;
    float w0 = RW[c], w1 = RW[64 + c], w2 = RW[128 + c];
    float bb = b1[c];
    float mw = m[0] * w0 + m[1] * w1 + m[2] * w2;
    float sum = mw + (float)E * bb;
    float quad = m[3] * w0 * w0 + m[4] * w1 * w1 + m[5] * w2 * w2 +
                 2.f * (m[6] * w0 * w1 + m[7] * w0 * w2 + m[8] * w1 * w2);
    float ss = quad + 2.f * bb * mw + (float)E * bb * bb;
    S[c] = sum;
    S[64 + c] = ss;
}

// ---------------- column stats -> replicated raw accumulators ----------------
template <int COLS, bool XBF>
__global__ __launch_bounds__(256) void colstats_kernel(const void* __restrict__ xv, int rows,
                                                       float* __restrict__ raw) {
    constexpr int TPR = COLS / 8;
    constexpr int RPB = 256 / TPR;
    __shared__ float4 sA[256], sB[256], sC[256], sD[256];
    int tid = threadIdx.x;
    int c8 = tid % TPR;
    int rl = tid / TPR;
    float s[8], q[8];
#pragma unroll
    for (int j = 0; j < 8; ++j) { s[j] = 0.f; q[j] = 0.f; }
    const long stride = (long)gridDim.x * RPB;
    long r = (long)blockIdx.x * RPB + rl;
    auto loadrow = [&](long rr, float* v) {
        if (XBF) {
            U16x8 t = *(const U16x8*)((const u16*)xv + rr * COLS + c8 * 8);
#pragma unroll
            for (int j = 0; j < 8; ++j) v[j] = b2f(t.s[j]);
        } else {
            float4 a = *(const float4*)((const float*)xv + rr * COLS + c8 * 8);
            float4 b = *(const float4*)((const float*)xv + rr * COLS + c8 * 8 + 4);
            v[0] = a.x; v[1] = a.y; v[2] = a.z; v[3] = a.w;
            v[4] = b.x; v[5] = b.y; v[6] = b.z; v[7] = b.w;
        }
    };
    for (; r + stride < rows; r += 2 * stride) {
        float v0[8], v1[8];
        loadrow(r, v0);
        loadrow(r + stride, v1);
#pragma unroll
        for (int j = 0; j < 8; ++j) {
            s[j] += v0[j] + v1[j];
            q[j] += v0[j] * v0[j] + v1[j] * v1[j];
        }
    }
    if (r < rows) {
        float v0[8];
        loadrow(r, v0);
#pragma unroll
        for (int j = 0; j < 8; ++j) { s[j] += v0[j]; q[j] += v0[j] * v0[j]; }
    }
    sA[tid] = make_float4(s[0], s[1], s[2], s[3]);
    sB[tid] = make_float4(s[4], s[5], s[6], s[7]);
    sC[tid] = make_float4(q[0], q[1], q[2], q[3]);
    sD[tid] = make_float4(q[4], q[5], q[6], q[7]);
    __syncthreads();
    for (int off = 128; off >= TPR; off >>= 1) {
        if (tid < off) {
            f4add(sA[tid], sA[tid + off]); f4add(sB[tid], sB[tid + off]);
            f4add(sC[tid], sC[tid + off]); f4add(sD[tid], sD[tid + off]);
        }
        __syncthreads();
    }
    if (tid < TPR) {
        float* slot = raw + (size_t)(blockIdx.x & (NSLOT - 1)) * 256;
        int c = tid * 8;
        float4 a = sA[tid], b = sB[tid], cq = sC[tid], d = sD[tid];
        atomicAdd(&slot[c + 0], a.x); atomicAdd(&slot[c + 1], a.y);
        atomicAdd(&slot[c + 2], a.z); atomicAdd(&slot[c + 3], a.w);
        atomicAdd(&slot[c + 4], b.x); atomicAdd(&slot[c + 5], b.y);
        atomicAdd(&slot[c + 6], b.z); atomicAdd(&slot[c + 7], b.w);
        atomicAdd(&slot[COLS + c + 0], cq.x); atomicAdd(&slot[COLS + c + 1], cq.y);
        atomicAdd(&slot[COLS + c + 2], cq.z); atomicAdd(&slot[COLS + c + 3], cq.w);
        atomicAdd(&slot[COLS + c + 4], d.x); atomicAdd(&slot[COLS + c + 5], d.y);
        atomicAdd(&slot[COLS + c + 6], d.z); atomicAdd(&slot[COLS + c + 7], d.w);
    }
}

// ---------------- reduce NSLOT replica slots -> final stats ----------------
__global__ __launch_bounds__(256) void finalize_stats_kernel(const float* __restrict__ raw,
                                                             float* __restrict__ stats, int n) {
    int i = threadIdx.x;
    if (i >= n) return;
    float s = 0.f;
    for (int r = 0; r < NSLOT; ++r) s += raw[r * 256 + i];
    stats[i] = s;
}

// ---------------- elementwise y = relu(bn(x)) [+= y], bf16 x/y ----------------
__global__ __launch_bounds__(256) void bn_act_kernel(const u16* __restrict__ x,
                                                     u16* __restrict__ y, long rows, int cols,
                                                     const float* __restrict__ acc,
                                                     const float* __restrict__ g,
                                                     const float* __restrict__ b, float inv_rows,
                                                     int accumulate) {
    long i = (long)blockIdx.x * 256 + threadIdx.x;
    long total8 = rows * (long)cols / 8;
    if (i >= total8) return;
    long base = i * 8;
    int c0 = (int)(base % cols);
    U16x8 xv = *(const U16x8*)&x[base];
    float r[8];
#pragma unroll
    for (int j = 0; j < 8; ++j) {
        int c = c0 + j;
        float mu = acc[c] * inv_rows;
        float var = acc[cols + c] * inv_rows - mu * mu;
        float al = g[c] * rsqrtf(fmaxf(var, 0.f) + EPS);
        float be = b[c] - mu * al;
        float o = al * b2f(xv.s[j]) + be;
        r[j] = fmaxf(o, 0.f);
    }
    if (accumulate) {
        U16x8 yv = *(const U16x8*)&y[base];
#pragma unroll
        for (int j = 0; j < 8; ++j) r[j] += b2f(yv.s[j]);
    }
    U16x8 o;
#pragma unroll
    for (int j = 0; j < 8; ++j) o.s[j] = f2b(r[j]);
    *(U16x8*)&y[base] = o;
}

// ---------------- generic tiled matmul: Y = preop(X) @ W (+bias)(+res) ----------------
// preop: 0 none, 1 bn, 2 bn+relu, 3 bn+prelu(scalar)
// XBF/RBF/OBF: bf16 flags; SOUT: emit col sum/sumsq of Y into raw slots
template <int K, int COLS, bool XBF, bool RBF, bool OBF, bool SOUT>
__global__ __launch_bounds__(256) void mm_kernel(const void* __restrict__ Xv,
                                                 const float* __restrict__ Wg,
                                                 const float* __restrict__ bias, const void* resv,
                                                 void* Yv, int rows, int preop,
                                                 const float* __restrict__ stats,
                                                 const float* __restrict__ g,
                                                 const float* __restrict__ b, float inv_rows,
                                                 const float* __restrict__ prelu, int prelu_idx,
                                                 float* __restrict__ raw) {
    constexpr int TPR = COLS / 4;
    constexpr int RPB = 256 / TPR;
    constexpr int XP = K + 4;
    __shared__ float ws[K * COLS];
    __shared__ float xs[RPB * XP];
    __shared__ float al[K];
    __shared__ float be[K];
    const int tid = threadIdx.x;

    for (int i = tid; i < K * COLS; i += 256) ws[i] = Wg[i];
    if (preop) {
        for (int k = tid; k < K; k += 256) {
            float mu = stats[k] * inv_rows;
            float var = stats[K + k] * inv_rows - mu * mu;
            float a = g[k] * rsqrtf(fmaxf(var, 0.f) + EPS);
            al[k] = a;
            be[k] = b[k] - mu * a;
        }
    }
    __syncthreads();

    const long r0 = (long)blockIdx.x * RPB;
    float pa = (preop == 3) ? prelu[prelu_idx] : 0.f;
    constexpr int NC = RPB * K / 4;
    for (int i = tid; i < NC; i += 256) {
        int b4 = i * 4;
        int rl = b4 / K, k0 = b4 % K;
        long r = r0 + rl;
        float v[4];
        if (r < rows) {
            if (XBF) {
                U16x4 t = *(const U16x4*)((const u16*)Xv + r * K + k0);
#pragma unroll
                for (int j = 0; j < 4; ++j) v[j] = b2f(t.s[j]);
            } else {
                float4 t = *(const float4*)((const float*)Xv + r * K + k0);
                v[0] = t.x; v[1] = t.y; v[2] = t.z; v[3] = t.w;
            }
        } else {
#pragma unroll
            for (int j = 0; j < 4; ++j) v[j] = 0.f;
        }
        if (preop) {
#pragma unroll
            for (int j = 0; j < 4; ++j) {
                float xx = al[k0 + j] * v[j] + be[k0 + j];
                if (preop == 2) xx = fmaxf(xx, 0.f);
                else if (preop == 3) xx = (xx >= 0.f) ? xx : pa * xx;
                v[j] = xx;
            }
        }
        xs[rl * XP + k0 + 0] = v[0];
        xs[rl * XP + k0 + 1] = v[1];
        xs[rl * XP + k0 + 2] = v[2];
        xs[rl * XP + k0 + 3] = v[3];
    }
    __syncthreads();

    const int rl = tid / TPR;
    const int c0 = (tid % TPR) * 4;
    float4 acc = {0.f, 0.f, 0.f, 0.f};
#pragma unroll
    for (int k = 0; k < K; k += 4) {
        float4 xv = *(const float4*)&xs[rl * XP + k];
#pragma unroll
        for (int j = 0; j < 4; ++j) {
            float xj = (&xv.x)[j];
            float4 wv = *(const float4*)&ws[(k + j) * COLS + c0];
            acc.x += xj * wv.x; acc.y += xj * wv.y;
            acc.z += xj * wv.z; acc.w += xj * wv.w;
        }
    }
    long r = r0 + rl;
    if (r < rows) {
        if (bias) f4add(acc, *(const float4*)&bias[c0]);
        if (resv) {
            if (RBF) {
                U16x4 t = *(const U16x4*)((const u16*)resv + r * COLS + c0);
                acc.x += b2f(t.s[0]); acc.y += b2f(t.s[1]);
                acc.z += b2f(t.s[2]); acc.w += b2f(t.s[3]);
            } else {
                f4add(acc, *(const float4*)((const float*)resv + r * COLS + c0));
            }
        }
        if (OBF) {
            U16x4 o;
            o.s[0] = f2b(acc.x); o.s[1] = f2b(acc.y);
            o.s[2] = f2b(acc.z); o.s[3] = f2b(acc.w);
            *(U16x4*)((u16*)Yv + r * COLS + c0) = o;
        } else {
            *(float4*)((float*)Yv + r * COLS + c0) = acc;
        }
    }
    if constexpr (SOUT) {
        __syncthreads();
        float4 va = (r < rows) ? acc : make_float4(0.f, 0.f, 0.f, 0.f);
        *(float4*)&ws[rl * COLS + c0] = va;
        float4 vq = make_float4(va.x * va.x, va.y * va.y, va.z * va.z, va.w * va.w);
        *(float4*)&ws[RPB * COLS + rl * COLS + c0] = vq;
        __syncthreads();
        for (int off2 = RPB / 2; off2 >= 1; off2 >>= 1) {
            if (rl < off2) {
                float4 x1 = *(float4*)&ws[rl * COLS + c0];
                f4add(x1, *(const float4*)&ws[(rl + off2) * COLS + c0]);
                *(float4*)&ws[rl * COLS + c0] = x1;
                float4 x2 = *(float4*)&ws[RPB * COLS + rl * COLS + c0];
                f4add(x2, *(const float4*)&ws[RPB * COLS + (rl + off2) * COLS + c0]);
                *(float4*)&ws[RPB * COLS + rl * COLS + c0] = x2;
            }
            __syncthreads();
        }
        if (rl == 0) {
            float* slot = raw + (size_t)(blockIdx.x & (NSLOT - 1)) * 256;
#pragma unroll
            for (int j = 0; j < 4; ++j) {
                atomicAdd(&slot[c0 + j], ws[c0 + j]);
                atomicAdd(&slot[COLS + c0 + j], ws[RPB * COLS + c0 + j]);
            }
        }
    }
}

// ---------------- edge-encoder mm: T2 = relu(bn1(ef@RW + b1)) @ W2 + b2, fused ----------------
__global__ __launch_bounds__(256) void ee_mm_kernel(
    const float* __restrict__ ef, const float* __restrict__ RW, const float* __restrict__ b1v,
    const float* __restrict__ W2, const float* __restrict__ b2, u16* __restrict__ T2, int E,
    const float* __restrict__ stats, const float* __restrict__ g, const float* __restrict__ b,
    float inv_rows, float* __restrict__ raw) {
    constexpr int K = 64, COLS = 64, TPR = 16, RPB = 16, XP = 68;
    __shared__ float ws[K * COLS];
    __shared__ float xs[RPB * XP];
    __shared__ float rws[192];
    __shared__ float efs[RPB * 3];
    __shared__ float al[K];
    __shared__ float be[K];
    const int tid = threadIdx.x;
    const long r0 = (long)blockIdx.x * RPB;

    for (int i = tid; i < K * COLS; i += 256) ws[i] = W2[i];
    if (tid < 192) rws[tid] = RW[tid];
    {
        long lim = ((long)E - r0) * 3;
        if (lim > RPB * 3) lim = RPB * 3;
        if (tid < RPB * 3) efs[tid] = (tid < lim) ? ef[r0 * 3 + tid] : 0.f;
    }
    for (int k = tid; k < K; k += 256) {
        float mu = stats[k] * inv_rows;
        float var = stats[K + k] * inv_rows - mu * mu;
        float a = g[k] * rsqrtf(fmaxf(var, 0.f) + EPS);
        al[k] = a;
        be[k] = b[k] - mu * a + a * b1v[k];  // fold b1 into affine
    }
    __syncthreads();
    for (int i = tid; i < RPB * K; i += 256) {
        int rl2 = i >> 6, k = i & 63;
        float t = efs[rl2 * 3 + 0] * rws[k] + efs[rl2 * 3 + 1] * rws[64 + k] +
                  efs[rl2 * 3 + 2] * rws[128 + k];
        float xx = al[k] * t + be[k];
        xs[rl2 * XP + k] = fmaxf(xx, 0.f);
    }
    __syncthreads();

    const int rl = tid / TPR;
    const int c0 = (tid % TPR) * 4;
    float4 acc = {0.f, 0.f, 0.f, 0.f};
#pragma unroll
    for (int k = 0; k < K; k += 4) {
        float4 xv = *(const float4*)&xs[rl * XP + k];
#pragma unroll
        for (int j = 0; j < 4; ++j) {
            float xj = (&xv.x)[j];
            float4 wv = *(const float4*)&ws[(k + j) * COLS + c0];
            acc.x += xj * wv.x; acc.y += xj * wv.y;
            acc.z += xj * wv.z; acc.w += xj * wv.w;
        }
    }
    long r = r0 + rl;
    if (r < E) {
        f4add(acc, *(const float4*)&b2[c0]);
        U16x4 o;
        o.s[0] = f2b(acc.x); o.s[1] = f2b(acc.y);
        o.s[2] = f2b(acc.z); o.s[3] = f2b(acc.w);
        *(U16x4*)&T2[r * COLS + c0] = o;
    }
    // fused col-stats of T2
    __syncthreads();
    float4 va = (r < E) ? acc : make_float4(0.f, 0.f, 0.f, 0.f);
    *(float4*)&ws[rl * COLS + c0] = va;
    float4 vq = make_float4(va.x * va.x, va.y * va.y, va.z * va.z, va.w * va.w);
    *(float4*)&ws[RPB * COLS + rl * COLS + c0] = vq;
    __syncthreads();
    for (int off2 = RPB / 2; off2 >= 1; off2 >>= 1) {
        if (rl < off2) {
            float4 x1 = *(float4*)&ws[rl * COLS + c0];
            f4add(x1, *(const float4*)&ws[(rl + off2) * COLS + c0]);
            *(float4*)&ws[rl * COLS + c0] = x1;
            float4 x2 = *(float4*)&ws[RPB * COLS + rl * COLS + c0];
            f4add(x2, *(const float4*)&ws[RPB * COLS + (rl + off2) * COLS + c0]);
            *(float4*)&ws[RPB * COLS + rl * COLS + c0] = x2;
        }
        __syncthreads();
    }
    if (rl == 0) {
        float* slot = raw + (size_t)(blockIdx.x & (NSLOT - 1)) * 256;
#pragma unroll
        for (int j = 0; j < 4; ++j) {
            atomicAdd(&slot[c0 + j], ws[c0 + j]);
            atomicAdd(&slot[COLS + c0 + j], ws[RPB * COLS + c0 + j]);
        }
    }
}

// ---------------- EGAT: f = leaky(eh@Wfij + ni[src] + nj[dst]); e_att; segment max ----------------
// split-column mapping: thread owns cols {c4..c4+3} and {HW+c4..HW+c4+3} -> conflict-free LDS
template <int COLS, bool WRITE_F>
__global__ __launch_bounds__(256) void egat_fe_kernel(
    const u16* __restrict__ EH, const float* __restrict__ Wg, const u16* __restrict__ NI,
    const u16* __restrict__ NJ, const int* __restrict__ src, const int* __restrict__ dst,
    const float* __restrict__ attn, u16* __restrict__ Fout, float* __restrict__ eatt,
    u32* __restrict__ emax, int E) {
    constexpr int H = COLS / 64;
    constexpr int TPR = COLS / 8;
    constexpr int RPB = 256 / TPR;
    constexpr int HW = COLS / 2;
    constexpr int XP = 68;
    __shared__ float ws[64 * COLS];
    __shared__ float xs[RPB * XP];
    const int tid = threadIdx.x;
    const int rl = tid / TPR;
    const int c4 = (tid % TPR) * 4;
    const long r0 = (long)blockIdx.x * RPB;
    const long e = r0 + rl;
    // prefetch edge meta + gathers (overlap with LDS staging + matmul)
    int d = 0;
    U16x4 ni0 = {}, ni1 = {}, nj0 = {}, nj1 = {};
    if (e < E) {
        int s = src[e];
        d = dst[e];
        ni0 = *(const U16x4*)&NI[(long)s * COLS + c4];
        ni1 = *(const U16x4*)&NI[(long)s * COLS + HW + c4];
        nj0 = *(const U16x4*)&NJ[(long)d * COLS + c4];
        nj1 = *(const U16x4*)&NJ[(long)d * COLS + HW + c4];
    }
    float4 av0 = *(const float4*)&attn[c4];
    float4 av1 = *(const float4*)&attn[HW + c4];
    for (int i = tid; i < 64 * COLS; i += 256) ws[i] = Wg[i];
    for (int i = tid; i < RPB * 8; i += 256) {
        int rr = i / 8, k0 = (i % 8) * 8;
        long r = r0 + rr;
        if (r < E) {
            U16x8 t = *(const U16x8*)&EH[r * 64 + k0];
#pragma unroll
            for (int j = 0; j < 8; ++j) xs[rr * XP + k0 + j] = b2f(t.s[j]);
        } else {
#pragma unroll
            for (int j = 0; j < 8; ++j) xs[rr * XP + k0 + j] = 0.f;
        }
    }
    __syncthreads();
    float acc0[4] = {0.f, 0.f, 0.f, 0.f};
    float acc1[4] = {0.f, 0.f, 0.f, 0.f};
    for (int k = 0; k < 64; k += 4) {
        float4 xv = *(const float4*)&xs[rl * XP + k];
#pragma unroll
        for (int kk = 0; kk < 4; ++kk) {
            float xj = (&xv.x)[kk];
            float4 w0 = *(const float4*)&ws[(k + kk) * COLS + c4];
            float4 w1 = *(const float4*)&ws[(k + kk) * COLS + HW + c4];
            acc0[0] += xj * w0.x; acc0[1] += xj * w0.y;
            acc0[2] += xj * w0.z; acc0[3] += xj * w0.w;
            acc1[0] += xj * w1.x; acc1[1] += xj * w1.y;
            acc1[2] += xj * w1.z; acc1[3] += xj * w1.w;
        }
    }
    float part0 = 0.f, part1 = 0.f;
    if (e < E) {
        U16x4 fo0, fo1;
#pragma unroll
        for (int j = 0; j < 4; ++j) {
            float f0 = acc0[j] + b2f(ni0.s[j]) + b2f(nj0.s[j]);
            float f1 = acc1[j] + b2f(ni1.s[j]) + b2f(nj1.s[j]);
            f0 = (f0 >= 0.f) ? f0 : 0.01f * f0;
            f1 = (f1 >= 0.f) ? f1 : 0.01f * f1;
            fo0.s[j] = f2b(f0);
            fo1.s[j] = f2b(f1);
            part0 += f0 * (&av0.x)[j];
            part1 += f1 * (&av1.x)[j];
        }
        if (WRITE_F) {
            *(U16x4*)&Fout[e * COLS + c4] = fo0;
            *(U16x4*)&Fout[e * COLS + HW + c4] = fo1;
        }
    }
#pragma unroll
    for (int off = 1; off < TPR; off <<= 1) {
        part0 += __shfl_xor(part0, off, 64);
        part1 += __shfl_xor(part1, off, 64);
    }
    if (e < E && (tid % TPR) == 0) {
        if (H == 2) {
            eatt[e * 2 + 0] = part0;
            eatt[e * 2 + 1] = part1;
            atomicMax(&emax[(long)d * 2 + 0], fenc(part0));
            atomicMax(&emax[(long)d * 2 + 1], fenc(part1));
        } else {
            float p = part0 + part1;
            eatt[e] = p;
            atomicMax(&emax[d], fenc(p));
        }
    }
}

// ---------------- softmax numerator + denominator ----------------
__global__ __launch_bounds__(256) void edge_softmax_kernel(float* __restrict__ eatt,
                                                           const int* __restrict__ dst,
                                                           const u32* __restrict__ emax,
                                                           float* __restrict__ denom, long total,
                                                           int H) {
    long i = (long)blockIdx.x * 256 + threadIdx.x;
    if (i >= total) return;
    long e = i / H;
    int h = (int)(i - e * H);
    long idx = (long)dst[e] * H + h;
    float m = fdec(emax[idx]);
    float v = expf(eatt[i] - m);
    eatt[i] = v;
    atomicAdd(&denom[idx], v);
}

// ---------------- weighted segment-sum scatter ----------------
template <int COLS>
__global__ __launch_bounds__(256) void egat_scatter_kernel(
    const u16* __restrict__ nodeh, const float* __restrict__ ee, const float* __restrict__ denom,
    const int* __restrict__ src, const int* __restrict__ dst, float* __restrict__ hout, int E) {
    constexpr int TPE = COLS / 2;
    constexpr int RPB = 256 / TPE;
    constexpr int H = COLS / 64;
    int tid = threadIdx.x;
    long e = (long)blockIdx.x * RPB + tid / TPE;
    if (e >= E) return;
    int c = (tid % TPE) * 2;
    int d = dst[e];
    int h = c >> 6;
    float a = ee[e * H + h] / denom[(long)d * H + h];
    U16x2 v = *(const U16x2*)&nodeh[(long)src[e] * COLS + c];
    atomicAdd(&hout[(long)d * COLS + c + 0], b2f(v.s[0]) * a);
    atomicAdd(&hout[(long)d * COLS + c + 1], b2f(v.s[1]) * a);
}

// ---------------- decoder tail: prelu(bn(t3)) @ Wout + bout -> pool by graph ----------------
__global__ __launch_bounds__(256) void decoder_out_kernel(
    const u16* __restrict__ t3, const float* __restrict__ stats, const float* __restrict__ g,
    const float* __restrict__ b, const float* __restrict__ prelu, const float* __restrict__ Wout,
    const float* __restrict__ bout, const int* __restrict__ gid, float* __restrict__ pool,
    int rows, float inv_rows) {
    int tid = threadIdx.x;
    long r = (long)blockIdx.x * 4 + (tid >> 6);
    if (r >= rows) return;
    int k = tid & 63;
    float mu = stats[k] * inv_rows;
    float var = stats[64 + k] * inv_rows - mu * mu;
    float al = g[k] * rsqrtf(fmaxf(var, 0.f) + EPS);
    float be = b[k] - mu * al;
    float a = prelu[3];
    float v = al * b2f(t3[r * 64 + k]) + be;
    v = (v >= 0.f) ? v : a * v;
    v *= Wout[k];
#pragma unroll
    for (int off = 1; off < 64; off <<= 1) v += __shfl_xor(v, off, 64);
    if (k == 0) atomicAdd(&pool[gid[r]], v + bout[0]);
}

// =====================================================================================
extern "C" void kernel_launch(void* const* d_in, const int* in_sizes, int n_in, void* d_out,
                              int out_size, void* d_ws, size_t ws_size, hipStream_t stream) {
    if (n_in < 57) return;
    const int* ntype = (const int*)d_in[0];
    const int* src = (const int*)d_in[1];
    const int* dst = (const int*)d_in[2];
    const int* gid = (const int*)d_in[3];
    const float* ang_rot = (const float*)d_in[4];
    const float* ang_ref = (const float*)d_in[5];
    const float* efeats = (const float*)d_in[6];
    const float* emb = (const float*)d_in[7];
    const float* enc_W = (const float*)d_in[8];
    const float* enc_b = (const float*)d_in[9];
    const float* ee_W1 = (const float*)d_in[10];
    const float* ee_b1 = (const float*)d_in[11];
    const float* ee_W2 = (const float*)d_in[12];
    const float* ee_b2 = (const float*)d_in[13];
    const float* enc_bn1_g = (const float*)d_in[14];
    const float* enc_bn1_b = (const float*)d_in[15];
    const float* enc_bn2_g = (const float*)d_in[16];
    const float* enc_bn2_b = (const float*)d_in[17];
    const float* ee_bn1_g = (const float*)d_in[18];
    const float* ee_bn1_b = (const float*)d_in[19];
    const float* ee_bn2_g = (const float*)d_in[20];
    const float* ee_bn2_b = (const float*)d_in[21];
    const float* l0_Wnode = (const float*)d_in[22];
    const float* l0_bnode = (const float*)d_in[23];
    const float* l0_Wni = (const float*)d_in[24];
    const float* l0_Wnj = (const float*)d_in[25];
    const float* l0_Wfij = (const float*)d_in[26];
    const float* l0_attn = (const float*)d_in[27];
    const float* l0_bnn_g = (const float*)d_in[28];
    const float* l0_bnn_b = (const float*)d_in[29];
    const float* l0_bne_g = (const float*)d_in[30];
    const float* l0_bne_b = (const float*)d_in[31];
    const float* l0_Wpn = (const float*)d_in[32];
    const float* l0_bpn = (const float*)d_in[33];
    const float* l0_Wpe = (const float*)d_in[34];
    const float* l0_bpe = (const float*)d_in[35];
    const float* l1_Wnode = (const float*)d_in[36];
    const float* l1_bnode = (const float*)d_in[37];
    const float* l1_Wni = (const float*)d_in[38];
    const float* l1_Wnj = (const float*)d_in[39];
    const float* l1_Wfij = (const float*)d_in[40];
    const float* l1_attn = (const float*)d_in[41];
    const float* l1_bnn_g = (const float*)d_in[42];
    const float* l1_bnn_b = (const float*)d_in[43];
    const float* l1_Wpn = (const float*)d_in[46];
    const float* l1_bpn = (const float*)d_in[47];
    const float* dec_W = (const float*)d_in[50];
    const float* dec_b = (const float*)d_in[51];
    const float* dec_bn_g = (const float*)d_in[52];
    const float* dec_bn_b = (const float*)d_in[53];
    const float* dec_prelu = (const float*)d_in[54];
    const float* dec_Wout = (const float*)d_in[55];
    const float* dec_bout = (const float*)d_in[56];

    float* out = (float*)d_out;
    float* H1 = out;                     // N x 64 (fp32)
    float* H2 = out + (long)NN * 64;     // N x 64 (fp32)
    float* POOL = out + (long)NN * 128;  // G x 1 (fp32)

    char* base = (char*)d_ws;
    size_t off = 0;
    auto alloc = [&](size_t bytes) -> void* {
        off = (off + 255) & ~(size_t)255;
        void* p = base + off;
        off += bytes;
        return p;
    };
    u16* EH = (u16*)alloc((size_t)NE * 64 * 2);
    u16* F128 = (u16*)alloc((size_t)NE * 128 * 2);
    float* EATT = (float*)alloc((size_t)NE * 2 * 4);
    u16* NX = (u16*)alloc((size_t)NN * 64 * 2);
    u16* NI = (u16*)alloc((size_t)NN * 128 * 2);
    u16* NJ = (u16*)alloc((size_t)NN * 128 * 2);
    u16* NHH = (u16*)alloc((size_t)NN * 128 * 2);
    char* zstart = base + ((off + 255) & ~(size_t)255);
    float* HOUT0 = (float*)alloc((size_t)NN * 128 * 4);
    float* HOUT1 = (float*)alloc((size_t)NN * 64 * 4);
    u32* EMAX0 = (u32*)alloc((size_t)NN * 2 * 4);
    float* DEN0 = (float*)alloc((size_t)NN * 2 * 4);
    u32* EMAX1 = (u32*)alloc((size_t)NN * 4);
    float* DEN1 = (float*)alloc((size_t)NN * 4);
    float* STATS_RAW = (float*)alloc((size_t)13 * NSLOT * 256 * 4);
    float* RAWEF = (float*)alloc((size_t)NSLOT * 16 * 4);
    float* STATS = (float*)alloc((size_t)13 * 256 * 4);
    char* zend = base + off;
    float* RWrot = (float*)alloc(256 * 4);
    float* RWref = (float*)alloc(256 * 4);
    if (ws_size < off) return;

    u16* T2 = F128 + (size_t)NE * 64;  // NE x 64 bf16
    u16* NX0 = F128;                   // NN x 64 bf16 (node-enc temp)
    u16* NT = F128 + (size_t)NN * 64;  // NN x 64 bf16 (node-enc temp)
    u16* DT0 = NI;
    u16* DT1 = NJ;

    auto RAW = [&](int idx) { return STATS_RAW + (size_t)idx * NSLOT * 256; };
    float* S_enc1 = STATS + 0 * 256;
    float* S_enc2 = STATS + 1 * 256;
    float* S_ee1r = STATS + 2 * 256;
    float* S_ee2r = STATS + 3 * 256;
    float* S_ee1f = STATS + 4 * 256;
    float* S_ee2f = STATS + 5 * 256;
    float* S_bnn0 = STATS + 6 * 256;
    float* S_bne0 = STATS + 7 * 256;
    float* S_bnn1 = STATS + 8 * 256;
    float* S_d0 = STATS + 9 * 256;
    float* S_d1 = STATS + 10 * 256;
    float* S_d2 = STATS + 11 * 256;
    float* S_d3 = STATS + 12 * 256;

    const float invN = 1.f / (float)NN;
    const float invE = 1.f / (float)NE;
    const int GS = 640;

    hipMemsetAsync(zstart, 0, (size_t)(zend - zstart), stream);
    hipMemsetAsync(POOL, 0, (size_t)NG * 4, stream);

    setup_kernel<<<1, 64, 0, stream>>>(ang_rot, ang_ref, ee_W1, RWrot, RWref);

    // ---- node encoder ----
    gather_emb_kernel<<<(NN * 8 + 255) / 256, 256, 0, stream>>>(ntype, emb, NX0, NN);
    colstats_kernel<64, true><<<GS, 256, 0, stream>>>(NX0, NN, RAW(0));
    finalize_stats_kernel<<<1, 256, 0, stream>>>(RAW(0), S_enc1, 128);
    mm_kernel<64, 64, true, false, true, true><<<(NN + 15) / 16, 256, 0, stream>>>(
        NX0, enc_W, enc_b, nullptr, NT, NN, 2, S_enc1, enc_bn1_g, enc_bn1_b, invN, nullptr, 0,
        RAW(1));
    finalize_stats_kernel<<<1, 256, 0, stream>>>(RAW(1), S_enc2, 128);
    bn_act_kernel<<<(NN * 8 + 255) / 256, 256, 0, stream>>>(NT, NX, NN, 64, S_enc2, enc_bn2_g,
                                                            enc_bn2_b, invN, 0);

    // ---- edge encoder (T1 eliminated: analytic stats + fused recompute) ----
    efstats_kernel<<<256, 256, 0, stream>>>(efeats, NE, RAWEF);
    ee_stats_kernel<<<1, 128, 0, stream>>>(RAWEF, RWrot, RWref, ee_b1, S_ee1r, S_ee1f, NE);
    for (int br = 0; br < 2; ++br) {
        const float* RW = br ? RWref : RWrot;
        float* S1 = br ? S_ee1f : S_ee1r;
        float* S2 = br ? S_ee2f : S_ee2r;
        int r2 = br ? 5 : 3;
        ee_mm_kernel<<<(NE + 15) / 16, 256, 0, stream>>>(efeats, RW, ee_b1, ee_W2, ee_b2, T2, NE,
                                                         S1, ee_bn1_g, ee_bn1_b, invE, RAW(r2));
        finalize_stats_kernel<<<1, 256, 0, stream>>>(RAW(r2), S2, 128);
        bn_act_kernel<<<(NE * 8 + 255) / 256, 256, 0, stream>>>(T2, EH, NE, 64, S2, ee_bn2_g,
                                                                ee_bn2_b, invE, br);
    }

    // ---- layer 0 (H=2) ----
    mm_kernel<64, 128, true, false, true, false><<<(NN + 7) / 8, 256, 0, stream>>>(
        NX, l0_Wni, nullptr, nullptr, NI, NN, 0, nullptr, nullptr, nullptr, 0.f, nullptr, 0,
        nullptr);
    mm_kernel<64, 128, true, false, true, false><<<(NN + 7) / 8, 256, 0, stream>>>(
        NX, l0_Wnj, nullptr, nullptr, NJ, NN, 0, nullptr, nullptr, nullptr, 0.f, nullptr, 0,
        nullptr);
    mm_kernel<64, 128, true, false, true, false><<<(NN + 7) / 8, 256, 0, stream>>>(
        NX, l0_Wnode, l0_bnode, nullptr, NHH, NN, 0, nullptr, nullptr, nullptr, 0.f, nullptr, 0,
        nullptr);
    egat_fe_kernel<128, true><<<(NE + 15) / 16, 256, 0, stream>>>(EH, l0_Wfij, NI, NJ, src, dst,
                                                                  l0_attn, F128, EATT, EMAX0, NE);
    edge_softmax_kernel<<<((long)NE * 2 + 255) / 256, 256, 0, stream>>>(EATT, dst, EMAX0, DEN0,
                                                                        (long)NE * 2, 2);
    egat_scatter_kernel<128><<<(NE + 3) / 4, 256, 0, stream>>>(NHH, EATT, DEN0, src, dst, HOUT0,
                                                               NE);
    colstats_kernel<128, false><<<GS, 256, 0, stream>>>(HOUT0, NN, RAW(6));
    finalize_stats_kernel<<<1, 256, 0, stream>>>(RAW(6), S_bnn0, 256);
    colstats_kernel<128, true><<<GS, 256, 0, stream>>>(F128, NE, RAW(7));
    finalize_stats_kernel<<<1, 256, 0, stream>>>(RAW(7), S_bne0, 256);
    mm_kernel<128, 64, false, true, false, false><<<(NN + 15) / 16, 256, 0, stream>>>(
        HOUT0, l0_Wpn, l0_bpn, NX, H1, NN, 1, S_bnn0, l0_bnn_g, l0_bnn_b, invN, nullptr, 0,
        nullptr);
    mm_kernel<128, 64, true, true, true, false><<<(NE + 15) / 16, 256, 0, stream>>>(
        F128, l0_Wpe, l0_bpe, EH, EH, NE, 1, S_bne0, l0_bne_g, l0_bne_b, invE, nullptr, 0,
        nullptr);

    // ---- layer 1 (H=1; edge output dead -> skipped) ----
    mm_kernel<64, 64, false, false, true, false><<<(NN + 15) / 16, 256, 0, stream>>>(
        H1, l1_Wni, nullptr, nullptr, NI, NN, 0, nullptr, nullptr, nullptr, 0.f, nullptr, 0,
        nullptr);
    mm_kernel<64, 64, false, false, true, false><<<(NN + 15) / 16, 256, 0, stream>>>(
        H1, l1_Wnj, nullptr, nullptr, NJ, NN, 0, nullptr, nullptr, nullptr, 0.f, nullptr, 0,
        nullptr);
    mm_kernel<64, 64, false, false, true, false><<<(NN + 15) / 16, 256, 0, stream>>>(
        H1, l1_Wnode, l1_bnode, nullptr, NHH, NN, 0, nullptr, nullptr, nullptr, 0.f, nullptr, 0,
        nullptr);
    egat_fe_kernel<64, false><<<(NE + 31) / 32, 256, 0, stream>>>(EH, l1_Wfij, NI, NJ, src, dst,
                                                                  l1_attn, nullptr, EATT, EMAX1,
                                                                  NE);
    edge_softmax_kernel<<<(NE + 255) / 256, 256, 0, stream>>>(EATT, dst, EMAX1, DEN1, (long)NE, 1);
    egat_scatter_kernel<64><<<(NE + 7) / 8, 256, 0, stream>>>(NHH, EATT, DEN1, src, dst, HOUT1,
                                                              NE);
    colstats_kernel<64, false><<<GS, 256, 0, stream>>>(HOUT1, NN, RAW(8));
    finalize_stats_kernel<<<1, 256, 0, stream>>>(RAW(8), S_bnn1, 128);
    mm_kernel<64, 64, false, false, false, false><<<(NN + 15) / 16, 256, 0, stream>>>(
        HOUT1, l1_Wpn, l1_bpn, H1, H2, NN, 1, S_bnn1, l1_bnn_g, l1_bnn_b, invN, nullptr, 0,
        nullptr);

    // ---- decoder ----
    mm_kernel<64, 64, false, false, true, true><<<(NN + 15) / 16, 256, 0, stream>>>(
        H2, dec_W, dec_b, nullptr, DT0, NN, 0, nullptr, nullptr, nullptr, 0.f, nullptr, 0, RAW(9));
    finalize_stats_kernel<<<1, 256, 0, stream>>>(RAW(9), S_d0, 128);
    mm_kernel<64, 64, true, false, true, true><<<(NN + 15) / 16, 256, 0, stream>>>(
        DT0, dec_W + 4096, dec_b + 64, nullptr, DT1, NN, 3, S_d0, dec_bn_g, dec_bn_b, invN,
        dec_prelu, 0, RAW(10));
    finalize_stats_kernel<<<1, 256, 0, stream>>>(RAW(10), S_d1, 128);
    mm_kernel<64, 64, true, false, true, true><<<(NN + 15) / 16, 256, 0, stream>>>(
        DT1, dec_W + 8192, dec_b + 128, nullptr, DT0, NN, 3, S_d1, dec_bn_g + 64, dec_bn_b + 64,
        invN, dec_prelu, 1, RAW(11));
    finalize_stats_kernel<<<1, 256, 0, stream>>>(RAW(11), S_d2, 128);
    mm_kernel<64, 64, true, false, true, true><<<(NN + 15) / 16, 256, 0, stream>>>(
        DT0, dec_W + 12288, dec_b + 192, nullptr, DT1, NN, 3, S_d2, dec_bn_g + 128,
        dec_bn_b + 128, invN, dec_prelu, 2, RAW(12));
    finalize_stats_kernel<<<1, 256, 0, stream>>>(RAW(12), S_d3, 128);
    decoder_out_kernel<<<(NN + 3) / 4, 256, 0, stream>>>(DT1, S_d3, dec_bn_g + 192,
                                                         dec_bn_b + 192, dec_prelu, dec_Wout,
                                                         dec_bout, gid, POOL, NN, invN);
}

// Round 5
// 1536.215 us; speedup vs baseline: 1.1900x; 1.1900x over previous
//
#include <hip/hip_runtime.h>
#include <math.h>

#define NN 50000
#define NE 400000
#define NG 512
#define EPS 1e-5f
#define NSLOT 256  // stats replica slots (atomic contention spreading)

typedef unsigned int u32;
typedef unsigned short u16;

__device__ __forceinline__ float b2f(u16 h) { return __uint_as_float(((u32)h) << 16); }
__device__ __forceinline__ u16 f2b(float f) {
    u32 x = __float_as_uint(f);
    u32 r = x + 0x7fffu + ((x >> 16) & 1u);
    return (u16)(r >> 16);
}
struct alignas(16) U16x8 { u16 s[8]; };
struct alignas(8) U16x4 { u16 s[4]; };
struct alignas(4) U16x2 { u16 s[2]; };

__device__ __forceinline__ void f4add(float4& a, const float4 b) {
    a.x += b.x; a.y += b.y; a.z += b.z; a.w += b.w;
}

// ---------------- setup: fold rotation matrices into ee_W1 (fp32) ----------------
__global__ void setup_kernel(const float* __restrict__ ang_rot, const float* __restrict__ ang_ref,
                             const float* __restrict__ W1, float* __restrict__ RWrot,
                             float* __restrict__ RWref) {
    int c = threadIdx.x;  // 64
    for (int which = 0; which < 2; ++which) {
        const float* a = which ? ang_ref : ang_rot;
        float t = a[0], p = a[1], q = a[2];
        float ct = cosf(t), st = sinf(t);
        float cp = cosf(p), sp = sinf(p);
        float cq = cosf(q), sq = sinf(q);
        float Rt[3][3] = {{ct, -st, 0.f}, {st, ct, 0.f}, {0.f, 0.f, 1.f}};
        float Rp[3][3] = {{cp, 0.f, -sp}, {0.f, 1.f, 0.f}, {sp, 0.f, cp}};
        float Rq[3][3] = {{1.f, 0.f, 0.f}, {0.f, cq, -sq}, {0.f, sq, cq}};
        float Rtp[3][3], R[3][3];
        for (int i = 0; i < 3; ++i)
            for (int j = 0; j < 3; ++j) {
                float s = 0.f;
                for (int k = 0; k < 3; ++k) s += Rt[i][k] * Rp[k][j];
                Rtp[i][j] = s;
            }
        for (int i = 0; i < 3; ++i)
            for (int j = 0; j < 3; ++j) {
                float s = 0.f;
                for (int k = 0; k < 3; ++k) s += Rtp[i][k] * Rq[k][j];
                R[i][j] = s;
            }
        float sgn = which ? -1.f : 1.f;  // R_ref = -rotmat(angles_ref)
        float* RW = which ? RWref : RWrot;
        if (c < 64) {
            for (int j = 0; j < 3; ++j) {
                float s = 0.f;
                for (int m = 0; m < 3; ++m) s += sgn * R[j][m] * W1[m * 64 + c];
                RW[j * 64 + c] = s;  // RW = R @ W1  (3 x 64)
            }
        }
    }
}

// ---------------- CSR build: degree hist -> scan -> fill ----------------
__global__ __launch_bounds__(256) void hist_kernel(const int* __restrict__ dst, int E,
                                                   int* __restrict__ deg) {
    int e = blockIdx.x * 256 + threadIdx.x;
    if (e < E) atomicAdd(&deg[dst[e]], 1);
}

__global__ __launch_bounds__(1024) void scan_kernel(const int* __restrict__ deg,
                                                    int* __restrict__ rowptr,
                                                    int* __restrict__ curs, int n) {
    __shared__ int part[1024];
    int tid = threadIdx.x;
    const int CHUNK = (n + 1023) / 1024;
    int s0 = tid * CHUNK;
    int sum = 0;
    for (int i = 0; i < CHUNK; ++i) {
        int idx = s0 + i;
        if (idx < n) sum += deg[idx];
    }
    part[tid] = sum;
    __syncthreads();
    for (int off = 1; off < 1024; off <<= 1) {
        int v = (tid >= off) ? part[tid - off] : 0;
        __syncthreads();
        part[tid] += v;
        __syncthreads();
    }
    int run = (tid == 0) ? 0 : part[tid - 1];
    for (int i = 0; i < CHUNK; ++i) {
        int idx = s0 + i;
        if (idx < n) {
            rowptr[idx] = run;
            curs[idx] = run;
            run += deg[idx];
        }
    }
    if (tid == 1023) rowptr[n] = run;
}

__global__ __launch_bounds__(256) void fill_kernel(const int* __restrict__ src,
                                                   const int* __restrict__ dst, int E,
                                                   int* __restrict__ curs,
                                                   int* __restrict__ epos,
                                                   int* __restrict__ esrc) {
    int e = blockIdx.x * 256 + threadIdx.x;
    if (e >= E) return;
    int pos = atomicAdd(&curs[dst[e]], 1);
    epos[e] = pos;
    esrc[pos] = src[e];
}

// ---------------- embedding gather: fp32 table -> bf16 out ----------------
__global__ __launch_bounds__(256) void gather_emb_kernel(const int* __restrict__ ntype,
                                                         const float* __restrict__ emb,
                                                         u16* __restrict__ out, int n) {
    long i = (long)blockIdx.x * 256 + threadIdx.x;  // over n*8
    long e = i >> 3;
    if (e >= n) return;
    int c0 = (int)(i & 7) * 8;
    int t = ntype[e];
    float4 a = *(const float4*)&emb[(long)t * 64 + c0];
    float4 b = *(const float4*)&emb[(long)t * 64 + c0 + 4];
    U16x8 o;
    o.s[0] = f2b(a.x); o.s[1] = f2b(a.y); o.s[2] = f2b(a.z); o.s[3] = f2b(a.w);
    o.s[4] = f2b(b.x); o.s[5] = f2b(b.y); o.s[6] = f2b(b.z); o.s[7] = f2b(b.w);
    *(U16x8*)&out[e * 64 + c0] = o;
}

// ---------------- efeats second moments: 9 scalars -> replica slots ----------------
__global__ __launch_bounds__(256) void efstats_kernel(const float* __restrict__ ef, int E,
                                                      float* __restrict__ raw) {
    int tid = threadIdx.x;
    float a[9];
#pragma unroll
    for (int j = 0; j < 9; ++j) a[j] = 0.f;
    for (long e = (long)blockIdx.x * 256 + tid; e < E; e += (long)gridDim.x * 256) {
        float f0 = ef[e * 3 + 0], f1 = ef[e * 3 + 1], f2 = ef[e * 3 + 2];
        a[0] += f0; a[1] += f1; a[2] += f2;
        a[3] += f0 * f0; a[4] += f1 * f1; a[5] += f2 * f2;
        a[6] += f0 * f1; a[7] += f0 * f2; a[8] += f1 * f2;
    }
#pragma unroll
    for (int off = 1; off < 64; off <<= 1)
#pragma unroll
        for (int j = 0; j < 9; ++j) a[j] += __shfl_xor(a[j], off, 64);
    __shared__ float sred[4][9];
    int wv = tid >> 6, ln = tid & 63;
    if (ln == 0)
#pragma unroll
        for (int j = 0; j < 9; ++j) sred[wv][j] = a[j];
    __syncthreads();
    if (tid < 9) {
        float v = sred[0][tid] + sred[1][tid] + sred[2][tid] + sred[3][tid];
        atomicAdd(&raw[(size_t)(blockIdx.x & (NSLOT - 1)) * 16 + tid], v);
    }
}

// ---------------- analytic T1 column stats for both branches ----------------
__global__ void ee_stats_kernel(const float* __restrict__ efraw, const float* __restrict__ RWrot,
                                const float* __restrict__ RWref, const float* __restrict__ b1,
                                float* __restrict__ S_rot, float* __restrict__ S_ref, int E) {
    __shared__ float m[9];
    int t = threadIdx.x;  // 128
    if (t < 9) {
        float s = 0.f;
        for (int r = 0; r < NSLOT; ++r) s += efraw[r * 16 + t];
        m[t] = s;
    }
    __syncthreads();
    int br = t >> 6, c = t & 63;
    const float* RW = br ? RWref : RWrot;
    float* S = br ? S_ref : S_rot;
    float w0 = RW[c], w1 = RW[64 + c], w2 = RW[128 + c];
    float bb = b1[c];
    float mw = m[0] * w0 + m[1] * w1 + m[2] * w2;
    float sum = mw + (float)E * bb;
    float quad = m[3] * w0 * w0 + m[4] * w1 * w1 + m[5] * w2 * w2 +
                 2.f * (m[6] * w0 * w1 + m[7] * w0 * w2 + m[8] * w1 * w2);
    float ss = quad + 2.f * bb * mw + (float)E * bb * bb;
    S[c] = sum;
    S[64 + c] = ss;
}

// ---------------- column stats -> replicated raw accumulators ----------------
template <int COLS, bool XBF>
__global__ __launch_bounds__(256) void colstats_kernel(const void* __restrict__ xv, int rows,
                                                       float* __restrict__ raw) {
    constexpr int TPR = COLS / 8;
    constexpr int RPB = 256 / TPR;
    __shared__ float4 sA[256], sB[256], sC[256], sD[256];
    int tid = threadIdx.x;
    int c8 = tid % TPR;
    int rl = tid / TPR;
    float s[8], q[8];
#pragma unroll
    for (int j = 0; j < 8; ++j) { s[j] = 0.f; q[j] = 0.f; }
    const long stride = (long)gridDim.x * RPB;
    long r = (long)blockIdx.x * RPB + rl;
    auto loadrow = [&](long rr, float* v) {
        if (XBF) {
            U16x8 t = *(const U16x8*)((const u16*)xv + rr * COLS + c8 * 8);
#pragma unroll
            for (int j = 0; j < 8; ++j) v[j] = b2f(t.s[j]);
        } else {
            float4 a = *(const float4*)((const float*)xv + rr * COLS + c8 * 8);
            float4 b = *(const float4*)((const float*)xv + rr * COLS + c8 * 8 + 4);
            v[0] = a.x; v[1] = a.y; v[2] = a.z; v[3] = a.w;
            v[4] = b.x; v[5] = b.y; v[6] = b.z; v[7] = b.w;
        }
    };
    for (; r + stride < rows; r += 2 * stride) {
        float v0[8], v1[8];
        loadrow(r, v0);
        loadrow(r + stride, v1);
#pragma unroll
        for (int j = 0; j < 8; ++j) {
            s[j] += v0[j] + v1[j];
            q[j] += v0[j] * v0[j] + v1[j] * v1[j];
        }
    }
    if (r < rows) {
        float v0[8];
        loadrow(r, v0);
#pragma unroll
        for (int j = 0; j < 8; ++j) { s[j] += v0[j]; q[j] += v0[j] * v0[j]; }
    }
    sA[tid] = make_float4(s[0], s[1], s[2], s[3]);
    sB[tid] = make_float4(s[4], s[5], s[6], s[7]);
    sC[tid] = make_float4(q[0], q[1], q[2], q[3]);
    sD[tid] = make_float4(q[4], q[5], q[6], q[7]);
    __syncthreads();
    for (int off = 128; off >= TPR; off >>= 1) {
        if (tid < off) {
            f4add(sA[tid], sA[tid + off]); f4add(sB[tid], sB[tid + off]);
            f4add(sC[tid], sC[tid + off]); f4add(sD[tid], sD[tid + off]);
        }
        __syncthreads();
    }
    if (tid < TPR) {
        float* slot = raw + (size_t)(blockIdx.x & (NSLOT - 1)) * 256;
        int c = tid * 8;
        float4 a = sA[tid], b = sB[tid], cq = sC[tid], d = sD[tid];
        atomicAdd(&slot[c + 0], a.x); atomicAdd(&slot[c + 1], a.y);
        atomicAdd(&slot[c + 2], a.z); atomicAdd(&slot[c + 3], a.w);
        atomicAdd(&slot[c + 4], b.x); atomicAdd(&slot[c + 5], b.y);
        atomicAdd(&slot[c + 6], b.z); atomicAdd(&slot[c + 7], b.w);
        atomicAdd(&slot[COLS + c + 0], cq.x); atomicAdd(&slot[COLS + c + 1], cq.y);
        atomicAdd(&slot[COLS + c + 2], cq.z); atomicAdd(&slot[COLS + c + 3], cq.w);
        atomicAdd(&slot[COLS + c + 4], d.x); atomicAdd(&slot[COLS + c + 5], d.y);
        atomicAdd(&slot[COLS + c + 6], d.z); atomicAdd(&slot[COLS + c + 7], d.w);
    }
}

// ---------------- reduce NSLOT replica slots -> final stats ----------------
__global__ __launch_bounds__(256) void finalize_stats_kernel(const float* __restrict__ raw,
                                                             float* __restrict__ stats, int n) {
    int i = threadIdx.x;
    if (i >= n) return;
    float s = 0.f;
    for (int r = 0; r < NSLOT; ++r) s += raw[r * 256 + i];
    stats[i] = s;
}

// ---------------- elementwise y = relu(bn(x)) [+= y], bf16 x/y ----------------
__global__ __launch_bounds__(256) void bn_act_kernel(const u16* __restrict__ x,
                                                     u16* __restrict__ y, long rows, int cols,
                                                     const float* __restrict__ acc,
                                                     const float* __restrict__ g,
                                                     const float* __restrict__ b, float inv_rows,
                                                     int accumulate) {
    long i = (long)blockIdx.x * 256 + threadIdx.x;
    long total8 = rows * (long)cols / 8;
    if (i >= total8) return;
    long base = i * 8;
    int c0 = (int)(base % cols);
    U16x8 xv = *(const U16x8*)&x[base];
    float r[8];
#pragma unroll
    for (int j = 0; j < 8; ++j) {
        int c = c0 + j;
        float mu = acc[c] * inv_rows;
        float var = acc[cols + c] * inv_rows - mu * mu;
        float al = g[c] * rsqrtf(fmaxf(var, 0.f) + EPS);
        float be = b[c] - mu * al;
        float o = al * b2f(xv.s[j]) + be;
        r[j] = fmaxf(o, 0.f);
    }
    if (accumulate) {
        U16x8 yv = *(const U16x8*)&y[base];
#pragma unroll
        for (int j = 0; j < 8; ++j) r[j] += b2f(yv.s[j]);
    }
    U16x8 o;
#pragma unroll
    for (int j = 0; j < 8; ++j) o.s[j] = f2b(r[j]);
    *(U16x8*)&y[base] = o;
}

// ---------------- generic tiled matmul: Y = preop(X) @ W (+bias)(+res) ----------------
template <int K, int COLS, bool XBF, bool RBF, bool OBF, bool SOUT>
__global__ __launch_bounds__(256) void mm_kernel(const void* __restrict__ Xv,
                                                 const float* __restrict__ Wg,
                                                 const float* __restrict__ bias, const void* resv,
                                                 void* Yv, int rows, int preop,
                                                 const float* __restrict__ stats,
                                                 const float* __restrict__ g,
                                                 const float* __restrict__ b, float inv_rows,
                                                 const float* __restrict__ prelu, int prelu_idx,
                                                 float* __restrict__ raw) {
    constexpr int TPR = COLS / 4;
    constexpr int RPB = 256 / TPR;
    constexpr int XP = K + 4;
    __shared__ float ws[K * COLS];
    __shared__ float xs[RPB * XP];
    __shared__ float al[K];
    __shared__ float be[K];
    const int tid = threadIdx.x;

    for (int i = tid; i < K * COLS; i += 256) ws[i] = Wg[i];
    if (preop) {
        for (int k = tid; k < K; k += 256) {
            float mu = stats[k] * inv_rows;
            float var = stats[K + k] * inv_rows - mu * mu;
            float a = g[k] * rsqrtf(fmaxf(var, 0.f) + EPS);
            al[k] = a;
            be[k] = b[k] - mu * a;
        }
    }
    __syncthreads();

    const long r0 = (long)blockIdx.x * RPB;
    float pa = (preop == 3) ? prelu[prelu_idx] : 0.f;
    constexpr int NC = RPB * K / 4;
    for (int i = tid; i < NC; i += 256) {
        int b4 = i * 4;
        int rl = b4 / K, k0 = b4 % K;
        long r = r0 + rl;
        float v[4];
        if (r < rows) {
            if (XBF) {
                U16x4 t = *(const U16x4*)((const u16*)Xv + r * K + k0);
#pragma unroll
                for (int j = 0; j < 4; ++j) v[j] = b2f(t.s[j]);
            } else {
                float4 t = *(const float4*)((const float*)Xv + r * K + k0);
                v[0] = t.x; v[1] = t.y; v[2] = t.z; v[3] = t.w;
            }
        } else {
#pragma unroll
            for (int j = 0; j < 4; ++j) v[j] = 0.f;
        }
        if (preop) {
#pragma unroll
            for (int j = 0; j < 4; ++j) {
                float xx = al[k0 + j] * v[j] + be[k0 + j];
                if (preop == 2) xx = fmaxf(xx, 0.f);
                else if (preop == 3) xx = (xx >= 0.f) ? xx : pa * xx;
                v[j] = xx;
            }
        }
        xs[rl * XP + k0 + 0] = v[0];
        xs[rl * XP + k0 + 1] = v[1];
        xs[rl * XP + k0 + 2] = v[2];
        xs[rl * XP + k0 + 3] = v[3];
    }
    __syncthreads();

    const int rl = tid / TPR;
    const int c0 = (tid % TPR) * 4;
    float4 acc = {0.f, 0.f, 0.f, 0.f};
#pragma unroll
    for (int k = 0; k < K; k += 4) {
        float4 xv = *(const float4*)&xs[rl * XP + k];
#pragma unroll
        for (int j = 0; j < 4; ++j) {
            float xj = (&xv.x)[j];
            float4 wv = *(const float4*)&ws[(k + j) * COLS + c0];
            acc.x += xj * wv.x; acc.y += xj * wv.y;
            acc.z += xj * wv.z; acc.w += xj * wv.w;
        }
    }
    long r = r0 + rl;
    if (r < rows) {
        if (bias) f4add(acc, *(const float4*)&bias[c0]);
        if (resv) {
            if (RBF) {
                U16x4 t = *(const U16x4*)((const u16*)resv + r * COLS + c0);
                acc.x += b2f(t.s[0]); acc.y += b2f(t.s[1]);
                acc.z += b2f(t.s[2]); acc.w += b2f(t.s[3]);
            } else {
                f4add(acc, *(const float4*)((const float*)resv + r * COLS + c0));
            }
        }
        if (OBF) {
            U16x4 o;
            o.s[0] = f2b(acc.x); o.s[1] = f2b(acc.y);
            o.s[2] = f2b(acc.z); o.s[3] = f2b(acc.w);
            *(U16x4*)((u16*)Yv + r * COLS + c0) = o;
        } else {
            *(float4*)((float*)Yv + r * COLS + c0) = acc;
        }
    }
    if constexpr (SOUT) {
        __syncthreads();
        float4 va = (r < rows) ? acc : make_float4(0.f, 0.f, 0.f, 0.f);
        *(float4*)&ws[rl * COLS + c0] = va;
        float4 vq = make_float4(va.x * va.x, va.y * va.y, va.z * va.z, va.w * va.w);
        *(float4*)&ws[RPB * COLS + rl * COLS + c0] = vq;
        __syncthreads();
        for (int off2 = RPB / 2; off2 >= 1; off2 >>= 1) {
            if (rl < off2) {
                float4 x1 = *(float4*)&ws[rl * COLS + c0];
                f4add(x1, *(const float4*)&ws[(rl + off2) * COLS + c0]);
                *(float4*)&ws[rl * COLS + c0] = x1;
                float4 x2 = *(float4*)&ws[RPB * COLS + rl * COLS + c0];
                f4add(x2, *(const float4*)&ws[RPB * COLS + (rl + off2) * COLS + c0]);
                *(float4*)&ws[RPB * COLS + rl * COLS + c0] = x2;
            }
            __syncthreads();
        }
        if (rl == 0) {
            float* slot = raw + (size_t)(blockIdx.x & (NSLOT - 1)) * 256;
#pragma unroll
            for (int j = 0; j < 4; ++j) {
                atomicAdd(&slot[c0 + j], ws[c0 + j]);
                atomicAdd(&slot[COLS + c0 + j], ws[RPB * COLS + c0 + j]);
            }
        }
    }
}

// ---------------- edge-encoder mm: T2 = relu(bn1(ef@RW + b1)) @ W2 + b2, fused ----------------
__global__ __launch_bounds__(256) void ee_mm_kernel(
    const float* __restrict__ ef, const float* __restrict__ RW, const float* __restrict__ b1v,
    const float* __restrict__ W2, const float* __restrict__ b2, u16* __restrict__ T2, int E,
    const float* __restrict__ stats, const float* __restrict__ g, const float* __restrict__ b,
    float inv_rows, float* __restrict__ raw) {
    constexpr int K = 64, COLS = 64, TPR = 16, RPB = 16, XP = 68;
    __shared__ float ws[K * COLS];
    __shared__ float xs[RPB * XP];
    __shared__ float rws[192];
    __shared__ float efs[RPB * 3];
    __shared__ float al[K];
    __shared__ float be[K];
    const int tid = threadIdx.x;
    const long r0 = (long)blockIdx.x * RPB;

    for (int i = tid; i < K * COLS; i += 256) ws[i] = W2[i];
    if (tid < 192) rws[tid] = RW[tid];
    {
        long lim = ((long)E - r0) * 3;
        if (lim > RPB * 3) lim = RPB * 3;
        if (tid < RPB * 3) efs[tid] = (tid < lim) ? ef[r0 * 3 + tid] : 0.f;
    }
    for (int k = tid; k < K; k += 256) {
        float mu = stats[k] * inv_rows;
        float var = stats[K + k] * inv_rows - mu * mu;
        float a = g[k] * rsqrtf(fmaxf(var, 0.f) + EPS);
        al[k] = a;
        be[k] = b[k] - mu * a + a * b1v[k];  // fold b1 into affine
    }
    __syncthreads();
    for (int i = tid; i < RPB * K; i += 256) {
        int rl2 = i >> 6, k = i & 63;
        float t = efs[rl2 * 3 + 0] * rws[k] + efs[rl2 * 3 + 1] * rws[64 + k] +
                  efs[rl2 * 3 + 2] * rws[128 + k];
        float xx = al[k] * t + be[k];
        xs[rl2 * XP + k] = fmaxf(xx, 0.f);
    }
    __syncthreads();

    const int rl = tid / TPR;
    const int c0 = (tid % TPR) * 4;
    float4 acc = {0.f, 0.f, 0.f, 0.f};
#pragma unroll
    for (int k = 0; k < K; k += 4) {
        float4 xv = *(const float4*)&xs[rl * XP + k];
#pragma unroll
        for (int j = 0; j < 4; ++j) {
            float xj = (&xv.x)[j];
            float4 wv = *(const float4*)&ws[(k + j) * COLS + c0];
            acc.x += xj * wv.x; acc.y += xj * wv.y;
            acc.z += xj * wv.z; acc.w += xj * wv.w;
        }
    }
    long r = r0 + rl;
    if (r < E) {
        f4add(acc, *(const float4*)&b2[c0]);
        U16x4 o;
        o.s[0] = f2b(acc.x); o.s[1] = f2b(acc.y);
        o.s[2] = f2b(acc.z); o.s[3] = f2b(acc.w);
        *(U16x4*)&T2[r * COLS + c0] = o;
    }
    __syncthreads();
    float4 va = (r < E) ? acc : make_float4(0.f, 0.f, 0.f, 0.f);
    *(float4*)&ws[rl * COLS + c0] = va;
    float4 vq = make_float4(va.x * va.x, va.y * va.y, va.z * va.z, va.w * va.w);
    *(float4*)&ws[RPB * COLS + rl * COLS + c0] = vq;
    __syncthreads();
    for (int off2 = RPB / 2; off2 >= 1; off2 >>= 1) {
        if (rl < off2) {
            float4 x1 = *(float4*)&ws[rl * COLS + c0];
            f4add(x1, *(const float4*)&ws[(rl + off2) * COLS + c0]);
            *(float4*)&ws[rl * COLS + c0] = x1;
            float4 x2 = *(float4*)&ws[RPB * COLS + rl * COLS + c0];
            f4add(x2, *(const float4*)&ws[RPB * COLS + (rl + off2) * COLS + c0]);
            *(float4*)&ws[RPB * COLS + rl * COLS + c0] = x2;
        }
        __syncthreads();
    }
    if (rl == 0) {
        float* slot = raw + (size_t)(blockIdx.x & (NSLOT - 1)) * 256;
#pragma unroll
        for (int j = 0; j < 4; ++j) {
            atomicAdd(&slot[c0 + j], ws[c0 + j]);
            atomicAdd(&slot[COLS + c0 + j], ws[RPB * COLS + c0 + j]);
        }
    }
}

// ---------------- EGAT: f = leaky(eh@Wfij + ni[src] + nj[dst]); raw att -> CSR slot ----------------
template <int COLS, bool WRITE_F>
__global__ __launch_bounds__(256) void egat_fe_kernel(
    const u16* __restrict__ EH, const float* __restrict__ Wg, const u16* __restrict__ NI,
    const u16* __restrict__ NJ, const int* __restrict__ src, const int* __restrict__ dst,
    const int* __restrict__ epos, const float* __restrict__ attn, u16* __restrict__ Fout,
    float* __restrict__ eatt, int E) {
    constexpr int H = COLS / 64;
    constexpr int TPR = COLS / 8;
    constexpr int RPB = 256 / TPR;
    constexpr int HW = COLS / 2;
    constexpr int XP = 68;
    __shared__ float ws[64 * COLS];
    __shared__ float xs[RPB * XP];
    const int tid = threadIdx.x;
    const int rl = tid / TPR;
    const int c4 = (tid % TPR) * 4;
    const long r0 = (long)blockIdx.x * RPB;
    const long e = r0 + rl;
    U16x4 ni0 = {}, ni1 = {}, nj0 = {}, nj1 = {};
    if (e < E) {
        int s = src[e];
        int d = dst[e];
        ni0 = *(const U16x4*)&NI[(long)s * COLS + c4];
        ni1 = *(const U16x4*)&NI[(long)s * COLS + HW + c4];
        nj0 = *(const U16x4*)&NJ[(long)d * COLS + c4];
        nj1 = *(const U16x4*)&NJ[(long)d * COLS + HW + c4];
    }
    float4 av0 = *(const float4*)&attn[c4];
    float4 av1 = *(const float4*)&attn[HW + c4];
    for (int i = tid; i < 64 * COLS; i += 256) ws[i] = Wg[i];
    for (int i = tid; i < RPB * 8; i += 256) {
        int rr = i / 8, k0 = (i % 8) * 8;
        long r = r0 + rr;
        if (r < E) {
            U16x8 t = *(const U16x8*)&EH[r * 64 + k0];
#pragma unroll
            for (int j = 0; j < 8; ++j) xs[rr * XP + k0 + j] = b2f(t.s[j]);
        } else {
#pragma unroll
            for (int j = 0; j < 8; ++j) xs[rr * XP + k0 + j] = 0.f;
        }
    }
    __syncthreads();
    float acc0[4] = {0.f, 0.f, 0.f, 0.f};
    float acc1[4] = {0.f, 0.f, 0.f, 0.f};
    for (int k = 0; k < 64; k += 4) {
        float4 xv = *(const float4*)&xs[rl * XP + k];
#pragma unroll
        for (int kk = 0; kk < 4; ++kk) {
            float xj = (&xv.x)[kk];
            float4 w0 = *(const float4*)&ws[(k + kk) * COLS + c4];
            float4 w1 = *(const float4*)&ws[(k + kk) * COLS + HW + c4];
            acc0[0] += xj * w0.x; acc0[1] += xj * w0.y;
            acc0[2] += xj * w0.z; acc0[3] += xj * w0.w;
            acc1[0] += xj * w1.x; acc1[1] += xj * w1.y;
            acc1[2] += xj * w1.z; acc1[3] += xj * w1.w;
        }
    }
    float part0 = 0.f, part1 = 0.f;
    if (e < E) {
        U16x4 fo0, fo1;
#pragma unroll
        for (int j = 0; j < 4; ++j) {
            float f0 = acc0[j] + b2f(ni0.s[j]) + b2f(nj0.s[j]);
            float f1 = acc1[j] + b2f(ni1.s[j]) + b2f(nj1.s[j]);
            f0 = (f0 >= 0.f) ? f0 : 0.01f * f0;
            f1 = (f1 >= 0.f) ? f1 : 0.01f * f1;
            fo0.s[j] = f2b(f0);
            fo1.s[j] = f2b(f1);
            part0 += f0 * (&av0.x)[j];
            part1 += f1 * (&av1.x)[j];
        }
        if (WRITE_F) {
            *(U16x4*)&Fout[e * COLS + c4] = fo0;
            *(U16x4*)&Fout[e * COLS + HW + c4] = fo1;
        }
    }
#pragma unroll
    for (int off = 1; off < TPR; off <<= 1) {
        part0 += __shfl_xor(part0, off, 64);
        part1 += __shfl_xor(part1, off, 64);
    }
    if (e < E && (tid % TPR) == 0) {
        long pos = epos[e];
        if (H == 2) {
            eatt[pos * 2 + 0] = part0;
            eatt[pos * 2 + 1] = part1;
        } else {
            eatt[pos] = part0 + part1;
        }
    }
}

// ---------------- CSR gather aggregate: per-node softmax + weighted sum ----------------
template <int COLS>
__global__ __launch_bounds__(256) void csr_aggregate_kernel(
    const int* __restrict__ rowptr, const int* __restrict__ esrc,
    const float* __restrict__ eatt, const u16* __restrict__ nodeh, float* __restrict__ hout,
    int n) {
    constexpr int H = COLS / 64;
    constexpr int TPN = COLS / 2;
    constexpr int NPB = 256 / TPN;
    int tid = threadIdx.x;
    int node = blockIdx.x * NPB + tid / TPN;
    if (node >= n) return;
    int c = (tid % TPN) * 2;
    int h = (H == 2) ? (c >> 6) : 0;
    int p0 = rowptr[node], p1 = rowptr[node + 1];
    float m = -INFINITY, s = 0.f;
    for (int p = p0; p < p1; ++p) {
        float v = eatt[(long)p * H + h];
        float mn = fmaxf(m, v);
        s = s * expf(m - mn) + expf(v - mn);
        m = mn;
    }
    float inv = (s > 0.f) ? 1.f / s : 0.f;
    float a0 = 0.f, a1 = 0.f;
    for (int p = p0; p < p1; ++p) {
        float w = expf(eatt[(long)p * H + h] - m) * inv;
        U16x2 v = *(const U16x2*)&nodeh[(long)esrc[p] * COLS + c];
        a0 += b2f(v.s[0]) * w;
        a1 += b2f(v.s[1]) * w;
    }
    *(float2*)&hout[(long)node * COLS + c] = make_float2(a0, a1);
}

// ---------------- decoder tail: prelu(bn(t3)) @ Wout + bout -> pool by graph ----------------
__global__ __launch_bounds__(256) void decoder_out_kernel(
    const u16* __restrict__ t3, const float* __restrict__ stats, const float* __restrict__ g,
    const float* __restrict__ b, const float* __restrict__ prelu, const float* __restrict__ Wout,
    const float* __restrict__ bout, const int* __restrict__ gid, float* __restrict__ pool,
    int rows, float inv_rows) {
    int tid = threadIdx.x;
    long r = (long)blockIdx.x * 4 + (tid >> 6);
    if (r >= rows) return;
    int k = tid & 63;
    float mu = stats[k] * inv_rows;
    float var = stats[64 + k] * inv_rows - mu * mu;
    float al = g[k] * rsqrtf(fmaxf(var, 0.f) + EPS);
    float be = b[k] - mu * al;
    float a = prelu[3];
    float v = al * b2f(t3[r * 64 + k]) + be;
    v = (v >= 0.f) ? v : a * v;
    v *= Wout[k];
#pragma unroll
    for (int off = 1; off < 64; off <<= 1) v += __shfl_xor(v, off, 64);
    if (k == 0) atomicAdd(&pool[gid[r]], v + bout[0]);
}

// =====================================================================================
extern "C" void kernel_launch(void* const* d_in, const int* in_sizes, int n_in, void* d_out,
                              int out_size, void* d_ws, size_t ws_size, hipStream_t stream) {
    if (n_in < 57) return;
    const int* ntype = (const int*)d_in[0];
    const int* src = (const int*)d_in[1];
    const int* dst = (const int*)d_in[2];
    const int* gid = (const int*)d_in[3];
    const float* ang_rot = (const float*)d_in[4];
    const float* ang_ref = (const float*)d_in[5];
    const float* efeats = (const float*)d_in[6];
    const float* emb = (const float*)d_in[7];
    const float* enc_W = (const float*)d_in[8];
    const float* enc_b = (const float*)d_in[9];
    const float* ee_W1 = (const float*)d_in[10];
    const float* ee_b1 = (const float*)d_in[11];
    const float* ee_W2 = (const float*)d_in[12];
    const float* ee_b2 = (const float*)d_in[13];
    const float* enc_bn1_g = (const float*)d_in[14];
    const float* enc_bn1_b = (const float*)d_in[15];
    const float* enc_bn2_g = (const float*)d_in[16];
    const float* enc_bn2_b = (const float*)d_in[17];
    const float* ee_bn1_g = (const float*)d_in[18];
    const float* ee_bn1_b = (const float*)d_in[19];
    const float* ee_bn2_g = (const float*)d_in[20];
    const float* ee_bn2_b = (const float*)d_in[21];
    const float* l0_Wnode = (const float*)d_in[22];
    const float* l0_bnode = (const float*)d_in[23];
    const float* l0_Wni = (const float*)d_in[24];
    const float* l0_Wnj = (const float*)d_in[25];
    const float* l0_Wfij = (const float*)d_in[26];
    const float* l0_attn = (const float*)d_in[27];
    const float* l0_bnn_g = (const float*)d_in[28];
    const float* l0_bnn_b = (const float*)d_in[29];
    const float* l0_bne_g = (const float*)d_in[30];
    const float* l0_bne_b = (const float*)d_in[31];
    const float* l0_Wpn = (const float*)d_in[32];
    const float* l0_bpn = (const float*)d_in[33];
    const float* l0_Wpe = (const float*)d_in[34];
    const float* l0_bpe = (const float*)d_in[35];
    const float* l1_Wnode = (const float*)d_in[36];
    const float* l1_bnode = (const float*)d_in[37];
    const float* l1_Wni = (const float*)d_in[38];
    const float* l1_Wnj = (const float*)d_in[39];
    const float* l1_Wfij = (const float*)d_in[40];
    const float* l1_attn = (const float*)d_in[41];
    const float* l1_bnn_g = (const float*)d_in[42];
    const float* l1_bnn_b = (const float*)d_in[43];
    const float* l1_Wpn = (const float*)d_in[46];
    const float* l1_bpn = (const float*)d_in[47];
    const float* dec_W = (const float*)d_in[50];
    const float* dec_b = (const float*)d_in[51];
    const float* dec_bn_g = (const float*)d_in[52];
    const float* dec_bn_b = (const float*)d_in[53];
    const float* dec_prelu = (const float*)d_in[54];
    const float* dec_Wout = (const float*)d_in[55];
    const float* dec_bout = (const float*)d_in[56];

    float* out = (float*)d_out;
    float* H1 = out;                     // N x 64 (fp32)
    float* H2 = out + (long)NN * 64;     // N x 64 (fp32)
    float* POOL = out + (long)NN * 128;  // G x 1 (fp32)

    char* base = (char*)d_ws;
    size_t off = 0;
    auto alloc = [&](size_t bytes) -> void* {
        off = (off + 255) & ~(size_t)255;
        void* p = base + off;
        off += bytes;
        return p;
    };
    u16* EH = (u16*)alloc((size_t)NE * 64 * 2);
    u16* F128 = (u16*)alloc((size_t)NE * 128 * 2);
    float* EATT = (float*)alloc((size_t)NE * 2 * 4);
    u16* NX = (u16*)alloc((size_t)NN * 64 * 2);
    u16* NI = (u16*)alloc((size_t)NN * 128 * 2);
    u16* NJ = (u16*)alloc((size_t)NN * 128 * 2);
    u16* NHH = (u16*)alloc((size_t)NN * 128 * 2);
    float* HOUT0 = (float*)alloc((size_t)NN * 128 * 4);
    float* HOUT1 = (float*)alloc((size_t)NN * 64 * 4);
    int* ROWPTR = (int*)alloc((size_t)(NN + 1) * 4);
    int* CURS = (int*)alloc((size_t)NN * 4);
    int* EPOS = (int*)alloc((size_t)NE * 4);
    int* ESRC = (int*)alloc((size_t)NE * 4);
    float* RWrot = (float*)alloc(256 * 4);
    float* RWref = (float*)alloc(256 * 4);
    float* STATS = (float*)alloc((size_t)13 * 256 * 4);
    char* zstart = base + ((off + 255) & ~(size_t)255);
    int* DEG = (int*)alloc((size_t)NN * 4);
    float* STATS_RAW = (float*)alloc((size_t)13 * NSLOT * 256 * 4);
    float* RAWEF = (float*)alloc((size_t)NSLOT * 16 * 4);
    char* zend = base + off;
    if (ws_size < off) return;

    u16* T2 = F128 + (size_t)NE * 64;  // NE x 64 bf16
    u16* NX0 = F128;                   // NN x 64 bf16 (node-enc temp)
    u16* NT = F128 + (size_t)NN * 64;  // NN x 64 bf16 (node-enc temp)
    u16* DT0 = NI;
    u16* DT1 = NJ;

    auto RAW = [&](int idx) { return STATS_RAW + (size_t)idx * NSLOT * 256; };
    float* S_enc1 = STATS + 0 * 256;
    float* S_enc2 = STATS + 1 * 256;
    float* S_ee1r = STATS + 2 * 256;
    float* S_ee2r = STATS + 3 * 256;
    float* S_ee1f = STATS + 4 * 256;
    float* S_ee2f = STATS + 5 * 256;
    float* S_bnn0 = STATS + 6 * 256;
    float* S_bne0 = STATS + 7 * 256;
    float* S_bnn1 = STATS + 8 * 256;
    float* S_d0 = STATS + 9 * 256;
    float* S_d1 = STATS + 10 * 256;
    float* S_d2 = STATS + 11 * 256;
    float* S_d3 = STATS + 12 * 256;

    const float invN = 1.f / (float)NN;
    const float invE = 1.f / (float)NE;
    const int GS = 640;

    hipMemsetAsync(zstart, 0, (size_t)(zend - zstart), stream);
    hipMemsetAsync(POOL, 0, (size_t)NG * 4, stream);

    setup_kernel<<<1, 64, 0, stream>>>(ang_rot, ang_ref, ee_W1, RWrot, RWref);

    // ---- CSR build (dst-sorted; shared by both layers) ----
    hist_kernel<<<(NE + 255) / 256, 256, 0, stream>>>(dst, NE, DEG);
    scan_kernel<<<1, 1024, 0, stream>>>(DEG, ROWPTR, CURS, NN);
    fill_kernel<<<(NE + 255) / 256, 256, 0, stream>>>(src, dst, NE, CURS, EPOS, ESRC);

    // ---- node encoder ----
    gather_emb_kernel<<<(NN * 8 + 255) / 256, 256, 0, stream>>>(ntype, emb, NX0, NN);
    colstats_kernel<64, true><<<GS, 256, 0, stream>>>(NX0, NN, RAW(0));
    finalize_stats_kernel<<<1, 256, 0, stream>>>(RAW(0), S_enc1, 128);
    mm_kernel<64, 64, true, false, true, true><<<(NN + 15) / 16, 256, 0, stream>>>(
        NX0, enc_W, enc_b, nullptr, NT, NN, 2, S_enc1, enc_bn1_g, enc_bn1_b, invN, nullptr, 0,
        RAW(1));
    finalize_stats_kernel<<<1, 256, 0, stream>>>(RAW(1), S_enc2, 128);
    bn_act_kernel<<<(NN * 8 + 255) / 256, 256, 0, stream>>>(NT, NX, NN, 64, S_enc2, enc_bn2_g,
                                                            enc_bn2_b, invN, 0);

    // ---- edge encoder (T1 eliminated: analytic stats + fused recompute) ----
    efstats_kernel<<<256, 256, 0, stream>>>(efeats, NE, RAWEF);
    ee_stats_kernel<<<1, 128, 0, stream>>>(RAWEF, RWrot, RWref, ee_b1, S_ee1r, S_ee1f, NE);
    for (int br = 0; br < 2; ++br) {
        const float* RW = br ? RWref : RWrot;
        float* S1 = br ? S_ee1f : S_ee1r;
        float* S2 = br ? S_ee2f : S_ee2r;
        int r2 = br ? 5 : 3;
        ee_mm_kernel<<<(NE + 15) / 16, 256, 0, stream>>>(efeats, RW, ee_b1, ee_W2, ee_b2, T2, NE,
                                                         S1, ee_bn1_g, ee_bn1_b, invE, RAW(r2));
        finalize_stats_kernel<<<1, 256, 0, stream>>>(RAW(r2), S2, 128);
        bn_act_kernel<<<(NE * 8 + 255) / 256, 256, 0, stream>>>(T2, EH, NE, 64, S2, ee_bn2_g,
                                                                ee_bn2_b, invE, br);
    }

    // ---- layer 0 (H=2) ----
    mm_kernel<64, 128, true, false, true, false><<<(NN + 7) / 8, 256, 0, stream>>>(
        NX, l0_Wni, nullptr, nullptr, NI, NN, 0, nullptr, nullptr, nullptr, 0.f, nullptr, 0,
        nullptr);
    mm_kernel<64, 128, true, false, true, false><<<(NN + 7) / 8, 256, 0, stream>>>(
        NX, l0_Wnj, nullptr, nullptr, NJ, NN, 0, nullptr, nullptr, nullptr, 0.f, nullptr, 0,
        nullptr);
    mm_kernel<64, 128, true, false, true, false><<<(NN + 7) / 8, 256, 0, stream>>>(
        NX, l0_Wnode, l0_bnode, nullptr, NHH, NN, 0, nullptr, nullptr, nullptr, 0.f, nullptr, 0,
        nullptr);
    egat_fe_kernel<128, true><<<(NE + 15) / 16, 256, 0, stream>>>(
        EH, l0_Wfij, NI, NJ, src, dst, EPOS, l0_attn, F128, EATT, NE);
    csr_aggregate_kernel<128><<<(NN + 3) / 4, 256, 0, stream>>>(ROWPTR, ESRC, EATT, NHH, HOUT0,
                                                                NN);
    colstats_kernel<128, false><<<GS, 256, 0, stream>>>(HOUT0, NN, RAW(6));
    finalize_stats_kernel<<<1, 256, 0, stream>>>(RAW(6), S_bnn0, 256);
    colstats_kernel<128, true><<<GS, 256, 0, stream>>>(F128, NE, RAW(7));
    finalize_stats_kernel<<<1, 256, 0, stream>>>(RAW(7), S_bne0, 256);
    mm_kernel<128, 64, false, true, false, false><<<(NN + 15) / 16, 256, 0, stream>>>(
        HOUT0, l0_Wpn, l0_bpn, NX, H1, NN, 1, S_bnn0, l0_bnn_g, l0_bnn_b, invN, nullptr, 0,
        nullptr);
    mm_kernel<128, 64, true, true, true, false><<<(NE + 15) / 16, 256, 0, stream>>>(
        F128, l0_Wpe, l0_bpe, EH, EH, NE, 1, S_bne0, l0_bne_g, l0_bne_b, invE, nullptr, 0,
        nullptr);

    // ---- layer 1 (H=1; edge output dead -> skipped) ----
    mm_kernel<64, 64, false, false, true, false><<<(NN + 15) / 16, 256, 0, stream>>>(
        H1, l1_Wni, nullptr, nullptr, NI, NN, 0, nullptr, nullptr, nullptr, 0.f, nullptr, 0,
        nullptr);
    mm_kernel<64, 64, false, false, true, false><<<(NN + 15) / 16, 256, 0, stream>>>(
        H1, l1_Wnj, nullptr, nullptr, NJ, NN, 0, nullptr, nullptr, nullptr, 0.f, nullptr, 0,
        nullptr);
    mm_kernel<64, 64, false, false, true, false><<<(NN + 15) / 16, 256, 0, stream>>>(
        H1, l1_Wnode, l1_bnode, nullptr, NHH, NN, 0, nullptr, nullptr, nullptr, 0.f, nullptr, 0,
        nullptr);
    egat_fe_kernel<64, false><<<(NE + 31) / 32, 256, 0, stream>>>(
        EH, l1_Wfij, NI, NJ, src, dst, EPOS, l1_attn, nullptr, EATT, NE);
    csr_aggregate_kernel<64><<<(NN + 7) / 8, 256, 0, stream>>>(ROWPTR, ESRC, EATT, NHH, HOUT1,
                                                               NN);
    colstats_kernel<64, false><<<GS, 256, 0, stream>>>(HOUT1, NN, RAW(8));
    finalize_stats_kernel<<<1, 256, 0, stream>>>(RAW(8), S_bnn1, 128);
    mm_kernel<64, 64, false, false, false, false><<<(NN + 15) / 16, 256, 0, stream>>>(
        HOUT1, l1_Wpn, l1_bpn, H1, H2, NN, 1, S_bnn1, l1_bnn_g, l1_bnn_b, invN, nullptr, 0,
        nullptr);

    // ---- decoder ----
    mm_kernel<64, 64, false, false, true, true><<<(NN + 15) / 16, 256, 0, stream>>>(
        H2, dec_W, dec_b, nullptr, DT0, NN, 0, nullptr, nullptr, nullptr, 0.f, nullptr, 0, RAW(9));
    finalize_stats_kernel<<<1, 256, 0, stream>>>(RAW(9), S_d0, 128);
    mm_kernel<64, 64, true, false, true, true><<<(NN + 15) / 16, 256, 0, stream>>>(
        DT0, dec_W + 4096, dec_b + 64, nullptr, DT1, NN, 3, S_d0, dec_bn_g, dec_bn_b, invN,
        dec_prelu, 0, RAW(10));
    finalize_stats_kernel<<<1, 256, 0, stream>>>(RAW(10), S_d1, 128);
    mm_kernel<64, 64, true, false, true, true><<<(NN + 15) / 16, 256, 0, stream>>>(
        DT1, dec_W + 8192, dec_b + 128, nullptr, DT0, NN, 3, S_d1, dec_bn_g + 64, dec_bn_b + 64,
        invN, dec_prelu, 1, RAW(11));
    finalize_stats_kernel<<<1, 256, 0, stream>>>(RAW(11), S_d2, 128);
    mm_kernel<64, 64, true, false, true, true><<<(NN + 15) / 16, 256, 0, stream>>>(
        DT0, dec_W + 12288, dec_b + 192, nullptr, DT1, NN, 3, S_d2, dec_bn_g + 128,
        dec_bn_b + 128, invN, dec_prelu, 2, RAW(12));
    finalize_stats_kernel<<<1, 256, 0, stream>>>(RAW(12), S_d3, 128);
    decoder_out_kernel<<<(NN + 3) / 4, 256, 0, stream>>>(DT1, S_d3, dec_bn_g + 192,
                                                         dec_bn_b + 192, dec_prelu, dec_Wout,
                                                         dec_bout, gid, POOL, NN, invN);
}

// Round 6
// 1111.299 us; speedup vs baseline: 1.6450x; 1.3824x over previous
//
#include <hip/hip_runtime.h>
#include <math.h>

#define NN 50000
#define NE 400000
#define NG 512
#define EPS 1e-5f
#define NSLOT 256  // stats replica slots (atomic contention spreading)

typedef unsigned int u32;
typedef unsigned short u16;

typedef __attribute__((ext_vector_type(8))) short s16x8;  // 8 bf16 (4 VGPRs)
typedef __attribute__((ext_vector_type(4))) float f32x4;

__device__ __forceinline__ float b2f(u16 h) { return __uint_as_float(((u32)h) << 16); }
__device__ __forceinline__ u16 f2b(float f) {
    u32 x = __float_as_uint(f);
    u32 r = x + 0x7fffu + ((x >> 16) & 1u);
    return (u16)(r >> 16);
}
struct alignas(16) U16x8 { u16 s[8]; };
struct alignas(8) U16x4 { u16 s[4]; };
struct alignas(4) U16x2 { u16 s[2]; };

__device__ __forceinline__ void f4add(float4& a, const float4 b) {
    a.x += b.x; a.y += b.y; a.z += b.z; a.w += b.w;
}

// ---------------- setup: fold rotation matrices into ee_W1 (fp32) ----------------
__global__ void setup_kernel(const float* __restrict__ ang_rot, const float* __restrict__ ang_ref,
                             const float* __restrict__ W1, float* __restrict__ RWrot,
                             float* __restrict__ RWref) {
    int c = threadIdx.x;  // 64
    for (int which = 0; which < 2; ++which) {
        const float* a = which ? ang_ref : ang_rot;
        float t = a[0], p = a[1], q = a[2];
        float ct = cosf(t), st = sinf(t);
        float cp = cosf(p), sp = sinf(p);
        float cq = cosf(q), sq = sinf(q);
        float Rt[3][3] = {{ct, -st, 0.f}, {st, ct, 0.f}, {0.f, 0.f, 1.f}};
        float Rp[3][3] = {{cp, 0.f, -sp}, {0.f, 1.f, 0.f}, {sp, 0.f, cp}};
        float Rq[3][3] = {{1.f, 0.f, 0.f}, {0.f, cq, -sq}, {0.f, sq, cq}};
        float Rtp[3][3], R[3][3];
        for (int i = 0; i < 3; ++i)
            for (int j = 0; j < 3; ++j) {
                float s = 0.f;
                for (int k = 0; k < 3; ++k) s += Rt[i][k] * Rp[k][j];
                Rtp[i][j] = s;
            }
        for (int i = 0; i < 3; ++i)
            for (int j = 0; j < 3; ++j) {
                float s = 0.f;
                for (int k = 0; k < 3; ++k) s += Rtp[i][k] * Rq[k][j];
                R[i][j] = s;
            }
        float sgn = which ? -1.f : 1.f;  // R_ref = -rotmat(angles_ref)
        float* RW = which ? RWref : RWrot;
        if (c < 64) {
            for (int j = 0; j < 3; ++j) {
                float s = 0.f;
                for (int m = 0; m < 3; ++m) s += sgn * R[j][m] * W1[m * 64 + c];
                RW[j * 64 + c] = s;  // RW = R @ W1  (3 x 64)
            }
        }
    }
}

// ---------------- W [K][C] fp32 -> WT [C][K] bf16 ----------------
__global__ __launch_bounds__(256) void wt_kernel(const float* __restrict__ W,
                                                 u16* __restrict__ WT, int K, int C) {
    int i = blockIdx.x * 256 + threadIdx.x;
    if (i >= K * C) return;
    int k = i / C, c = i - k * C;
    WT[c * K + k] = f2b(W[i]);
}

// ---------------- CSR build: degree hist -> scan -> fill ----------------
__global__ __launch_bounds__(256) void hist_kernel(const int* __restrict__ dst, int E,
                                                   int* __restrict__ deg) {
    int e = blockIdx.x * 256 + threadIdx.x;
    if (e < E) atomicAdd(&deg[dst[e]], 1);
}

__global__ __launch_bounds__(1024) void scan_kernel(const int* __restrict__ deg,
                                                    int* __restrict__ rowptr,
                                                    int* __restrict__ curs, int n) {
    __shared__ int part[1024];
    int tid = threadIdx.x;
    const int CHUNK = (n + 1023) / 1024;
    int s0 = tid * CHUNK;
    int sum = 0;
    for (int i = 0; i < CHUNK; ++i) {
        int idx = s0 + i;
        if (idx < n) sum += deg[idx];
    }
    part[tid] = sum;
    __syncthreads();
    for (int off = 1; off < 1024; off <<= 1) {
        int v = (tid >= off) ? part[tid - off] : 0;
        __syncthreads();
        part[tid] += v;
        __syncthreads();
    }
    int run = (tid == 0) ? 0 : part[tid - 1];
    for (int i = 0; i < CHUNK; ++i) {
        int idx = s0 + i;
        if (idx < n) {
            rowptr[idx] = run;
            curs[idx] = run;
            run += deg[idx];
        }
    }
    if (tid == 1023) rowptr[n] = run;
}

__global__ __launch_bounds__(256) void fill_kernel(const int* __restrict__ src,
                                                   const int* __restrict__ dst, int E,
                                                   int* __restrict__ curs,
                                                   int* __restrict__ epos,
                                                   int* __restrict__ esrc) {
    int e = blockIdx.x * 256 + threadIdx.x;
    if (e >= E) return;
    int pos = atomicAdd(&curs[dst[e]], 1);
    epos[e] = pos;
    esrc[pos] = src[e];
}

// ---------------- embedding gather: fp32 table -> bf16 out ----------------
__global__ __launch_bounds__(256) void gather_emb_kernel(const int* __restrict__ ntype,
                                                         const float* __restrict__ emb,
                                                         u16* __restrict__ out, int n) {
    long i = (long)blockIdx.x * 256 + threadIdx.x;  // over n*8
    long e = i >> 3;
    if (e >= n) return;
    int c0 = (int)(i & 7) * 8;
    int t = ntype[e];
    float4 a = *(const float4*)&emb[(long)t * 64 + c0];
    float4 b = *(const float4*)&emb[(long)t * 64 + c0 + 4];
    U16x8 o;
    o.s[0] = f2b(a.x); o.s[1] = f2b(a.y); o.s[2] = f2b(a.z); o.s[3] = f2b(a.w);
    o.s[4] = f2b(b.x); o.s[5] = f2b(b.y); o.s[6] = f2b(b.z); o.s[7] = f2b(b.w);
    *(U16x8*)&out[e * 64 + c0] = o;
}

// ---------------- efeats second moments: 9 scalars -> replica slots ----------------
__global__ __launch_bounds__(256) void efstats_kernel(const float* __restrict__ ef, int E,
                                                      float* __restrict__ raw) {
    int tid = threadIdx.x;
    float a[9];
#pragma unroll
    for (int j = 0; j < 9; ++j) a[j] = 0.f;
    for (long e = (long)blockIdx.x * 256 + tid; e < E; e += (long)gridDim.x * 256) {
        float f0 = ef[e * 3 + 0], f1 = ef[e * 3 + 1], f2 = ef[e * 3 + 2];
        a[0] += f0; a[1] += f1; a[2] += f2;
        a[3] += f0 * f0; a[4] += f1 * f1; a[5] += f2 * f2;
        a[6] += f0 * f1; a[7] += f0 * f2; a[8] += f1 * f2;
    }
#pragma unroll
    for (int off = 1; off < 64; off <<= 1)
#pragma unroll
        for (int j = 0; j < 9; ++j) a[j] += __shfl_xor(a[j], off, 64);
    __shared__ float sred[4][9];
    int wv = tid >> 6, ln = tid & 63;
    if (ln == 0)
#pragma unroll
        for (int j = 0; j < 9; ++j) sred[wv][j] = a[j];
    __syncthreads();
    if (tid < 9) {
        float v = sred[0][tid] + sred[1][tid] + sred[2][tid] + sred[3][tid];
        atomicAdd(&raw[(size_t)(blockIdx.x & (NSLOT - 1)) * 16 + tid], v);
    }
}

// ---------------- analytic T1 column stats for both branches ----------------
__global__ void ee_stats_kernel(const float* __restrict__ efraw, const float* __restrict__ RWrot,
                                const float* __restrict__ RWref, const float* __restrict__ b1,
                                float* __restrict__ S_rot, float* __restrict__ S_ref, int E) {
    __shared__ float m[9];
    int t = threadIdx.x;  // 128
    if (t < 9) {
        float s = 0.f;
        for (int r = 0; r < NSLOT; ++r) s += efraw[r * 16 + t];
        m[t] = s;
    }
    __syncthreads();
    int br = t >> 6, c = t & 63;
    const float* RW = br ? RWref : RWrot;
    float* S = br ? S_ref : S_rot;
    float w0 = RW[c], w1 = RW[64 + c], w2 = RW[128 + c];
    float bb = b1[c];
    float mw = m[0] * w0 + m[1] * w1 + m[2] * w2;
    float sum = mw + (float)E * bb;
    float quad = m[3] * w0 * w0 + m[4] * w1 * w1 + m[5] * w2 * w2 +
                 2.f * (m[6] * w0 * w1 + m[7] * w0 * w2 + m[8] * w1 * w2);
    float ss = quad + 2.f * bb * mw + (float)E * bb * bb;
    S[c] = sum;
    S[64 + c] = ss;
}

// ---------------- column stats -> replicated raw accumulators ----------------
template <int COLS, bool XBF>
__global__ __launch_bounds__(256) void colstats_kernel(const void* __restrict__ xv, int rows,
                                                       float* __restrict__ raw) {
    constexpr int TPR = COLS / 8;
    constexpr int RPB = 256 / TPR;
    __shared__ float4 sA[256], sB[256], sC[256], sD[256];
    int tid = threadIdx.x;
    int c8 = tid % TPR;
    int rl = tid / TPR;
    float s[8], q[8];
#pragma unroll
    for (int j = 0; j < 8; ++j) { s[j] = 0.f; q[j] = 0.f; }
    const long stride = (long)gridDim.x * RPB;
    long r = (long)blockIdx.x * RPB + rl;
    auto loadrow = [&](long rr, float* v) {
        if (XBF) {
            U16x8 t = *(const U16x8*)((const u16*)xv + rr * COLS + c8 * 8);
#pragma unroll
            for (int j = 0; j < 8; ++j) v[j] = b2f(t.s[j]);
        } else {
            float4 a = *(const float4*)((const float*)xv + rr * COLS + c8 * 8);
            float4 b = *(const float4*)((const float*)xv + rr * COLS + c8 * 8 + 4);
            v[0] = a.x; v[1] = a.y; v[2] = a.z; v[3] = a.w;
            v[4] = b.x; v[5] = b.y; v[6] = b.z; v[7] = b.w;
        }
    };
    for (; r + stride < rows; r += 2 * stride) {
        float v0[8], v1[8];
        loadrow(r, v0);
        loadrow(r + stride, v1);
#pragma unroll
        for (int j = 0; j < 8; ++j) {
            s[j] += v0[j] + v1[j];
            q[j] += v0[j] * v0[j] + v1[j] * v1[j];
        }
    }
    if (r < rows) {
        float v0[8];
        loadrow(r, v0);
#pragma unroll
        for (int j = 0; j < 8; ++j) { s[j] += v0[j]; q[j] += v0[j] * v0[j]; }
    }
    sA[tid] = make_float4(s[0], s[1], s[2], s[3]);
    sB[tid] = make_float4(s[4], s[5], s[6], s[7]);
    sC[tid] = make_float4(q[0], q[1], q[2], q[3]);
    sD[tid] = make_float4(q[4], q[5], q[6], q[7]);
    __syncthreads();
    for (int off = 128; off >= TPR; off >>= 1) {
        if (tid < off) {
            f4add(sA[tid], sA[tid + off]); f4add(sB[tid], sB[tid + off]);
            f4add(sC[tid], sC[tid + off]); f4add(sD[tid], sD[tid + off]);
        }
        __syncthreads();
    }
    if (tid < TPR) {
        float* slot = raw + (size_t)(blockIdx.x & (NSLOT - 1)) * 256;
        int c = tid * 8;
        float4 a = sA[tid], b = sB[tid], cq = sC[tid], d = sD[tid];
        atomicAdd(&slot[c + 0], a.x); atomicAdd(&slot[c + 1], a.y);
        atomicAdd(&slot[c + 2], a.z); atomicAdd(&slot[c + 3], a.w);
        atomicAdd(&slot[c + 4], b.x); atomicAdd(&slot[c + 5], b.y);
        atomicAdd(&slot[c + 6], b.z); atomicAdd(&slot[c + 7], b.w);
        atomicAdd(&slot[COLS + c + 0], cq.x); atomicAdd(&slot[COLS + c + 1], cq.y);
        atomicAdd(&slot[COLS + c + 2], cq.z); atomicAdd(&slot[COLS + c + 3], cq.w);
        atomicAdd(&slot[COLS + c + 4], d.x); atomicAdd(&slot[COLS + c + 5], d.y);
        atomicAdd(&slot[COLS + c + 6], d.z); atomicAdd(&slot[COLS + c + 7], d.w);
    }
}

// ---------------- reduce NSLOT replica slots -> final stats ----------------
__global__ __launch_bounds__(256) void finalize_stats_kernel(const float* __restrict__ raw,
                                                             float* __restrict__ stats, int n) {
    int i = threadIdx.x;
    if (i >= n) return;
    float s = 0.f;
    for (int r = 0; r < NSLOT; ++r) s += raw[r * 256 + i];
    stats[i] = s;
}

// ---------------- elementwise y = relu(bn(x)) [+= y], bf16 x/y ----------------
__global__ __launch_bounds__(256) void bn_act_kernel(const u16* __restrict__ x,
                                                     u16* __restrict__ y, long rows, int cols,
                                                     const float* __restrict__ acc,
                                                     const float* __restrict__ g,
                                                     const float* __restrict__ b, float inv_rows,
                                                     int accumulate) {
    long i = (long)blockIdx.x * 256 + threadIdx.x;
    long total8 = rows * (long)cols / 8;
    if (i >= total8) return;
    long base = i * 8;
    int c0 = (int)(base % cols);
    U16x8 xv = *(const U16x8*)&x[base];
    float r[8];
#pragma unroll
    for (int j = 0; j < 8; ++j) {
        int c = c0 + j;
        float mu = acc[c] * inv_rows;
        float var = acc[cols + c] * inv_rows - mu * mu;
        float al = g[c] * rsqrtf(fmaxf(var, 0.f) + EPS);
        float be = b[c] - mu * al;
        float o = al * b2f(xv.s[j]) + be;
        r[j] = fmaxf(o, 0.f);
    }
    if (accumulate) {
        U16x8 yv = *(const U16x8*)&y[base];
#pragma unroll
        for (int j = 0; j < 8; ++j) r[j] += b2f(yv.s[j]);
    }
    U16x8 o;
#pragma unroll
    for (int j = 0; j < 8; ++j) o.s[j] = f2b(r[j]);
    *(U16x8*)&y[base] = o;
}

// ---------------- generic tiled matmul (fp32 VALU; NN-scale only) ----------------
template <int K, int COLS, bool XBF, bool RBF, bool OBF, bool SOUT>
__global__ __launch_bounds__(256) void mm_kernel(const void* __restrict__ Xv,
                                                 const float* __restrict__ Wg,
                                                 const float* __restrict__ bias, const void* resv,
                                                 void* Yv, int rows, int preop,
                                                 const float* __restrict__ stats,
                                                 const float* __restrict__ g,
                                                 const float* __restrict__ b, float inv_rows,
                                                 const float* __restrict__ prelu, int prelu_idx,
                                                 float* __restrict__ raw) {
    constexpr int TPR = COLS / 4;
    constexpr int RPB = 256 / TPR;
    constexpr int XP = K + 4;
    __shared__ float ws[K * COLS];
    __shared__ float xs[RPB * XP];
    __shared__ float al[K];
    __shared__ float be[K];
    const int tid = threadIdx.x;

    for (int i = tid; i < K * COLS; i += 256) ws[i] = Wg[i];
    if (preop) {
        for (int k = tid; k < K; k += 256) {
            float mu = stats[k] * inv_rows;
            float var = stats[K + k] * inv_rows - mu * mu;
            float a = g[k] * rsqrtf(fmaxf(var, 0.f) + EPS);
            al[k] = a;
            be[k] = b[k] - mu * a;
        }
    }
    __syncthreads();

    const long r0 = (long)blockIdx.x * RPB;
    float pa = (preop == 3) ? prelu[prelu_idx] : 0.f;
    constexpr int NC = RPB * K / 4;
    for (int i = tid; i < NC; i += 256) {
        int b4 = i * 4;
        int rl = b4 / K, k0 = b4 % K;
        long r = r0 + rl;
        float v[4];
        if (r < rows) {
            if (XBF) {
                U16x4 t = *(const U16x4*)((const u16*)Xv + r * K + k0);
#pragma unroll
                for (int j = 0; j < 4; ++j) v[j] = b2f(t.s[j]);
            } else {
                float4 t = *(const float4*)((const float*)Xv + r * K + k0);
                v[0] = t.x; v[1] = t.y; v[2] = t.z; v[3] = t.w;
            }
        } else {
#pragma unroll
            for (int j = 0; j < 4; ++j) v[j] = 0.f;
        }
        if (preop) {
#pragma unroll
            for (int j = 0; j < 4; ++j) {
                float xx = al[k0 + j] * v[j] + be[k0 + j];
                if (preop == 2) xx = fmaxf(xx, 0.f);
                else if (preop == 3) xx = (xx >= 0.f) ? xx : pa * xx;
                v[j] = xx;
            }
        }
        xs[rl * XP + k0 + 0] = v[0];
        xs[rl * XP + k0 + 1] = v[1];
        xs[rl * XP + k0 + 2] = v[2];
        xs[rl * XP + k0 + 3] = v[3];
    }
    __syncthreads();

    const int rl = tid / TPR;
    const int c0 = (tid % TPR) * 4;
    float4 acc = {0.f, 0.f, 0.f, 0.f};
#pragma unroll
    for (int k = 0; k < K; k += 4) {
        float4 xv = *(const float4*)&xs[rl * XP + k];
#pragma unroll
        for (int j = 0; j < 4; ++j) {
            float xj = (&xv.x)[j];
            float4 wv = *(const float4*)&ws[(k + j) * COLS + c0];
            acc.x += xj * wv.x; acc.y += xj * wv.y;
            acc.z += xj * wv.z; acc.w += xj * wv.w;
        }
    }
    long r = r0 + rl;
    if (r < rows) {
        if (bias) f4add(acc, *(const float4*)&bias[c0]);
        if (resv) {
            if (RBF) {
                U16x4 t = *(const U16x4*)((const u16*)resv + r * COLS + c0);
                acc.x += b2f(t.s[0]); acc.y += b2f(t.s[1]);
                acc.z += b2f(t.s[2]); acc.w += b2f(t.s[3]);
            } else {
                f4add(acc, *(const float4*)((const float*)resv + r * COLS + c0));
            }
        }
        if (OBF) {
            U16x4 o;
            o.s[0] = f2b(acc.x); o.s[1] = f2b(acc.y);
            o.s[2] = f2b(acc.z); o.s[3] = f2b(acc.w);
            *(U16x4*)((u16*)Yv + r * COLS + c0) = o;
        } else {
            *(float4*)((float*)Yv + r * COLS + c0) = acc;
        }
    }
    if constexpr (SOUT) {
        __syncthreads();
        float4 va = (r < rows) ? acc : make_float4(0.f, 0.f, 0.f, 0.f);
        *(float4*)&ws[rl * COLS + c0] = va;
        float4 vq = make_float4(va.x * va.x, va.y * va.y, va.z * va.z, va.w * va.w);
        *(float4*)&ws[RPB * COLS + rl * COLS + c0] = vq;
        __syncthreads();
        for (int off2 = RPB / 2; off2 >= 1; off2 >>= 1) {
            if (rl < off2) {
                float4 x1 = *(float4*)&ws[rl * COLS + c0];
                f4add(x1, *(const float4*)&ws[(rl + off2) * COLS + c0]);
                *(float4*)&ws[rl * COLS + c0] = x1;
                float4 x2 = *(float4*)&ws[RPB * COLS + rl * COLS + c0];
                f4add(x2, *(const float4*)&ws[RPB * COLS + (rl + off2) * COLS + c0]);
                *(float4*)&ws[RPB * COLS + rl * COLS + c0] = x2;
            }
            __syncthreads();
        }
        if (rl == 0) {
            float* slot = raw + (size_t)(blockIdx.x & (NSLOT - 1)) * 256;
#pragma unroll
            for (int j = 0; j < 4; ++j) {
                atomicAdd(&slot[c0 + j], ws[c0 + j]);
                atomicAdd(&slot[COLS + c0 + j], ws[RPB * COLS + c0 + j]);
            }
        }
    }
}

// ================= MFMA kernels (NE-scale matmuls) =================
// Fragment layout (guide §3, m89/m91/m92 verified):
//   A: lane l holds A[row=l&15][k=(l>>4)*8+j]  (8 contiguous bf16 from X row)
//   B: lane l holds B[k=(l>>4)*8+j][col=l&15]  (8 contiguous bf16 from W^T row)
//   D: lane l reg r holds D[row=(l>>4)*4+r][col=l&15]
// Per wave: one 16-row tile; block = 4 waves = 64 rows. NE/64 = 6250 exact.

// ---- T2 = relu(bn1(ef@RW + b1)) @ W2 + b2 (T1 generated in-register) + col-stats ----
__global__ __launch_bounds__(256) void mfma_ee_kernel(
    const float* __restrict__ ef, const float* __restrict__ RW, const float* __restrict__ b1v,
    const u16* __restrict__ W2T, const float* __restrict__ b2, u16* __restrict__ T2, int E,
    const float* __restrict__ stats, const float* __restrict__ g, const float* __restrict__ b,
    float inv_rows, float* __restrict__ raw) {
    __shared__ float rws[192];
    __shared__ float al[64], be[64];
    __shared__ float ssum[64], ssq[64];
    const int tid = threadIdx.x;
    if (tid < 192) rws[tid] = RW[tid];
    if (tid < 64) {
        float mu = stats[tid] * inv_rows;
        float var = stats[64 + tid] * inv_rows - mu * mu;
        float a = g[tid] * rsqrtf(fmaxf(var, 0.f) + EPS);
        al[tid] = a;
        be[tid] = b[tid] - mu * a + a * b1v[tid];  // fold b1 into affine
        ssum[tid] = 0.f;
        ssq[tid] = 0.f;
    }
    __syncthreads();
    const int lane = tid & 63, wv = tid >> 6;
    const int q = lane >> 4, rr = lane & 15;
    const long r0 = ((long)blockIdx.x * 4 + wv) * 16;
    const long ar = r0 + rr;
    float e0 = ef[ar * 3], e1 = ef[ar * 3 + 1], e2 = ef[ar * 3 + 2];
    s16x8 afr[2];
#pragma unroll
    for (int kk = 0; kk < 2; ++kk) {
        union { u16 u[8]; s16x8 v; } t;
#pragma unroll
        for (int j = 0; j < 8; ++j) {
            int k = kk * 32 + q * 8 + j;
            float tv = e0 * rws[k] + e1 * rws[64 + k] + e2 * rws[128 + k];
            t.u[j] = f2b(fmaxf(al[k] * tv + be[k], 0.f));
        }
        afr[kk] = t.v;
    }
    f32x4 acc[4];
#pragma unroll
    for (int ct = 0; ct < 4; ++ct) {
        acc[ct] = (f32x4){0.f, 0.f, 0.f, 0.f};
#pragma unroll
        for (int kk = 0; kk < 2; ++kk) {
            s16x8 bfr = *(const s16x8*)&W2T[(size_t)(ct * 16 + rr) * 64 + kk * 32 + q * 8];
            acc[ct] = __builtin_amdgcn_mfma_f32_16x16x32_bf16(afr[kk], bfr, acc[ct], 0, 0, 0);
        }
    }
#pragma unroll
    for (int ct = 0; ct < 4; ++ct) {
        int col = ct * 16 + rr;
        float bb = b2[col];
        float s = 0.f, qq = 0.f;
#pragma unroll
        for (int r = 0; r < 4; ++r) {
            long orr = r0 + q * 4 + r;
            float v = acc[ct][r] + bb;
            T2[orr * 64 + col] = f2b(v);
            s += v;
            qq += v * v;
        }
        // reduce across the 4 quarters (same col held by lanes differing in q)
        s += __shfl_xor(s, 16, 64); s += __shfl_xor(s, 32, 64);
        qq += __shfl_xor(qq, 16, 64); qq += __shfl_xor(qq, 32, 64);
        if (q == 0) {
            atomicAdd(&ssum[col], s);
            atomicAdd(&ssq[col], qq);
        }
    }
    __syncthreads();
    if (tid < 64) {
        float* slot = raw + (size_t)(blockIdx.x & (NSLOT - 1)) * 256;
        atomicAdd(&slot[tid], ssum[tid]);
        atomicAdd(&slot[64 + tid], ssq[tid]);
    }
}

// ---- f = leaky(EH@Wfij + NI[src] + NJ[dst]); att scores -> CSR slots ----
template <int COLS, bool WRITE_F>
__global__ __launch_bounds__(256) void mfma_egat_kernel(
    const u16* __restrict__ EH, const u16* __restrict__ WT, const u16* __restrict__ NI,
    const u16* __restrict__ NJ, const int* __restrict__ src, const int* __restrict__ dst,
    const int* __restrict__ epos, const float* __restrict__ attn, u16* __restrict__ Fout,
    float* __restrict__ eatt, int E) {
    constexpr int H = COLS / 64;
    constexpr int NCT = COLS / 16;
    const int tid = threadIdx.x;
    const int lane = tid & 63, wv = tid >> 6;
    const int q = lane >> 4, rr = lane & 15;
    const long r0 = ((long)blockIdx.x * 4 + wv) * 16;
    s16x8 afr[2];
#pragma unroll
    for (int kk = 0; kk < 2; ++kk)
        afr[kk] = *(const s16x8*)&EH[(r0 + rr) * 64 + kk * 32 + q * 8];
    int sidx[4], didx[4];
#pragma unroll
    for (int r = 0; r < 4; ++r) {
        long orr = r0 + q * 4 + r;
        sidx[r] = src[orr];
        didx[r] = dst[orr];
    }
    f32x4 acc[NCT];
#pragma unroll
    for (int ct = 0; ct < NCT; ++ct) {
        acc[ct] = (f32x4){0.f, 0.f, 0.f, 0.f};
#pragma unroll
        for (int kk = 0; kk < 2; ++kk) {
            s16x8 bfr = *(const s16x8*)&WT[(size_t)(ct * 16 + rr) * 64 + kk * 32 + q * 8];
            acc[ct] = __builtin_amdgcn_mfma_f32_16x16x32_bf16(afr[kk], bfr, acc[ct], 0, 0, 0);
        }
    }
    float part[H][4];
#pragma unroll
    for (int h = 0; h < H; ++h)
#pragma unroll
        for (int r = 0; r < 4; ++r) part[h][r] = 0.f;
#pragma unroll
    for (int ct = 0; ct < NCT; ++ct) {
        int col = ct * 16 + rr;
        float av = attn[col];
        const int h = (H == 2) ? (ct >> 2) : 0;
#pragma unroll
        for (int r = 0; r < 4; ++r) {
            long orr = r0 + q * 4 + r;
            float f = acc[ct][r] + b2f(NI[(size_t)sidx[r] * COLS + col]) +
                      b2f(NJ[(size_t)didx[r] * COLS + col]);
            f = (f >= 0.f) ? f : 0.01f * f;
            if (WRITE_F) Fout[orr * COLS + col] = f2b(f);
            part[h][r] += f * av;
        }
    }
#pragma unroll
    for (int h = 0; h < H; ++h)
#pragma unroll
        for (int r = 0; r < 4; ++r) {
            float p = part[h][r];
            p += __shfl_xor(p, 1, 64);
            p += __shfl_xor(p, 2, 64);
            p += __shfl_xor(p, 4, 64);
            p += __shfl_xor(p, 8, 64);
            part[h][r] = p;
        }
    if (rr == 0) {
#pragma unroll
        for (int r = 0; r < 4; ++r) {
            long pos = epos[r0 + q * 4 + r];
            if (H == 2) {
                eatt[pos * 2 + 0] = part[0][r];
                eatt[pos * 2 + 1] = part[1][r];
            } else {
                eatt[pos] = part[0][r];
            }
        }
    }
}

// ---- EH = bn(F128)@Wpe + bpe + EH (K=128, in-place residual) ----
__global__ __launch_bounds__(256) void mfma_pe_kernel(
    const u16* __restrict__ X, const u16* __restrict__ WT, const float* __restrict__ bias,
    u16* __restrict__ EHio, int E, const float* __restrict__ stats, const float* __restrict__ g,
    const float* __restrict__ b, float inv_rows) {
    __shared__ float al[128], be[128];
    const int tid = threadIdx.x;
    if (tid < 128) {
        float mu = stats[tid] * inv_rows;
        float var = stats[128 + tid] * inv_rows - mu * mu;
        float a = g[tid] * rsqrtf(fmaxf(var, 0.f) + EPS);
        al[tid] = a;
        be[tid] = b[tid] - mu * a;
    }
    __syncthreads();
    const int lane = tid & 63, wv = tid >> 6;
    const int q = lane >> 4, rr = lane & 15;
    const long r0 = ((long)blockIdx.x * 4 + wv) * 16;
    s16x8 afr[4];
#pragma unroll
    for (int kk = 0; kk < 4; ++kk) {
        U16x8 t = *(const U16x8*)&X[(r0 + rr) * 128 + kk * 32 + q * 8];
        union { u16 u[8]; s16x8 v; } o;
#pragma unroll
        for (int j = 0; j < 8; ++j) {
            int k = kk * 32 + q * 8 + j;
            o.u[j] = f2b(al[k] * b2f(t.s[j]) + be[k]);
        }
        afr[kk] = o.v;
    }
    f32x4 acc[4];
#pragma unroll
    for (int ct = 0; ct < 4; ++ct) {
        acc[ct] = (f32x4){0.f, 0.f, 0.f, 0.f};
#pragma unroll
        for (int kk = 0; kk < 4; ++kk) {
            s16x8 bfr = *(const s16x8*)&WT[(size_t)(ct * 16 + rr) * 128 + kk * 32 + q * 8];
            acc[ct] = __builtin_amdgcn_mfma_f32_16x16x32_bf16(afr[kk], bfr, acc[ct], 0, 0, 0);
        }
    }
#pragma unroll
    for (int ct = 0; ct < 4; ++ct) {
        int col = ct * 16 + rr;
        float bb = bias[col];
#pragma unroll
        for (int r = 0; r < 4; ++r) {
            long orr = r0 + q * 4 + r;
            float v = acc[ct][r] + bb + b2f(EHio[orr * 64 + col]);
            EHio[orr * 64 + col] = f2b(v);
        }
    }
}

// ---------------- CSR gather aggregate: per-node softmax + weighted sum ----------------
template <int COLS>
__global__ __launch_bounds__(256) void csr_aggregate_kernel(
    const int* __restrict__ rowptr, const int* __restrict__ esrc,
    const float* __restrict__ eatt, const u16* __restrict__ nodeh, float* __restrict__ hout,
    int n) {
    constexpr int H = COLS / 64;
    constexpr int TPN = COLS / 2;
    constexpr int NPB = 256 / TPN;
    int tid = threadIdx.x;
    int node = blockIdx.x * NPB + tid / TPN;
    if (node >= n) return;
    int c = (tid % TPN) * 2;
    int h = (H == 2) ? (c >> 6) : 0;
    int p0 = rowptr[node], p1 = rowptr[node + 1];
    float m = -INFINITY, s = 0.f;
    for (int p = p0; p < p1; ++p) {
        float v = eatt[(long)p * H + h];
        float mn = fmaxf(m, v);
        s = s * expf(m - mn) + expf(v - mn);
        m = mn;
    }
    float inv = (s > 0.f) ? 1.f / s : 0.f;
    float a0 = 0.f, a1 = 0.f;
    for (int p = p0; p < p1; ++p) {
        float w = expf(eatt[(long)p * H + h] - m) * inv;
        U16x2 v = *(const U16x2*)&nodeh[(long)esrc[p] * COLS + c];
        a0 += b2f(v.s[0]) * w;
        a1 += b2f(v.s[1]) * w;
    }
    *(float2*)&hout[(long)node * COLS + c] = make_float2(a0, a1);
}

// ---------------- decoder tail: prelu(bn(t3)) @ Wout + bout -> pool by graph ----------------
__global__ __launch_bounds__(256) void decoder_out_kernel(
    const u16* __restrict__ t3, const float* __restrict__ stats, const float* __restrict__ g,
    const float* __restrict__ b, const float* __restrict__ prelu, const float* __restrict__ Wout,
    const float* __restrict__ bout, const int* __restrict__ gid, float* __restrict__ pool,
    int rows, float inv_rows) {
    int tid = threadIdx.x;
    long r = (long)blockIdx.x * 4 + (tid >> 6);
    if (r >= rows) return;
    int k = tid & 63;
    float mu = stats[k] * inv_rows;
    float var = stats[64 + k] * inv_rows - mu * mu;
    float al = g[k] * rsqrtf(fmaxf(var, 0.f) + EPS);
    float be = b[k] - mu * al;
    float a = prelu[3];
    float v = al * b2f(t3[r * 64 + k]) + be;
    v = (v >= 0.f) ? v : a * v;
    v *= Wout[k];
#pragma unroll
    for (int off = 1; off < 64; off <<= 1) v += __shfl_xor(v, off, 64);
    if (k == 0) atomicAdd(&pool[gid[r]], v + bout[0]);
}

// =====================================================================================
extern "C" void kernel_launch(void* const* d_in, const int* in_sizes, int n_in, void* d_out,
                              int out_size, void* d_ws, size_t ws_size, hipStream_t stream) {
    if (n_in < 57) return;
    const int* ntype = (const int*)d_in[0];
    const int* src = (const int*)d_in[1];
    const int* dst = (const int*)d_in[2];
    const int* gid = (const int*)d_in[3];
    const float* ang_rot = (const float*)d_in[4];
    const float* ang_ref = (const float*)d_in[5];
    const float* efeats = (const float*)d_in[6];
    const float* emb = (const float*)d_in[7];
    const float* enc_W = (const float*)d_in[8];
    const float* enc_b = (const float*)d_in[9];
    const float* ee_W1 = (const float*)d_in[10];
    const float* ee_b1 = (const float*)d_in[11];
    const float* ee_W2 = (const float*)d_in[12];
    const float* ee_b2 = (const float*)d_in[13];
    const float* enc_bn1_g = (const float*)d_in[14];
    const float* enc_bn1_b = (const float*)d_in[15];
    const float* enc_bn2_g = (const float*)d_in[16];
    const float* enc_bn2_b = (const float*)d_in[17];
    const float* ee_bn1_g = (const float*)d_in[18];
    const float* ee_bn1_b = (const float*)d_in[19];
    const float* ee_bn2_g = (const float*)d_in[20];
    const float* ee_bn2_b = (const float*)d_in[21];
    const float* l0_Wnode = (const float*)d_in[22];
    const float* l0_bnode = (const float*)d_in[23];
    const float* l0_Wni = (const float*)d_in[24];
    const float* l0_Wnj = (const float*)d_in[25];
    const float* l0_Wfij = (const float*)d_in[26];
    const float* l0_attn = (const float*)d_in[27];
    const float* l0_bnn_g = (const float*)d_in[28];
    const float* l0_bnn_b = (const float*)d_in[29];
    const float* l0_bne_g = (const float*)d_in[30];
    const float* l0_bne_b = (const float*)d_in[31];
    const float* l0_Wpn = (const float*)d_in[32];
    const float* l0_bpn = (const float*)d_in[33];
    const float* l0_Wpe = (const float*)d_in[34];
    const float* l0_bpe = (const float*)d_in[35];
    const float* l1_Wnode = (const float*)d_in[36];
    const float* l1_bnode = (const float*)d_in[37];
    const float* l1_Wni = (const float*)d_in[38];
    const float* l1_Wnj = (const float*)d_in[39];
    const float* l1_Wfij = (const float*)d_in[40];
    const float* l1_attn = (const float*)d_in[41];
    const float* l1_bnn_g = (const float*)d_in[42];
    const float* l1_bnn_b = (const float*)d_in[43];
    const float* l1_Wpn = (const float*)d_in[46];
    const float* l1_bpn = (const float*)d_in[47];
    const float* dec_W = (const float*)d_in[50];
    const float* dec_b = (const float*)d_in[51];
    const float* dec_bn_g = (const float*)d_in[52];
    const float* dec_bn_b = (const float*)d_in[53];
    const float* dec_prelu = (const float*)d_in[54];
    const float* dec_Wout = (const float*)d_in[55];
    const float* dec_bout = (const float*)d_in[56];

    float* out = (float*)d_out;
    float* H1 = out;                     // N x 64 (fp32)
    float* H2 = out + (long)NN * 64;     // N x 64 (fp32)
    float* POOL = out + (long)NN * 128;  // G x 1 (fp32)

    char* base = (char*)d_ws;
    size_t off = 0;
    auto alloc = [&](size_t bytes) -> void* {
        off = (off + 255) & ~(size_t)255;
        void* p = base + off;
        off += bytes;
        return p;
    };
    u16* EH = (u16*)alloc((size_t)NE * 64 * 2);
    u16* F128 = (u16*)alloc((size_t)NE * 128 * 2);
    float* EATT = (float*)alloc((size_t)NE * 2 * 4);
    u16* NX = (u16*)alloc((size_t)NN * 64 * 2);
    u16* NI = (u16*)alloc((size_t)NN * 128 * 2);
    u16* NJ = (u16*)alloc((size_t)NN * 128 * 2);
    u16* NHH = (u16*)alloc((size_t)NN * 128 * 2);
    float* HOUT0 = (float*)alloc((size_t)NN * 128 * 4);
    float* HOUT1 = (float*)alloc((size_t)NN * 64 * 4);
    int* ROWPTR = (int*)alloc((size_t)(NN + 1) * 4);
    int* CURS = (int*)alloc((size_t)NN * 4);
    int* EPOS = (int*)alloc((size_t)NE * 4);
    int* ESRC = (int*)alloc((size_t)NE * 4);
    float* RWrot = (float*)alloc(256 * 4);
    float* RWref = (float*)alloc(256 * 4);
    u16* W2T = (u16*)alloc((size_t)64 * 64 * 2);
    u16* WfijT0 = (u16*)alloc((size_t)128 * 64 * 2);
    u16* WfijT1 = (u16*)alloc((size_t)64 * 64 * 2);
    u16* WpeT = (u16*)alloc((size_t)64 * 128 * 2);
    float* STATS = (float*)alloc((size_t)13 * 256 * 4);
    char* zstart = base + ((off + 255) & ~(size_t)255);
    int* DEG = (int*)alloc((size_t)NN * 4);
    float* STATS_RAW = (float*)alloc((size_t)13 * NSLOT * 256 * 4);
    float* RAWEF = (float*)alloc((size_t)NSLOT * 16 * 4);
    char* zend = base + off;
    if (ws_size < off) return;

    u16* T2 = F128 + (size_t)NE * 64;  // NE x 64 bf16
    u16* NX0 = F128;                   // NN x 64 bf16 (node-enc temp)
    u16* NT = F128 + (size_t)NN * 64;  // NN x 64 bf16 (node-enc temp)
    u16* DT0 = NI;
    u16* DT1 = NJ;

    auto RAW = [&](int idx) { return STATS_RAW + (size_t)idx * NSLOT * 256; };
    float* S_enc1 = STATS + 0 * 256;
    float* S_enc2 = STATS + 1 * 256;
    float* S_ee1r = STATS + 2 * 256;
    float* S_ee2r = STATS + 3 * 256;
    float* S_ee1f = STATS + 4 * 256;
    float* S_ee2f = STATS + 5 * 256;
    float* S_bnn0 = STATS + 6 * 256;
    float* S_bne0 = STATS + 7 * 256;
    float* S_bnn1 = STATS + 8 * 256;
    float* S_d0 = STATS + 9 * 256;
    float* S_d1 = STATS + 10 * 256;
    float* S_d2 = STATS + 11 * 256;
    float* S_d3 = STATS + 12 * 256;

    const float invN = 1.f / (float)NN;
    const float invE = 1.f / (float)NE;
    const int GS = 640;
    const int MFB = NE / 64;  // 6250 blocks, 64 rows each (exact)

    hipMemsetAsync(zstart, 0, (size_t)(zend - zstart), stream);
    hipMemsetAsync(POOL, 0, (size_t)NG * 4, stream);

    setup_kernel<<<1, 64, 0, stream>>>(ang_rot, ang_ref, ee_W1, RWrot, RWref);
    wt_kernel<<<(64 * 64 + 255) / 256, 256, 0, stream>>>(ee_W2, W2T, 64, 64);
    wt_kernel<<<(64 * 128 + 255) / 256, 256, 0, stream>>>(l0_Wfij, WfijT0, 64, 128);
    wt_kernel<<<(64 * 64 + 255) / 256, 256, 0, stream>>>(l1_Wfij, WfijT1, 64, 64);
    wt_kernel<<<(128 * 64 + 255) / 256, 256, 0, stream>>>(l0_Wpe, WpeT, 128, 64);

    // ---- CSR build (dst-sorted; shared by both layers) ----
    hist_kernel<<<(NE + 255) / 256, 256, 0, stream>>>(dst, NE, DEG);
    scan_kernel<<<1, 1024, 0, stream>>>(DEG, ROWPTR, CURS, NN);
    fill_kernel<<<(NE + 255) / 256, 256, 0, stream>>>(src, dst, NE, CURS, EPOS, ESRC);

    // ---- node encoder ----
    gather_emb_kernel<<<(NN * 8 + 255) / 256, 256, 0, stream>>>(ntype, emb, NX0, NN);
    colstats_kernel<64, true><<<GS, 256, 0, stream>>>(NX0, NN, RAW(0));
    finalize_stats_kernel<<<1, 256, 0, stream>>>(RAW(0), S_enc1, 128);
    mm_kernel<64, 64, true, false, true, true><<<(NN + 15) / 16, 256, 0, stream>>>(
        NX0, enc_W, enc_b, nullptr, NT, NN, 2, S_enc1, enc_bn1_g, enc_bn1_b, invN, nullptr, 0,
        RAW(1));
    finalize_stats_kernel<<<1, 256, 0, stream>>>(RAW(1), S_enc2, 128);
    bn_act_kernel<<<(NN * 8 + 255) / 256, 256, 0, stream>>>(NT, NX, NN, 64, S_enc2, enc_bn2_g,
                                                            enc_bn2_b, invN, 0);

    // ---- edge encoder (analytic T1 stats + MFMA fused recompute) ----
    efstats_kernel<<<256, 256, 0, stream>>>(efeats, NE, RAWEF);
    ee_stats_kernel<<<1, 128, 0, stream>>>(RAWEF, RWrot, RWref, ee_b1, S_ee1r, S_ee1f, NE);
    for (int br = 0; br < 2; ++br) {
        const float* RW = br ? RWref : RWrot;
        float* S1 = br ? S_ee1f : S_ee1r;
        float* S2 = br ? S_ee2f : S_ee2r;
        int r2 = br ? 5 : 3;
        mfma_ee_kernel<<<MFB, 256, 0, stream>>>(efeats, RW, ee_b1, W2T, ee_b2, T2, NE, S1,
                                                ee_bn1_g, ee_bn1_b, invE, RAW(r2));
        finalize_stats_kernel<<<1, 256, 0, stream>>>(RAW(r2), S2, 128);
        bn_act_kernel<<<(NE * 8 + 255) / 256, 256, 0, stream>>>(T2, EH, NE, 64, S2, ee_bn2_g,
                                                                ee_bn2_b, invE, br);
    }

    // ---- layer 0 (H=2) ----
    mm_kernel<64, 128, true, false, true, false><<<(NN + 7) / 8, 256, 0, stream>>>(
        NX, l0_Wni, nullptr, nullptr, NI, NN, 0, nullptr, nullptr, nullptr, 0.f, nullptr, 0,
        nullptr);
    mm_kernel<64, 128, true, false, true, false><<<(NN + 7) / 8, 256, 0, stream>>>(
        NX, l0_Wnj, nullptr, nullptr, NJ, NN, 0, nullptr, nullptr, nullptr, 0.f, nullptr, 0,
        nullptr);
    mm_kernel<64, 128, true, false, true, false><<<(NN + 7) / 8, 256, 0, stream>>>(
        NX, l0_Wnode, l0_bnode, nullptr, NHH, NN, 0, nullptr, nullptr, nullptr, 0.f, nullptr, 0,
        nullptr);
    mfma_egat_kernel<128, true><<<MFB, 256, 0, stream>>>(EH, WfijT0, NI, NJ, src, dst, EPOS,
                                                         l0_attn, F128, EATT, NE);
    csr_aggregate_kernel<128><<<(NN + 3) / 4, 256, 0, stream>>>(ROWPTR, ESRC, EATT, NHH, HOUT0,
                                                                NN);
    colstats_kernel<128, false><<<GS, 256, 0, stream>>>(HOUT0, NN, RAW(6));
    finalize_stats_kernel<<<1, 256, 0, stream>>>(RAW(6), S_bnn0, 256);
    colstats_kernel<128, true><<<GS, 256, 0, stream>>>(F128, NE, RAW(7));
    finalize_stats_kernel<<<1, 256, 0, stream>>>(RAW(7), S_bne0, 256);
    mm_kernel<128, 64, false, true, false, false><<<(NN + 15) / 16, 256, 0, stream>>>(
        HOUT0, l0_Wpn, l0_bpn, NX, H1, NN, 1, S_bnn0, l0_bnn_g, l0_bnn_b, invN, nullptr, 0,
        nullptr);
    mfma_pe_kernel<<<MFB, 256, 0, stream>>>(F128, WpeT, l0_bpe, EH, NE, S_bne0, l0_bne_g,
                                            l0_bne_b, invE);

    // ---- layer 1 (H=1; edge output dead -> skipped) ----
    mm_kernel<64, 64, false, false, true, false><<<(NN + 15) / 16, 256, 0, stream>>>(
        H1, l1_Wni, nullptr, nullptr, NI, NN, 0, nullptr, nullptr, nullptr, 0.f, nullptr, 0,
        nullptr);
    mm_kernel<64, 64, false, false, true, false><<<(NN + 15) / 16, 256, 0, stream>>>(
        H1, l1_Wnj, nullptr, nullptr, NJ, NN, 0, nullptr, nullptr, nullptr, 0.f, nullptr, 0,
        nullptr);
    mm_kernel<64, 64, false, false, true, false><<<(NN + 15) / 16, 256, 0, stream>>>(
        H1, l1_Wnode, l1_bnode, nullptr, NHH, NN, 0, nullptr, nullptr, nullptr, 0.f, nullptr, 0,
        nullptr);
    mfma_egat_kernel<64, false><<<MFB, 256, 0, stream>>>(EH, WfijT1, NI, NJ, src, dst, EPOS,
                                                         l1_attn, nullptr, EATT, NE);
    csr_aggregate_kernel<64><<<(NN + 7) / 8, 256, 0, stream>>>(ROWPTR, ESRC, EATT, NHH, HOUT1,
                                                               NN);
    colstats_kernel<64, false><<<GS, 256, 0, stream>>>(HOUT1, NN, RAW(8));
    finalize_stats_kernel<<<1, 256, 0, stream>>>(RAW(8), S_bnn1, 128);
    mm_kernel<64, 64, false, false, false, false><<<(NN + 15) / 16, 256, 0, stream>>>(
        HOUT1, l1_Wpn, l1_bpn, H1, H2, NN, 1, S_bnn1, l1_bnn_g, l1_bnn_b, invN, nullptr, 0,
        nullptr);

    // ---- decoder ----
    mm_kernel<64, 64, false, false, true, true><<<(NN + 15) / 16, 256, 0, stream>>>(
        H2, dec_W, dec_b, nullptr, DT0, NN, 0, nullptr, nullptr, nullptr, 0.f, nullptr, 0, RAW(9));
    finalize_stats_kernel<<<1, 256, 0, stream>>>(RAW(9), S_d0, 128);
    mm_kernel<64, 64, true, false, true, true><<<(NN + 15) / 16, 256, 0, stream>>>(
        DT0, dec_W + 4096, dec_b + 64, nullptr, DT1, NN, 3, S_d0, dec_bn_g, dec_bn_b, invN,
        dec_prelu, 0, RAW(10));
    finalize_stats_kernel<<<1, 256, 0, stream>>>(RAW(10), S_d1, 128);
    mm_kernel<64, 64, true, false, true, true><<<(NN + 15) / 16, 256, 0, stream>>>(
        DT1, dec_W + 8192, dec_b + 128, nullptr, DT0, NN, 3, S_d1, dec_bn_g + 64, dec_bn_b + 64,
        invN, dec_prelu, 1, RAW(11));
    finalize_stats_kernel<<<1, 256, 0, stream>>>(RAW(11), S_d2, 128);
    mm_kernel<64, 64, true, false, true, true><<<(NN + 15) / 16, 256, 0, stream>>>(
        DT0, dec_W + 12288, dec_b + 192, nullptr, DT1, NN, 3, S_d2, dec_bn_g + 128,
        dec_bn_b + 128, invN, dec_prelu, 2, RAW(12));
    finalize_stats_kernel<<<1, 256, 0, stream>>>(RAW(12), S_d3, 128);
    decoder_out_kernel<<<(NN + 3) / 4, 256, 0, stream>>>(DT1, S_d3, dec_bn_g + 192,
                                                         dec_bn_b + 192, dec_prelu, dec_Wout,
                                                         dec_bout, gid, POOL, NN, invN);
}

// Round 7
// 1035.616 us; speedup vs baseline: 1.7652x; 1.0731x over previous
//
#include <hip/hip_runtime.h>
#include <math.h>

#define NN 50000
#define NE 400000
#define NG 512
#define EPS 1e-5f
#define NSLOT 256  // stats replica slots (atomic contention spreading)

typedef unsigned int u32;
typedef unsigned short u16;

typedef __attribute__((ext_vector_type(8))) short s16x8;  // 8 bf16 (4 VGPRs)
typedef __attribute__((ext_vector_type(4))) float f32x4;

__device__ __forceinline__ float b2f(u16 h) { return __uint_as_float(((u32)h) << 16); }
__device__ __forceinline__ u16 f2b(float f) {
    u32 x = __float_as_uint(f);
    u32 r = x + 0x7fffu + ((x >> 16) & 1u);
    return (u16)(r >> 16);
}
struct alignas(16) U16x8 { u16 s[8]; };
struct alignas(8) U16x4 { u16 s[4]; };
struct alignas(4) U16x2 { u16 s[2]; };

__device__ __forceinline__ void f4add(float4& a, const float4 b) {
    a.x += b.x; a.y += b.y; a.z += b.z; a.w += b.w;
}

// ---------------- setup: fold rotation matrices into ee_W1 (fp32) ----------------
__global__ void setup_kernel(const float* __restrict__ ang_rot, const float* __restrict__ ang_ref,
                             const float* __restrict__ W1, float* __restrict__ RWrot,
                             float* __restrict__ RWref) {
    int c = threadIdx.x;  // 64
    for (int which = 0; which < 2; ++which) {
        const float* a = which ? ang_ref : ang_rot;
        float t = a[0], p = a[1], q = a[2];
        float ct = cosf(t), st = sinf(t);
        float cp = cosf(p), sp = sinf(p);
        float cq = cosf(q), sq = sinf(q);
        float Rt[3][3] = {{ct, -st, 0.f}, {st, ct, 0.f}, {0.f, 0.f, 1.f}};
        float Rp[3][3] = {{cp, 0.f, -sp}, {0.f, 1.f, 0.f}, {sp, 0.f, cp}};
        float Rq[3][3] = {{1.f, 0.f, 0.f}, {0.f, cq, -sq}, {0.f, sq, cq}};
        float Rtp[3][3], R[3][3];
        for (int i = 0; i < 3; ++i)
            for (int j = 0; j < 3; ++j) {
                float s = 0.f;
                for (int k = 0; k < 3; ++k) s += Rt[i][k] * Rp[k][j];
                Rtp[i][j] = s;
            }
        for (int i = 0; i < 3; ++i)
            for (int j = 0; j < 3; ++j) {
                float s = 0.f;
                for (int k = 0; k < 3; ++k) s += Rtp[i][k] * Rq[k][j];
                R[i][j] = s;
            }
        float sgn = which ? -1.f : 1.f;  // R_ref = -rotmat(angles_ref)
        float* RW = which ? RWref : RWrot;
        if (c < 64) {
            for (int j = 0; j < 3; ++j) {
                float s = 0.f;
                for (int m = 0; m < 3; ++m) s += sgn * R[j][m] * W1[m * 64 + c];
                RW[j * 64 + c] = s;  // RW = R @ W1  (3 x 64)
            }
        }
    }
}

// ---------------- W [K][C] fp32 -> WT [C][K] bf16 ----------------
__global__ __launch_bounds__(256) void wt_kernel(const float* __restrict__ W,
                                                 u16* __restrict__ WT, int K, int C) {
    int i = blockIdx.x * 256 + threadIdx.x;
    if (i >= K * C) return;
    int k = i / C, c = i - k * C;
    WT[c * K + k] = f2b(W[i]);
}

// ---------------- CSR build: degree hist -> 3-phase scan -> fill ----------------
__global__ __launch_bounds__(256) void hist_kernel(const int* __restrict__ dst, int E,
                                                   int* __restrict__ deg) {
    int e = blockIdx.x * 256 + threadIdx.x;
    if (e < E) atomicAdd(&deg[dst[e]], 1);
}

// per-block reduce of deg chunk -> bsum[block]
__global__ __launch_bounds__(256) void scan_part_kernel(const int* __restrict__ deg,
                                                        int* __restrict__ bsum, int n) {
    int i = blockIdx.x * 256 + threadIdx.x;
    int v = (i < n) ? deg[i] : 0;
#pragma unroll
    for (int off = 1; off < 64; off <<= 1) v += __shfl_xor(v, off, 64);
    __shared__ int ws[4];
    if ((threadIdx.x & 63) == 0) ws[threadIdx.x >> 6] = v;
    __syncthreads();
    if (threadIdx.x == 0) bsum[blockIdx.x] = ws[0] + ws[1] + ws[2] + ws[3];
}

// exclusive scan of block sums (nb <= 256), in place; also rowptr[n] = total
__global__ __launch_bounds__(256) void scan_top_kernel(int* __restrict__ bsum, int nb,
                                                       int* __restrict__ rowptr, int n,
                                                       int total) {
    __shared__ int s[256];
    int tid = threadIdx.x;
    s[tid] = (tid < nb) ? bsum[tid] : 0;
    __syncthreads();
    for (int off = 1; off < 256; off <<= 1) {
        int v = (tid >= off) ? s[tid - off] : 0;
        __syncthreads();
        s[tid] += v;
        __syncthreads();
    }
    if (tid < nb) bsum[tid] = (tid == 0) ? 0 : s[tid - 1];
    if (tid == 0) rowptr[n] = total;
}

// intra-block exclusive scan + block offset -> rowptr, curs
__global__ __launch_bounds__(256) void scan_fill_kernel(const int* __restrict__ deg,
                                                        const int* __restrict__ bsum,
                                                        int* __restrict__ rowptr,
                                                        int* __restrict__ curs, int n) {
    __shared__ int s[256];
    int tid = threadIdx.x;
    int i = blockIdx.x * 256 + tid;
    int v = (i < n) ? deg[i] : 0;
    s[tid] = v;
    __syncthreads();
    for (int off = 1; off < 256; off <<= 1) {
        int t = (tid >= off) ? s[tid - off] : 0;
        __syncthreads();
        s[tid] += t;
        __syncthreads();
    }
    if (i < n) {
        int excl = s[tid] - v + bsum[blockIdx.x];
        rowptr[i] = excl;
        curs[i] = excl;
    }
}

__global__ __launch_bounds__(256) void fill_kernel(const int* __restrict__ src,
                                                   const int* __restrict__ dst, int E,
                                                   int* __restrict__ curs,
                                                   int* __restrict__ epos,
                                                   int* __restrict__ esrc) {
    int e = blockIdx.x * 256 + threadIdx.x;
    if (e >= E) return;
    int pos = atomicAdd(&curs[dst[e]], 1);
    epos[e] = pos;
    esrc[pos] = src[e];
}

// ---------------- embedding gather: fp32 table -> bf16 out ----------------
__global__ __launch_bounds__(256) void gather_emb_kernel(const int* __restrict__ ntype,
                                                         const float* __restrict__ emb,
                                                         u16* __restrict__ out, int n) {
    long i = (long)blockIdx.x * 256 + threadIdx.x;  // over n*8
    long e = i >> 3;
    if (e >= n) return;
    int c0 = (int)(i & 7) * 8;
    int t = ntype[e];
    float4 a = *(const float4*)&emb[(long)t * 64 + c0];
    float4 b = *(const float4*)&emb[(long)t * 64 + c0 + 4];
    U16x8 o;
    o.s[0] = f2b(a.x); o.s[1] = f2b(a.y); o.s[2] = f2b(a.z); o.s[3] = f2b(a.w);
    o.s[4] = f2b(b.x); o.s[5] = f2b(b.y); o.s[6] = f2b(b.z); o.s[7] = f2b(b.w);
    *(U16x8*)&out[e * 64 + c0] = o;
}

// ---------------- efeats second moments: 9 scalars -> replica slots ----------------
__global__ __launch_bounds__(256) void efstats_kernel(const float* __restrict__ ef, int E,
                                                      float* __restrict__ raw) {
    int tid = threadIdx.x;
    float a[9];
#pragma unroll
    for (int j = 0; j < 9; ++j) a[j] = 0.f;
    for (long e = (long)blockIdx.x * 256 + tid; e < E; e += (long)gridDim.x * 256) {
        float f0 = ef[e * 3 + 0], f1 = ef[e * 3 + 1], f2 = ef[e * 3 + 2];
        a[0] += f0; a[1] += f1; a[2] += f2;
        a[3] += f0 * f0; a[4] += f1 * f1; a[5] += f2 * f2;
        a[6] += f0 * f1; a[7] += f0 * f2; a[8] += f1 * f2;
    }
#pragma unroll
    for (int off = 1; off < 64; off <<= 1)
#pragma unroll
        for (int j = 0; j < 9; ++j) a[j] += __shfl_xor(a[j], off, 64);
    __shared__ float sred[4][9];
    int wv = tid >> 6, ln = tid & 63;
    if (ln == 0)
#pragma unroll
        for (int j = 0; j < 9; ++j) sred[wv][j] = a[j];
    __syncthreads();
    if (tid < 9) {
        float v = sred[0][tid] + sred[1][tid] + sred[2][tid] + sred[3][tid];
        atomicAdd(&raw[(size_t)(blockIdx.x & (NSLOT - 1)) * 16 + tid], v);
    }
}

// ---------------- analytic T1 column stats for both branches ----------------
__global__ void ee_stats_kernel(const float* __restrict__ efraw, const float* __restrict__ RWrot,
                                const float* __restrict__ RWref, const float* __restrict__ b1,
                                float* __restrict__ S_rot, float* __restrict__ S_ref, int E) {
    __shared__ float m[9];
    int t = threadIdx.x;  // 128
    if (t < 9) {
        float s = 0.f;
        for (int r = 0; r < NSLOT; ++r) s += efraw[r * 16 + t];
        m[t] = s;
    }
    __syncthreads();
    int br = t >> 6, c = t & 63;
    const float* RW = br ? RWref : RWrot;
    float* S = br ? S_ref : S_rot;
    float w0 = RW[c], w1 = RW[64 + c], w2 = RW[128 + c];
    float bb = b1[c];
    float mw = m[0] * w0 + m[1] * w1 + m[2] * w2;
    float sum = mw + (float)E * bb;
    float quad = m[3] * w0 * w0 + m[4] * w1 * w1 + m[5] * w2 * w2 +
                 2.f * (m[6] * w0 * w1 + m[7] * w0 * w2 + m[8] * w1 * w2);
    float ss = quad + 2.f * bb * mw + (float)E * bb * bb;
    S[c] = sum;
    S[64 + c] = ss;
}

// ---------------- column stats -> replicated raw accumulators ----------------
template <int COLS, bool XBF>
__global__ __launch_bounds__(256) void colstats_kernel(const void* __restrict__ xv, int rows,
                                                       float* __restrict__ raw) {
    constexpr int TPR = COLS / 8;
    constexpr int RPB = 256 / TPR;
    __shared__ float4 sA[256], sB[256], sC[256], sD[256];
    int tid = threadIdx.x;
    int c8 = tid % TPR;
    int rl = tid / TPR;
    float s[8], q[8];
#pragma unroll
    for (int j = 0; j < 8; ++j) { s[j] = 0.f; q[j] = 0.f; }
    const long stride = (long)gridDim.x * RPB;
    long r = (long)blockIdx.x * RPB + rl;
    auto loadrow = [&](long rr, float* v) {
        if (XBF) {
            U16x8 t = *(const U16x8*)((const u16*)xv + rr * COLS + c8 * 8);
#pragma unroll
            for (int j = 0; j < 8; ++j) v[j] = b2f(t.s[j]);
        } else {
            float4 a = *(const float4*)((const float*)xv + rr * COLS + c8 * 8);
            float4 b = *(const float4*)((const float*)xv + rr * COLS + c8 * 8 + 4);
            v[0] = a.x; v[1] = a.y; v[2] = a.z; v[3] = a.w;
            v[4] = b.x; v[5] = b.y; v[6] = b.z; v[7] = b.w;
        }
    };
    for (; r + stride < rows; r += 2 * stride) {
        float v0[8], v1[8];
        loadrow(r, v0);
        loadrow(r + stride, v1);
#pragma unroll
        for (int j = 0; j < 8; ++j) {
            s[j] += v0[j] + v1[j];
            q[j] += v0[j] * v0[j] + v1[j] * v1[j];
        }
    }
    if (r < rows) {
        float v0[8];
        loadrow(r, v0);
#pragma unroll
        for (int j = 0; j < 8; ++j) { s[j] += v0[j]; q[j] += v0[j] * v0[j]; }
    }
    sA[tid] = make_float4(s[0], s[1], s[2], s[3]);
    sB[tid] = make_float4(s[4], s[5], s[6], s[7]);
    sC[tid] = make_float4(q[0], q[1], q[2], q[3]);
    sD[tid] = make_float4(q[4], q[5], q[6], q[7]);
    __syncthreads();
    for (int off = 128; off >= TPR; off >>= 1) {
        if (tid < off) {
            f4add(sA[tid], sA[tid + off]); f4add(sB[tid], sB[tid + off]);
            f4add(sC[tid], sC[tid + off]); f4add(sD[tid], sD[tid + off]);
        }
        __syncthreads();
    }
    if (tid < TPR) {
        float* slot = raw + (size_t)(blockIdx.x & (NSLOT - 1)) * 256;
        int c = tid * 8;
        float4 a = sA[tid], b = sB[tid], cq = sC[tid], d = sD[tid];
        atomicAdd(&slot[c + 0], a.x); atomicAdd(&slot[c + 1], a.y);
        atomicAdd(&slot[c + 2], a.z); atomicAdd(&slot[c + 3], a.w);
        atomicAdd(&slot[c + 4], b.x); atomicAdd(&slot[c + 5], b.y);
        atomicAdd(&slot[c + 6], b.z); atomicAdd(&slot[c + 7], b.w);
        atomicAdd(&slot[COLS + c + 0], cq.x); atomicAdd(&slot[COLS + c + 1], cq.y);
        atomicAdd(&slot[COLS + c + 2], cq.z); atomicAdd(&slot[COLS + c + 3], cq.w);
        atomicAdd(&slot[COLS + c + 4], d.x); atomicAdd(&slot[COLS + c + 5], d.y);
        atomicAdd(&slot[COLS + c + 6], d.z); atomicAdd(&slot[COLS + c + 7], d.w);
    }
}

// ---------------- reduce NSLOT replica slots -> final stats ----------------
__global__ __launch_bounds__(256) void finalize_stats_kernel(const float* __restrict__ raw,
                                                             float* __restrict__ stats, int n) {
    int i = threadIdx.x;
    if (i >= n) return;
    float s = 0.f;
    for (int r = 0; r < NSLOT; ++r) s += raw[r * 256 + i];
    stats[i] = s;
}

// ---------------- elementwise y = relu(bn(x)) [+= y], bf16 x/y ----------------
__global__ __launch_bounds__(256) void bn_act_kernel(const u16* __restrict__ x,
                                                     u16* __restrict__ y, long rows, int cols,
                                                     const float* __restrict__ acc,
                                                     const float* __restrict__ g,
                                                     const float* __restrict__ b, float inv_rows,
                                                     int accumulate) {
    long i = (long)blockIdx.x * 256 + threadIdx.x;
    long total8 = rows * (long)cols / 8;
    if (i >= total8) return;
    long base = i * 8;
    int c0 = (int)(base % cols);
    U16x8 xv = *(const U16x8*)&x[base];
    float r[8];
#pragma unroll
    for (int j = 0; j < 8; ++j) {
        int c = c0 + j;
        float mu = acc[c] * inv_rows;
        float var = acc[cols + c] * inv_rows - mu * mu;
        float al = g[c] * rsqrtf(fmaxf(var, 0.f) + EPS);
        float be = b[c] - mu * al;
        float o = al * b2f(xv.s[j]) + be;
        r[j] = fmaxf(o, 0.f);
    }
    if (accumulate) {
        U16x8 yv = *(const U16x8*)&y[base];
#pragma unroll
        for (int j = 0; j < 8; ++j) r[j] += b2f(yv.s[j]);
    }
    U16x8 o;
#pragma unroll
    for (int j = 0; j < 8; ++j) o.s[j] = f2b(r[j]);
    *(U16x8*)&y[base] = o;
}

// ---------------- generic tiled matmul (fp32 VALU; NN-scale only) ----------------
template <int K, int COLS, bool XBF, bool RBF, bool OBF, bool SOUT>
__global__ __launch_bounds__(256) void mm_kernel(const void* __restrict__ Xv,
                                                 const float* __restrict__ Wg,
                                                 const float* __restrict__ bias, const void* resv,
                                                 void* Yv, int rows, int preop,
                                                 const float* __restrict__ stats,
                                                 const float* __restrict__ g,
                                                 const float* __restrict__ b, float inv_rows,
                                                 const float* __restrict__ prelu, int prelu_idx,
                                                 float* __restrict__ raw) {
    constexpr int TPR = COLS / 4;
    constexpr int RPB = 256 / TPR;
    constexpr int XP = K + 4;
    __shared__ float ws[K * COLS];
    __shared__ float xs[RPB * XP];
    __shared__ float al[K];
    __shared__ float be[K];
    const int tid = threadIdx.x;

    for (int i = tid; i < K * COLS; i += 256) ws[i] = Wg[i];
    if (preop) {
        for (int k = tid; k < K; k += 256) {
            float mu = stats[k] * inv_rows;
            float var = stats[K + k] * inv_rows - mu * mu;
            float a = g[k] * rsqrtf(fmaxf(var, 0.f) + EPS);
            al[k] = a;
            be[k] = b[k] - mu * a;
        }
    }
    __syncthreads();

    const long r0 = (long)blockIdx.x * RPB;
    float pa = (preop == 3) ? prelu[prelu_idx] : 0.f;
    constexpr int NC = RPB * K / 4;
    for (int i = tid; i < NC; i += 256) {
        int b4 = i * 4;
        int rl = b4 / K, k0 = b4 % K;
        long r = r0 + rl;
        float v[4];
        if (r < rows) {
            if (XBF) {
                U16x4 t = *(const U16x4*)((const u16*)Xv + r * K + k0);
#pragma unroll
                for (int j = 0; j < 4; ++j) v[j] = b2f(t.s[j]);
            } else {
                float4 t = *(const float4*)((const float*)Xv + r * K + k0);
                v[0] = t.x; v[1] = t.y; v[2] = t.z; v[3] = t.w;
            }
        } else {
#pragma unroll
            for (int j = 0; j < 4; ++j) v[j] = 0.f;
        }
        if (preop) {
#pragma unroll
            for (int j = 0; j < 4; ++j) {
                float xx = al[k0 + j] * v[j] + be[k0 + j];
                if (preop == 2) xx = fmaxf(xx, 0.f);
                else if (preop == 3) xx = (xx >= 0.f) ? xx : pa * xx;
                v[j] = xx;
            }
        }
        xs[rl * XP + k0 + 0] = v[0];
        xs[rl * XP + k0 + 1] = v[1];
        xs[rl * XP + k0 + 2] = v[2];
        xs[rl * XP + k0 + 3] = v[3];
    }
    __syncthreads();

    const int rl = tid / TPR;
    const int c0 = (tid % TPR) * 4;
    float4 acc = {0.f, 0.f, 0.f, 0.f};
#pragma unroll
    for (int k = 0; k < K; k += 4) {
        float4 xv = *(const float4*)&xs[rl * XP + k];
#pragma unroll
        for (int j = 0; j < 4; ++j) {
            float xj = (&xv.x)[j];
            float4 wv = *(const float4*)&ws[(k + j) * COLS + c0];
            acc.x += xj * wv.x; acc.y += xj * wv.y;
            acc.z += xj * wv.z; acc.w += xj * wv.w;
        }
    }
    long r = r0 + rl;
    if (r < rows) {
        if (bias) f4add(acc, *(const float4*)&bias[c0]);
        if (resv) {
            if (RBF) {
                U16x4 t = *(const U16x4*)((const u16*)resv + r * COLS + c0);
                acc.x += b2f(t.s[0]); acc.y += b2f(t.s[1]);
                acc.z += b2f(t.s[2]); acc.w += b2f(t.s[3]);
            } else {
                f4add(acc, *(const float4*)((const float*)resv + r * COLS + c0));
            }
        }
        if (OBF) {
            U16x4 o;
            o.s[0] = f2b(acc.x); o.s[1] = f2b(acc.y);
            o.s[2] = f2b(acc.z); o.s[3] = f2b(acc.w);
            *(U16x4*)((u16*)Yv + r * COLS + c0) = o;
        } else {
            *(float4*)((float*)Yv + r * COLS + c0) = acc;
        }
    }
    if constexpr (SOUT) {
        __syncthreads();
        float4 va = (r < rows) ? acc : make_float4(0.f, 0.f, 0.f, 0.f);
        *(float4*)&ws[rl * COLS + c0] = va;
        float4 vq = make_float4(va.x * va.x, va.y * va.y, va.z * va.z, va.w * va.w);
        *(float4*)&ws[RPB * COLS + rl * COLS + c0] = vq;
        __syncthreads();
        for (int off2 = RPB / 2; off2 >= 1; off2 >>= 1) {
            if (rl < off2) {
                float4 x1 = *(float4*)&ws[rl * COLS + c0];
                f4add(x1, *(const float4*)&ws[(rl + off2) * COLS + c0]);
                *(float4*)&ws[rl * COLS + c0] = x1;
                float4 x2 = *(float4*)&ws[RPB * COLS + rl * COLS + c0];
                f4add(x2, *(const float4*)&ws[RPB * COLS + (rl + off2) * COLS + c0]);
                *(float4*)&ws[RPB * COLS + rl * COLS + c0] = x2;
            }
            __syncthreads();
        }
        if (rl == 0) {
            float* slot = raw + (size_t)(blockIdx.x & (NSLOT - 1)) * 256;
#pragma unroll
            for (int j = 0; j < 4; ++j) {
                atomicAdd(&slot[c0 + j], ws[c0 + j]);
                atomicAdd(&slot[COLS + c0 + j], ws[RPB * COLS + c0 + j]);
            }
        }
    }
}

// ================= MFMA kernels (NE-scale matmuls) =================
// Fragment layout (guide §3, m89/m91/m92 verified):
//   A: lane l holds A[row=l&15][k=(l>>4)*8+j]
//   B: lane l holds B[k=(l>>4)*8+j][col=l&15]  (8 contiguous bf16 from W^T row)
//   D: lane l reg r holds D[row=(l>>4)*4+r][col=l&15]

// ---- T2 = relu(bn1(ef@RW + b1)) @ W2 + b2 (T1 generated in-register) + col-stats ----
__global__ __launch_bounds__(256) void mfma_ee_kernel(
    const float* __restrict__ ef, const float* __restrict__ RW, const float* __restrict__ b1v,
    const u16* __restrict__ W2T, const float* __restrict__ b2, u16* __restrict__ T2, int E,
    const float* __restrict__ stats, const float* __restrict__ g, const float* __restrict__ b,
    float inv_rows, float* __restrict__ raw) {
    __shared__ float rws[192];
    __shared__ float al[64], be[64];
    __shared__ float ssum[64], ssq[64];
    const int tid = threadIdx.x;
    if (tid < 192) rws[tid] = RW[tid];
    if (tid < 64) {
        float mu = stats[tid] * inv_rows;
        float var = stats[64 + tid] * inv_rows - mu * mu;
        float a = g[tid] * rsqrtf(fmaxf(var, 0.f) + EPS);
        al[tid] = a;
        be[tid] = b[tid] - mu * a + a * b1v[tid];  // fold b1 into affine
        ssum[tid] = 0.f;
        ssq[tid] = 0.f;
    }
    __syncthreads();
    const int lane = tid & 63, wv = tid >> 6;
    const int q = lane >> 4, rr = lane & 15;
    const long r0 = ((long)blockIdx.x * 4 + wv) * 16;
    const long ar = r0 + rr;
    float e0 = ef[ar * 3], e1 = ef[ar * 3 + 1], e2 = ef[ar * 3 + 2];
    s16x8 afr[2];
#pragma unroll
    for (int kk = 0; kk < 2; ++kk) {
        union { u16 u[8]; s16x8 v; } t;
#pragma unroll
        for (int j = 0; j < 8; ++j) {
            int k = kk * 32 + q * 8 + j;
            float tv = e0 * rws[k] + e1 * rws[64 + k] + e2 * rws[128 + k];
            t.u[j] = f2b(fmaxf(al[k] * tv + be[k], 0.f));
        }
        afr[kk] = t.v;
    }
    f32x4 acc[4];
#pragma unroll
    for (int ct = 0; ct < 4; ++ct) {
        acc[ct] = (f32x4){0.f, 0.f, 0.f, 0.f};
#pragma unroll
        for (int kk = 0; kk < 2; ++kk) {
            s16x8 bfr = *(const s16x8*)&W2T[(size_t)(ct * 16 + rr) * 64 + kk * 32 + q * 8];
            acc[ct] = __builtin_amdgcn_mfma_f32_16x16x32_bf16(afr[kk], bfr, acc[ct], 0, 0, 0);
        }
    }
#pragma unroll
    for (int ct = 0; ct < 4; ++ct) {
        int col = ct * 16 + rr;
        float bb = b2[col];
        float s = 0.f, qq = 0.f;
#pragma unroll
        for (int r = 0; r < 4; ++r) {
            long orr = r0 + q * 4 + r;
            float v = acc[ct][r] + bb;
            T2[orr * 64 + col] = f2b(v);
            s += v;
            qq += v * v;
        }
        s += __shfl_xor(s, 16, 64); s += __shfl_xor(s, 32, 64);
        qq += __shfl_xor(qq, 16, 64); qq += __shfl_xor(qq, 32, 64);
        if (q == 0) {
            atomicAdd(&ssum[col], s);
            atomicAdd(&ssq[col], qq);
        }
    }
    __syncthreads();
    if (tid < 64) {
        float* slot = raw + (size_t)(blockIdx.x & (NSLOT - 1)) * 256;
        atomicAdd(&slot[tid], ssum[tid]);
        atomicAdd(&slot[64 + tid], ssq[tid]);
    }
}

// ---- f = leaky(EH@Wfij + NI[src] + NJ[dst]); att scores -> CSR slots; opt col-stats ----
template <int COLS, bool WRITE_F, bool SOUT>
__global__ __launch_bounds__(256) void mfma_egat_kernel(
    const u16* __restrict__ EH, const u16* __restrict__ WT, const u16* __restrict__ NI,
    const u16* __restrict__ NJ, const int* __restrict__ src, const int* __restrict__ dst,
    const int* __restrict__ epos, const float* __restrict__ attn, u16* __restrict__ Fout,
    float* __restrict__ eatt, int E, float* __restrict__ raw) {
    constexpr int H = COLS / 64;
    constexpr int NCT = COLS / 16;
    __shared__ float ssum[SOUT ? COLS : 1];
    __shared__ float ssq[SOUT ? COLS : 1];
    const int tid = threadIdx.x;
    if (SOUT) {
        for (int i = tid; i < COLS; i += 256) { ssum[i] = 0.f; ssq[i] = 0.f; }
        __syncthreads();
    }
    const int lane = tid & 63, wv = tid >> 6;
    const int q = lane >> 4, rr = lane & 15;
    const long r0 = ((long)blockIdx.x * 4 + wv) * 16;
    s16x8 afr[2];
#pragma unroll
    for (int kk = 0; kk < 2; ++kk)
        afr[kk] = *(const s16x8*)&EH[(r0 + rr) * 64 + kk * 32 + q * 8];
    int sidx[4], didx[4];
#pragma unroll
    for (int r = 0; r < 4; ++r) {
        long orr = r0 + q * 4 + r;
        sidx[r] = src[orr];
        didx[r] = dst[orr];
    }
    f32x4 acc[NCT];
#pragma unroll
    for (int ct = 0; ct < NCT; ++ct) {
        acc[ct] = (f32x4){0.f, 0.f, 0.f, 0.f};
#pragma unroll
        for (int kk = 0; kk < 2; ++kk) {
            s16x8 bfr = *(const s16x8*)&WT[(size_t)(ct * 16 + rr) * 64 + kk * 32 + q * 8];
            acc[ct] = __builtin_amdgcn_mfma_f32_16x16x32_bf16(afr[kk], bfr, acc[ct], 0, 0, 0);
        }
    }
    float part[H][4];
#pragma unroll
    for (int h = 0; h < H; ++h)
#pragma unroll
        for (int r = 0; r < 4; ++r) part[h][r] = 0.f;
#pragma unroll
    for (int ct = 0; ct < NCT; ++ct) {
        int col = ct * 16 + rr;
        float av = attn[col];
        const int h = (H == 2) ? (ct >> 2) : 0;
        float fs = 0.f, fq = 0.f;
#pragma unroll
        for (int r = 0; r < 4; ++r) {
            long orr = r0 + q * 4 + r;
            float f = acc[ct][r] + b2f(NI[(size_t)sidx[r] * COLS + col]) +
                      b2f(NJ[(size_t)didx[r] * COLS + col]);
            f = (f >= 0.f) ? f : 0.01f * f;
            if (WRITE_F) Fout[orr * COLS + col] = f2b(f);
            part[h][r] += f * av;
            if (SOUT) { fs += f; fq += f * f; }
        }
        if (SOUT) {
            fs += __shfl_xor(fs, 16, 64); fs += __shfl_xor(fs, 32, 64);
            fq += __shfl_xor(fq, 16, 64); fq += __shfl_xor(fq, 32, 64);
            if (q == 0) {
                atomicAdd(&ssum[col], fs);
                atomicAdd(&ssq[col], fq);
            }
        }
    }
#pragma unroll
    for (int h = 0; h < H; ++h)
#pragma unroll
        for (int r = 0; r < 4; ++r) {
            float p = part[h][r];
            p += __shfl_xor(p, 1, 64);
            p += __shfl_xor(p, 2, 64);
            p += __shfl_xor(p, 4, 64);
            p += __shfl_xor(p, 8, 64);
            part[h][r] = p;
        }
    if (rr == 0) {
#pragma unroll
        for (int r = 0; r < 4; ++r) {
            long pos = epos[r0 + q * 4 + r];
            if (H == 2) {
                eatt[pos * 2 + 0] = part[0][r];
                eatt[pos * 2 + 1] = part[1][r];
            } else {
                eatt[pos] = part[0][r];
            }
        }
    }
    if (SOUT) {
        __syncthreads();
        float* slot = raw + (size_t)(blockIdx.x & (NSLOT - 1)) * 256;
        for (int i = tid; i < COLS; i += 256) {
            atomicAdd(&slot[i], ssum[i]);
            atomicAdd(&slot[COLS + i], ssq[i]);
        }
    }
}

// ---- EH = bn(F128)@Wpe + bpe + EH (K=128, in-place residual) ----
__global__ __launch_bounds__(256) void mfma_pe_kernel(
    const u16* __restrict__ X, const u16* __restrict__ WT, const float* __restrict__ bias,
    u16* __restrict__ EHio, int E, const float* __restrict__ stats, const float* __restrict__ g,
    const float* __restrict__ b, float inv_rows) {
    __shared__ float al[128], be[128];
    const int tid = threadIdx.x;
    if (tid < 128) {
        float mu = stats[tid] * inv_rows;
        float var = stats[128 + tid] * inv_rows - mu * mu;
        float a = g[tid] * rsqrtf(fmaxf(var, 0.f) + EPS);
        al[tid] = a;
        be[tid] = b[tid] - mu * a;
    }
    __syncthreads();
    const int lane = tid & 63, wv = tid >> 6;
    const int q = lane >> 4, rr = lane & 15;
    const long r0 = ((long)blockIdx.x * 4 + wv) * 16;
    s16x8 afr[4];
#pragma unroll
    for (int kk = 0; kk < 4; ++kk) {
        U16x8 t = *(const U16x8*)&X[(r0 + rr) * 128 + kk * 32 + q * 8];
        union { u16 u[8]; s16x8 v; } o;
#pragma unroll
        for (int j = 0; j < 8; ++j) {
            int k = kk * 32 + q * 8 + j;
            o.u[j] = f2b(al[k] * b2f(t.s[j]) + be[k]);
        }
        afr[kk] = o.v;
    }
    f32x4 acc[4];
#pragma unroll
    for (int ct = 0; ct < 4; ++ct) {
        acc[ct] = (f32x4){0.f, 0.f, 0.f, 0.f};
#pragma unroll
        for (int kk = 0; kk < 4; ++kk) {
            s16x8 bfr = *(const s16x8*)&WT[(size_t)(ct * 16 + rr) * 128 + kk * 32 + q * 8];
            acc[ct] = __builtin_amdgcn_mfma_f32_16x16x32_bf16(afr[kk], bfr, acc[ct], 0, 0, 0);
        }
    }
#pragma unroll
    for (int ct = 0; ct < 4; ++ct) {
        int col = ct * 16 + rr;
        float bb = bias[col];
#pragma unroll
        for (int r = 0; r < 4; ++r) {
            long orr = r0 + q * 4 + r;
            float v = acc[ct][r] + bb + b2f(EHio[orr * 64 + col]);
            EHio[orr * 64 + col] = f2b(v);
        }
    }
}

// ---------------- CSR gather aggregate: per-node softmax + weighted sum (+col-stats) ----------------
template <int COLS, bool SOUT>
__global__ __launch_bounds__(256) void csr_aggregate_kernel(
    const int* __restrict__ rowptr, const int* __restrict__ esrc,
    const float* __restrict__ eatt, const u16* __restrict__ nodeh, float* __restrict__ hout,
    int n, float* __restrict__ raw) {
    constexpr int H = COLS / 64;
    constexpr int TPN = COLS / 2;
    constexpr int NPB = 256 / TPN;
    __shared__ float ssum[SOUT ? COLS : 1];
    __shared__ float ssq[SOUT ? COLS : 1];
    int tid = threadIdx.x;
    if (SOUT) {
        for (int i = tid; i < COLS; i += 256) { ssum[i] = 0.f; ssq[i] = 0.f; }
        __syncthreads();
    }
    int node = blockIdx.x * NPB + tid / TPN;
    bool act = node < n;
    int c = (tid % TPN) * 2;
    float a0 = 0.f, a1 = 0.f;
    if (act) {
        int h = (H == 2) ? (c >> 6) : 0;
        int p0 = rowptr[node], p1 = rowptr[node + 1];
        float m = -INFINITY, s = 0.f;
        for (int p = p0; p < p1; ++p) {
            float v = eatt[(long)p * H + h];
            float mn = fmaxf(m, v);
            s = s * expf(m - mn) + expf(v - mn);
            m = mn;
        }
        float inv = (s > 0.f) ? 1.f / s : 0.f;
        for (int p = p0; p < p1; ++p) {
            float w = expf(eatt[(long)p * H + h] - m) * inv;
            U16x2 v = *(const U16x2*)&nodeh[(long)esrc[p] * COLS + c];
            a0 += b2f(v.s[0]) * w;
            a1 += b2f(v.s[1]) * w;
        }
        *(float2*)&hout[(long)node * COLS + c] = make_float2(a0, a1);
    }
    if (SOUT) {
        if (act) {
            atomicAdd(&ssum[c], a0);
            atomicAdd(&ssum[c + 1], a1);
            atomicAdd(&ssq[c], a0 * a0);
            atomicAdd(&ssq[c + 1], a1 * a1);
        }
        __syncthreads();
        float* slot = raw + (size_t)(blockIdx.x & (NSLOT - 1)) * 256;
        for (int i = tid; i < COLS; i += 256) {
            atomicAdd(&slot[i], ssum[i]);
            atomicAdd(&slot[COLS + i], ssq[i]);
        }
    }
}

// ---------------- decoder tail: prelu(bn(t3)) @ Wout + bout -> pool by graph ----------------
__global__ __launch_bounds__(256) void decoder_out_kernel(
    const u16* __restrict__ t3, const float* __restrict__ stats, const float* __restrict__ g,
    const float* __restrict__ b, const float* __restrict__ prelu, const float* __restrict__ Wout,
    const float* __restrict__ bout, const int* __restrict__ gid, float* __restrict__ pool,
    int rows, float inv_rows) {
    int tid = threadIdx.x;
    long r = (long)blockIdx.x * 4 + (tid >> 6);
    if (r >= rows) return;
    int k = tid & 63;
    float mu = stats[k] * inv_rows;
    float var = stats[64 + k] * inv_rows - mu * mu;
    float al = g[k] * rsqrtf(fmaxf(var, 0.f) + EPS);
    float be = b[k] - mu * al;
    float a = prelu[3];
    float v = al * b2f(t3[r * 64 + k]) + be;
    v = (v >= 0.f) ? v : a * v;
    v *= Wout[k];
#pragma unroll
    for (int off = 1; off < 64; off <<= 1) v += __shfl_xor(v, off, 64);
    if (k == 0) atomicAdd(&pool[gid[r]], v + bout[0]);
}

// =====================================================================================
extern "C" void kernel_launch(void* const* d_in, const int* in_sizes, int n_in, void* d_out,
                              int out_size, void* d_ws, size_t ws_size, hipStream_t stream) {
    if (n_in < 57) return;
    const int* ntype = (const int*)d_in[0];
    const int* src = (const int*)d_in[1];
    const int* dst = (const int*)d_in[2];
    const int* gid = (const int*)d_in[3];
    const float* ang_rot = (const float*)d_in[4];
    const float* ang_ref = (const float*)d_in[5];
    const float* efeats = (const float*)d_in[6];
    const float* emb = (const float*)d_in[7];
    const float* enc_W = (const float*)d_in[8];
    const float* enc_b = (const float*)d_in[9];
    const float* ee_W1 = (const float*)d_in[10];
    const float* ee_b1 = (const float*)d_in[11];
    const float* ee_W2 = (const float*)d_in[12];
    const float* ee_b2 = (const float*)d_in[13];
    const float* enc_bn1_g = (const float*)d_in[14];
    const float* enc_bn1_b = (const float*)d_in[15];
    const float* enc_bn2_g = (const float*)d_in[16];
    const float* enc_bn2_b = (const float*)d_in[17];
    const float* ee_bn1_g = (const float*)d_in[18];
    const float* ee_bn1_b = (const float*)d_in[19];
    const float* ee_bn2_g = (const float*)d_in[20];
    const float* ee_bn2_b = (const float*)d_in[21];
    const float* l0_Wnode = (const float*)d_in[22];
    const float* l0_bnode = (const float*)d_in[23];
    const float* l0_Wni = (const float*)d_in[24];
    const float* l0_Wnj = (const float*)d_in[25];
    const float* l0_Wfij = (const float*)d_in[26];
    const float* l0_attn = (const float*)d_in[27];
    const float* l0_bnn_g = (const float*)d_in[28];
    const float* l0_bnn_b = (const float*)d_in[29];
    const float* l0_bne_g = (const float*)d_in[30];
    const float* l0_bne_b = (const float*)d_in[31];
    const float* l0_Wpn = (const float*)d_in[32];
    const float* l0_bpn = (const float*)d_in[33];
    const float* l0_Wpe = (const float*)d_in[34];
    const float* l0_bpe = (const float*)d_in[35];
    const float* l1_Wnode = (const float*)d_in[36];
    const float* l1_bnode = (const float*)d_in[37];
    const float* l1_Wni = (const float*)d_in[38];
    const float* l1_Wnj = (const float*)d_in[39];
    const float* l1_Wfij = (const float*)d_in[40];
    const float* l1_attn = (const float*)d_in[41];
    const float* l1_bnn_g = (const float*)d_in[42];
    const float* l1_bnn_b = (const float*)d_in[43];
    const float* l1_Wpn = (const float*)d_in[46];
    const float* l1_bpn = (const float*)d_in[47];
    const float* dec_W = (const float*)d_in[50];
    const float* dec_b = (const float*)d_in[51];
    const float* dec_bn_g = (const float*)d_in[52];
    const float* dec_bn_b = (const float*)d_in[53];
    const float* dec_prelu = (const float*)d_in[54];
    const float* dec_Wout = (const float*)d_in[55];
    const float* dec_bout = (const float*)d_in[56];

    float* out = (float*)d_out;
    float* H1 = out;                     // N x 64 (fp32)
    float* H2 = out + (long)NN * 64;     // N x 64 (fp32)
    float* POOL = out + (long)NN * 128;  // G x 1 (fp32)

    char* base = (char*)d_ws;
    size_t off = 0;
    auto alloc = [&](size_t bytes) -> void* {
        off = (off + 255) & ~(size_t)255;
        void* p = base + off;
        off += bytes;
        return p;
    };
    u16* EH = (u16*)alloc((size_t)NE * 64 * 2);
    u16* F128 = (u16*)alloc((size_t)NE * 128 * 2);
    float* EATT = (float*)alloc((size_t)NE * 2 * 4);
    u16* NX = (u16*)alloc((size_t)NN * 64 * 2);
    u16* NI = (u16*)alloc((size_t)NN * 128 * 2);
    u16* NJ = (u16*)alloc((size_t)NN * 128 * 2);
    u16* NHH = (u16*)alloc((size_t)NN * 128 * 2);
    float* HOUT0 = (float*)alloc((size_t)NN * 128 * 4);
    float* HOUT1 = (float*)alloc((size_t)NN * 64 * 4);
    int* ROWPTR = (int*)alloc((size_t)(NN + 1) * 4);
    int* CURS = (int*)alloc((size_t)NN * 4);
    int* EPOS = (int*)alloc((size_t)NE * 4);
    int* ESRC = (int*)alloc((size_t)NE * 4);
    int* BSUM = (int*)alloc((size_t)256 * 4);
    float* RWrot = (float*)alloc(256 * 4);
    float* RWref = (float*)alloc(256 * 4);
    u16* W2T = (u16*)alloc((size_t)64 * 64 * 2);
    u16* WfijT0 = (u16*)alloc((size_t)128 * 64 * 2);
    u16* WfijT1 = (u16*)alloc((size_t)64 * 64 * 2);
    u16* WpeT = (u16*)alloc((size_t)64 * 128 * 2);
    float* STATS = (float*)alloc((size_t)13 * 256 * 4);
    char* zstart = base + ((off + 255) & ~(size_t)255);
    int* DEG = (int*)alloc((size_t)NN * 4);
    float* STATS_RAW = (float*)alloc((size_t)13 * NSLOT * 256 * 4);
    float* RAWEF = (float*)alloc((size_t)NSLOT * 16 * 4);
    char* zend = base + off;
    if (ws_size < off) return;

    u16* T2 = F128 + (size_t)NE * 64;  // NE x 64 bf16
    u16* NX0 = F128;                   // NN x 64 bf16 (node-enc temp)
    u16* NT = F128 + (size_t)NN * 64;  // NN x 64 bf16 (node-enc temp)
    u16* DT0 = NI;
    u16* DT1 = NJ;

    auto RAW = [&](int idx) { return STATS_RAW + (size_t)idx * NSLOT * 256; };
    float* S_enc1 = STATS + 0 * 256;
    float* S_enc2 = STATS + 1 * 256;
    float* S_ee1r = STATS + 2 * 256;
    float* S_ee2r = STATS + 3 * 256;
    float* S_ee1f = STATS + 4 * 256;
    float* S_ee2f = STATS + 5 * 256;
    float* S_bnn0 = STATS + 6 * 256;
    float* S_bne0 = STATS + 7 * 256;
    float* S_bnn1 = STATS + 8 * 256;
    float* S_d0 = STATS + 9 * 256;
    float* S_d1 = STATS + 10 * 256;
    float* S_d2 = STATS + 11 * 256;
    float* S_d3 = STATS + 12 * 256;

    const float invN = 1.f / (float)NN;
    const float invE = 1.f / (float)NE;
    const int GS = 640;
    const int MFB = NE / 64;            // 6250 blocks, 64 rows each (exact)
    const int NB = (NN + 255) / 256;    // scan blocks (196 <= 256)

    hipMemsetAsync(zstart, 0, (size_t)(zend - zstart), stream);
    hipMemsetAsync(POOL, 0, (size_t)NG * 4, stream);

    setup_kernel<<<1, 64, 0, stream>>>(ang_rot, ang_ref, ee_W1, RWrot, RWref);
    wt_kernel<<<(64 * 64 + 255) / 256, 256, 0, stream>>>(ee_W2, W2T, 64, 64);
    wt_kernel<<<(64 * 128 + 255) / 256, 256, 0, stream>>>(l0_Wfij, WfijT0, 64, 128);
    wt_kernel<<<(64 * 64 + 255) / 256, 256, 0, stream>>>(l1_Wfij, WfijT1, 64, 64);
    wt_kernel<<<(128 * 64 + 255) / 256, 256, 0, stream>>>(l0_Wpe, WpeT, 128, 64);

    // ---- CSR build (dst-sorted; shared by both layers) ----
    hist_kernel<<<(NE + 255) / 256, 256, 0, stream>>>(dst, NE, DEG);
    scan_part_kernel<<<NB, 256, 0, stream>>>(DEG, BSUM, NN);
    scan_top_kernel<<<1, 256, 0, stream>>>(BSUM, NB, ROWPTR, NN, NE);
    scan_fill_kernel<<<NB, 256, 0, stream>>>(DEG, BSUM, ROWPTR, CURS, NN);
    fill_kernel<<<(NE + 255) / 256, 256, 0, stream>>>(src, dst, NE, CURS, EPOS, ESRC);

    // ---- node encoder ----
    gather_emb_kernel<<<(NN * 8 + 255) / 256, 256, 0, stream>>>(ntype, emb, NX0, NN);
    colstats_kernel<64, true><<<GS, 256, 0, stream>>>(NX0, NN, RAW(0));
    finalize_stats_kernel<<<1, 256, 0, stream>>>(RAW(0), S_enc1, 128);
    mm_kernel<64, 64, true, false, true, true><<<(NN + 15) / 16, 256, 0, stream>>>(
        NX0, enc_W, enc_b, nullptr, NT, NN, 2, S_enc1, enc_bn1_g, enc_bn1_b, invN, nullptr, 0,
        RAW(1));
    finalize_stats_kernel<<<1, 256, 0, stream>>>(RAW(1), S_enc2, 128);
    bn_act_kernel<<<(NN * 8 + 255) / 256, 256, 0, stream>>>(NT, NX, NN, 64, S_enc2, enc_bn2_g,
                                                            enc_bn2_b, invN, 0);

    // ---- edge encoder (analytic T1 stats + MFMA fused recompute) ----
    efstats_kernel<<<256, 256, 0, stream>>>(efeats, NE, RAWEF);
    ee_stats_kernel<<<1, 128, 0, stream>>>(RAWEF, RWrot, RWref, ee_b1, S_ee1r, S_ee1f, NE);
    for (int br = 0; br < 2; ++br) {
        const float* RW = br ? RWref : RWrot;
        float* S1 = br ? S_ee1f : S_ee1r;
        float* S2 = br ? S_ee2f : S_ee2r;
        int r2 = br ? 5 : 3;
        mfma_ee_kernel<<<MFB, 256, 0, stream>>>(efeats, RW, ee_b1, W2T, ee_b2, T2, NE, S1,
                                                ee_bn1_g, ee_bn1_b, invE, RAW(r2));
        finalize_stats_kernel<<<1, 256, 0, stream>>>(RAW(r2), S2, 128);
        bn_act_kernel<<<(NE * 8 + 255) / 256, 256, 0, stream>>>(T2, EH, NE, 64, S2, ee_bn2_g,
                                                                ee_bn2_b, invE, br);
    }

    // ---- layer 0 (H=2) ----
    mm_kernel<64, 128, true, false, true, false><<<(NN + 7) / 8, 256, 0, stream>>>(
        NX, l0_Wni, nullptr, nullptr, NI, NN, 0, nullptr, nullptr, nullptr, 0.f, nullptr, 0,
        nullptr);
    mm_kernel<64, 128, true, false, true, false><<<(NN + 7) / 8, 256, 0, stream>>>(
        NX, l0_Wnj, nullptr, nullptr, NJ, NN, 0, nullptr, nullptr, nullptr, 0.f, nullptr, 0,
        nullptr);
    mm_kernel<64, 128, true, false, true, false><<<(NN + 7) / 8, 256, 0, stream>>>(
        NX, l0_Wnode, l0_bnode, nullptr, NHH, NN, 0, nullptr, nullptr, nullptr, 0.f, nullptr, 0,
        nullptr);
    mfma_egat_kernel<128, true, true><<<MFB, 256, 0, stream>>>(
        EH, WfijT0, NI, NJ, src, dst, EPOS, l0_attn, F128, EATT, NE, RAW(7));
    finalize_stats_kernel<<<1, 256, 0, stream>>>(RAW(7), S_bne0, 256);
    csr_aggregate_kernel<128, true><<<(NN + 3) / 4, 256, 0, stream>>>(ROWPTR, ESRC, EATT, NHH,
                                                                      HOUT0, NN, RAW(6));
    finalize_stats_kernel<<<1, 256, 0, stream>>>(RAW(6), S_bnn0, 256);
    mm_kernel<128, 64, false, true, false, false><<<(NN + 15) / 16, 256, 0, stream>>>(
        HOUT0, l0_Wpn, l0_bpn, NX, H1, NN, 1, S_bnn0, l0_bnn_g, l0_bnn_b, invN, nullptr, 0,
        nullptr);
    mfma_pe_kernel<<<MFB, 256, 0, stream>>>(F128, WpeT, l0_bpe, EH, NE, S_bne0, l0_bne_g,
                                            l0_bne_b, invE);

    // ---- layer 1 (H=1; edge output dead -> skipped) ----
    mm_kernel<64, 64, false, false, true, false><<<(NN + 15) / 16, 256, 0, stream>>>(
        H1, l1_Wni, nullptr, nullptr, NI, NN, 0, nullptr, nullptr, nullptr, 0.f, nullptr, 0,
        nullptr);
    mm_kernel<64, 64, false, false, true, false><<<(NN + 15) / 16, 256, 0, stream>>>(
        H1, l1_Wnj, nullptr, nullptr, NJ, NN, 0, nullptr, nullptr, nullptr, 0.f, nullptr, 0,
        nullptr);
    mm_kernel<64, 64, false, false, true, false><<<(NN + 15) / 16, 256, 0, stream>>>(
        H1, l1_Wnode, l1_bnode, nullptr, NHH, NN, 0, nullptr, nullptr, nullptr, 0.f, nullptr, 0,
        nullptr);
    mfma_egat_kernel<64, false, false><<<MFB, 256, 0, stream>>>(
        EH, WfijT1, NI, NJ, src, dst, EPOS, l1_attn, nullptr, EATT, NE, nullptr);
    csr_aggregate_kernel<64, true><<<(NN + 7) / 8, 256, 0, stream>>>(ROWPTR, ESRC, EATT, NHH,
                                                                     HOUT1, NN, RAW(8));
    finalize_stats_kernel<<<1, 256, 0, stream>>>(RAW(8), S_bnn1, 128);
    mm_kernel<64, 64, false, false, false, false><<<(NN + 15) / 16, 256, 0, stream>>>(
        HOUT1, l1_Wpn, l1_bpn, H1, H2, NN, 1, S_bnn1, l1_bnn_g, l1_bnn_b, invN, nullptr, 0,
        nullptr);

    // ---- decoder ----
    mm_kernel<64, 64, false, false, true, true><<<(NN + 15) / 16, 256, 0, stream>>>(
        H2, dec_W, dec_b, nullptr, DT0, NN, 0, nullptr, nullptr, nullptr, 0.f, nullptr, 0, RAW(9));
    finalize_stats_kernel<<<1, 256, 0, stream>>>(RAW(9), S_d0, 128);
    mm_kernel<64, 64, true, false, true, true><<<(NN + 15) / 16, 256, 0, stream>>>(
        DT0, dec_W + 4096, dec_b + 64, nullptr, DT1, NN, 3, S_d0, dec_bn_g, dec_bn_b, invN,
        dec_prelu, 0, RAW(10));
    finalize_stats_kernel<<<1, 256, 0, stream>>>(RAW(10), S_d1, 128);
    mm_kernel<64, 64, true, false, true, true><<<(NN + 15) / 16, 256, 0, stream>>>(
        DT1, dec_W + 8192, dec_b + 128, nullptr, DT0, NN, 3, S_d1, dec_bn_g + 64, dec_bn_b + 64,
        invN, dec_prelu, 1, RAW(11));
    finalize_stats_kernel<<<1, 256, 0, stream>>>(RAW(11), S_d2, 128);
    mm_kernel<64, 64, true, false, true, true><<<(NN + 15) / 16, 256, 0, stream>>>(
        DT0, dec_W + 12288, dec_b + 192, nullptr, DT1, NN, 3, S_d2, dec_bn_g + 128,
        dec_bn_b + 128, invN, dec_prelu, 2, RAW(12));
    finalize_stats_kernel<<<1, 256, 0, stream>>>(RAW(12), S_d3, 128);
    decoder_out_kernel<<<(NN + 3) / 4, 256, 0, stream>>>(DT1, S_d3, dec_bn_g + 192,
                                                         dec_bn_b + 192, dec_prelu, dec_Wout,
                                                         dec_bout, gid, POOL, NN, invN);
}

// Round 8
// 864.173 us; speedup vs baseline: 2.1154x; 1.1984x over previous
//
#include <hip/hip_runtime.h>
#include <math.h>

#define NN 50000
#define NE 400000
#define NG 512
#define EPS 1e-5f
#define NSLOT 256  // stats replica slots (atomic contention spreading)

typedef unsigned int u32;
typedef unsigned short u16;

typedef __attribute__((ext_vector_type(8))) short s16x8;  // 8 bf16 (4 VGPRs)
typedef __attribute__((ext_vector_type(4))) float f32x4;

__device__ __forceinline__ float b2f(u16 h) { return __uint_as_float(((u32)h) << 16); }
__device__ __forceinline__ u16 f2b(float f) {
    u32 x = __float_as_uint(f);
    u32 r = x + 0x7fffu + ((x >> 16) & 1u);
    return (u16)(r >> 16);
}
struct alignas(16) U16x8 { u16 s[8]; };
struct alignas(8) U16x4 { u16 s[4]; };
struct alignas(4) U16x2 { u16 s[2]; };

__device__ __forceinline__ void f4add(float4& a, const float4 b) {
    a.x += b.x; a.y += b.y; a.z += b.z; a.w += b.w;
}

// ---------------- setup: fold rotation matrices into ee_W1 (fp32) ----------------
__global__ void setup_kernel(const float* __restrict__ ang_rot, const float* __restrict__ ang_ref,
                             const float* __restrict__ W1, float* __restrict__ RWrot,
                             float* __restrict__ RWref) {
    int c = threadIdx.x;  // 64
    for (int which = 0; which < 2; ++which) {
        const float* a = which ? ang_ref : ang_rot;
        float t = a[0], p = a[1], q = a[2];
        float ct = cosf(t), st = sinf(t);
        float cp = cosf(p), sp = sinf(p);
        float cq = cosf(q), sq = sinf(q);
        float Rt[3][3] = {{ct, -st, 0.f}, {st, ct, 0.f}, {0.f, 0.f, 1.f}};
        float Rp[3][3] = {{cp, 0.f, -sp}, {0.f, 1.f, 0.f}, {sp, 0.f, cp}};
        float Rq[3][3] = {{1.f, 0.f, 0.f}, {0.f, cq, -sq}, {0.f, sq, cq}};
        float Rtp[3][3], R[3][3];
        for (int i = 0; i < 3; ++i)
            for (int j = 0; j < 3; ++j) {
                float s = 0.f;
                for (int k = 0; k < 3; ++k) s += Rt[i][k] * Rp[k][j];
                Rtp[i][j] = s;
            }
        for (int i = 0; i < 3; ++i)
            for (int j = 0; j < 3; ++j) {
                float s = 0.f;
                for (int k = 0; k < 3; ++k) s += Rtp[i][k] * Rq[k][j];
                R[i][j] = s;
            }
        float sgn = which ? -1.f : 1.f;  // R_ref = -rotmat(angles_ref)
        float* RW = which ? RWref : RWrot;
        if (c < 64) {
            for (int j = 0; j < 3; ++j) {
                float s = 0.f;
                for (int m = 0; m < 3; ++m) s += sgn * R[j][m] * W1[m * 64 + c];
                RW[j * 64 + c] = s;  // RW = R @ W1  (3 x 64)
            }
        }
    }
}

// ---------------- batched weight transpose: W [K][C] fp32 -> WT [C][K] bf16 ----------------
#define NWT 17
struct WtJobs {
    const float* W[NWT];
    u16* WT[NWT];
    int K[NWT];
    int C[NWT];
};
__global__ __launch_bounds__(256) void wt_all_kernel(WtJobs jobs) {
    int job = blockIdx.x >> 5;
    int idx = ((blockIdx.x & 31) << 8) + threadIdx.x;
    int K = jobs.K[job], C = jobs.C[job];
    if (idx >= K * C) return;
    int k = idx / C, c = idx - k * C;
    jobs.WT[job][c * K + k] = f2b(jobs.W[job][idx]);
}

// ---------------- CSR build: degree hist -> 3-phase scan -> fill ----------------
__global__ __launch_bounds__(256) void hist_kernel(const int* __restrict__ dst, int E,
                                                   int* __restrict__ deg) {
    int e = blockIdx.x * 256 + threadIdx.x;
    if (e < E) atomicAdd(&deg[dst[e]], 1);
}

__global__ __launch_bounds__(256) void scan_part_kernel(const int* __restrict__ deg,
                                                        int* __restrict__ bsum, int n) {
    int i = blockIdx.x * 256 + threadIdx.x;
    int v = (i < n) ? deg[i] : 0;
#pragma unroll
    for (int off = 1; off < 64; off <<= 1) v += __shfl_xor(v, off, 64);
    __shared__ int ws[4];
    if ((threadIdx.x & 63) == 0) ws[threadIdx.x >> 6] = v;
    __syncthreads();
    if (threadIdx.x == 0) bsum[blockIdx.x] = ws[0] + ws[1] + ws[2] + ws[3];
}

__global__ __launch_bounds__(256) void scan_top_kernel(int* __restrict__ bsum, int nb,
                                                       int* __restrict__ rowptr, int n,
                                                       int total) {
    __shared__ int s[256];
    int tid = threadIdx.x;
    s[tid] = (tid < nb) ? bsum[tid] : 0;
    __syncthreads();
    for (int off = 1; off < 256; off <<= 1) {
        int v = (tid >= off) ? s[tid - off] : 0;
        __syncthreads();
        s[tid] += v;
        __syncthreads();
    }
    if (tid < nb) bsum[tid] = (tid == 0) ? 0 : s[tid - 1];
    if (tid == 0) rowptr[n] = total;
}

__global__ __launch_bounds__(256) void scan_fill_kernel(const int* __restrict__ deg,
                                                        const int* __restrict__ bsum,
                                                        int* __restrict__ rowptr,
                                                        int* __restrict__ curs, int n) {
    __shared__ int s[256];
    int tid = threadIdx.x;
    int i = blockIdx.x * 256 + tid;
    int v = (i < n) ? deg[i] : 0;
    s[tid] = v;
    __syncthreads();
    for (int off = 1; off < 256; off <<= 1) {
        int t = (tid >= off) ? s[tid - off] : 0;
        __syncthreads();
        s[tid] += t;
        __syncthreads();
    }
    if (i < n) {
        int excl = s[tid] - v + bsum[blockIdx.x];
        rowptr[i] = excl;
        curs[i] = excl;
    }
}

__global__ __launch_bounds__(256) void fill_kernel(const int* __restrict__ src,
                                                   const int* __restrict__ dst, int E,
                                                   int* __restrict__ curs,
                                                   int* __restrict__ epos,
                                                   int* __restrict__ esrc) {
    int e = blockIdx.x * 256 + threadIdx.x;
    if (e >= E) return;
    int pos = atomicAdd(&curs[dst[e]], 1);
    epos[e] = pos;
    esrc[pos] = src[e];
}

// ---------------- embedding gather: fp32 table -> bf16 out ----------------
__global__ __launch_bounds__(256) void gather_emb_kernel(const int* __restrict__ ntype,
                                                         const float* __restrict__ emb,
                                                         u16* __restrict__ out, int n) {
    long i = (long)blockIdx.x * 256 + threadIdx.x;  // over n*8
    long e = i >> 3;
    if (e >= n) return;
    int c0 = (int)(i & 7) * 8;
    int t = ntype[e];
    float4 a = *(const float4*)&emb[(long)t * 64 + c0];
    float4 b = *(const float4*)&emb[(long)t * 64 + c0 + 4];
    U16x8 o;
    o.s[0] = f2b(a.x); o.s[1] = f2b(a.y); o.s[2] = f2b(a.z); o.s[3] = f2b(a.w);
    o.s[4] = f2b(b.x); o.s[5] = f2b(b.y); o.s[6] = f2b(b.z); o.s[7] = f2b(b.w);
    *(U16x8*)&out[e * 64 + c0] = o;
}

// ---------------- efeats second moments: 9 scalars -> replica slots ----------------
__global__ __launch_bounds__(256) void efstats_kernel(const float* __restrict__ ef, int E,
                                                      float* __restrict__ raw) {
    int tid = threadIdx.x;
    float a[9];
#pragma unroll
    for (int j = 0; j < 9; ++j) a[j] = 0.f;
    for (long e = (long)blockIdx.x * 256 + tid; e < E; e += (long)gridDim.x * 256) {
        float f0 = ef[e * 3 + 0], f1 = ef[e * 3 + 1], f2 = ef[e * 3 + 2];
        a[0] += f0; a[1] += f1; a[2] += f2;
        a[3] += f0 * f0; a[4] += f1 * f1; a[5] += f2 * f2;
        a[6] += f0 * f1; a[7] += f0 * f2; a[8] += f1 * f2;
    }
#pragma unroll
    for (int off = 1; off < 64; off <<= 1)
#pragma unroll
        for (int j = 0; j < 9; ++j) a[j] += __shfl_xor(a[j], off, 64);
    __shared__ float sred[4][9];
    int wv = tid >> 6, ln = tid & 63;
    if (ln == 0)
#pragma unroll
        for (int j = 0; j < 9; ++j) sred[wv][j] = a[j];
    __syncthreads();
    if (tid < 9) {
        float v = sred[0][tid] + sred[1][tid] + sred[2][tid] + sred[3][tid];
        atomicAdd(&raw[(size_t)(blockIdx.x & (NSLOT - 1)) * 16 + tid], v);
    }
}

// ---------------- analytic T1 column stats for both branches ----------------
__global__ void ee_stats_kernel(const float* __restrict__ efraw, const float* __restrict__ RWrot,
                                const float* __restrict__ RWref, const float* __restrict__ b1,
                                float* __restrict__ S_rot, float* __restrict__ S_ref, int E) {
    __shared__ float m[9];
    int t = threadIdx.x;  // 128
    if (t < 9) {
        float s = 0.f;
        for (int r = 0; r < NSLOT; ++r) s += efraw[r * 16 + t];
        m[t] = s;
    }
    __syncthreads();
    int br = t >> 6, c = t & 63;
    const float* RW = br ? RWref : RWrot;
    float* S = br ? S_ref : S_rot;
    float w0 = RW[c], w1 = RW[64 + c], w2 = RW[128 + c];
    float bb = b1[c];
    float mw = m[0] * w0 + m[1] * w1 + m[2] * w2;
    float sum = mw + (float)E * bb;
    float quad = m[3] * w0 * w0 + m[4] * w1 * w1 + m[5] * w2 * w2 +
                 2.f * (m[6] * w0 * w1 + m[7] * w0 * w2 + m[8] * w1 * w2);
    float ss = quad + 2.f * bb * mw + (float)E * bb * bb;
    S[c] = sum;
    S[64 + c] = ss;
}

// ---------------- column stats (bf16 input) -> replicated raw accumulators ----------------
template <int COLS>
__global__ __launch_bounds__(256) void colstats_kernel(const u16* __restrict__ xv, int rows,
                                                       float* __restrict__ raw) {
    constexpr int TPR = COLS / 8;
    constexpr int RPB = 256 / TPR;
    __shared__ float4 sA[256], sB[256], sC[256], sD[256];
    int tid = threadIdx.x;
    int c8 = tid % TPR;
    int rl = tid / TPR;
    float s[8], q[8];
#pragma unroll
    for (int j = 0; j < 8; ++j) { s[j] = 0.f; q[j] = 0.f; }
    const long stride = (long)gridDim.x * RPB;
    for (long r = (long)blockIdx.x * RPB + rl; r < rows; r += stride) {
        U16x8 t = *(const U16x8*)&xv[r * COLS + c8 * 8];
#pragma unroll
        for (int j = 0; j < 8; ++j) {
            float v = b2f(t.s[j]);
            s[j] += v;
            q[j] += v * v;
        }
    }
    sA[tid] = make_float4(s[0], s[1], s[2], s[3]);
    sB[tid] = make_float4(s[4], s[5], s[6], s[7]);
    sC[tid] = make_float4(q[0], q[1], q[2], q[3]);
    sD[tid] = make_float4(q[4], q[5], q[6], q[7]);
    __syncthreads();
    for (int off = 128; off >= TPR; off >>= 1) {
        if (tid < off) {
            f4add(sA[tid], sA[tid + off]); f4add(sB[tid], sB[tid + off]);
            f4add(sC[tid], sC[tid + off]); f4add(sD[tid], sD[tid + off]);
        }
        __syncthreads();
    }
    if (tid < TPR) {
        float* slot = raw + (size_t)(blockIdx.x & (NSLOT - 1)) * 256;
        int c = tid * 8;
        float4 a = sA[tid], b = sB[tid], cq = sC[tid], d = sD[tid];
        atomicAdd(&slot[c + 0], a.x); atomicAdd(&slot[c + 1], a.y);
        atomicAdd(&slot[c + 2], a.z); atomicAdd(&slot[c + 3], a.w);
        atomicAdd(&slot[c + 4], b.x); atomicAdd(&slot[c + 5], b.y);
        atomicAdd(&slot[c + 6], b.z); atomicAdd(&slot[c + 7], b.w);
        atomicAdd(&slot[COLS + c + 0], cq.x); atomicAdd(&slot[COLS + c + 1], cq.y);
        atomicAdd(&slot[COLS + c + 2], cq.z); atomicAdd(&slot[COLS + c + 3], cq.w);
        atomicAdd(&slot[COLS + c + 4], d.x); atomicAdd(&slot[COLS + c + 5], d.y);
        atomicAdd(&slot[COLS + c + 6], d.z); atomicAdd(&slot[COLS + c + 7], d.w);
    }
}

// ---------------- reduce NSLOT replica slots -> final stats ----------------
__global__ __launch_bounds__(256) void finalize_stats_kernel(const float* __restrict__ raw,
                                                             float* __restrict__ stats, int n) {
    int i = threadIdx.x;
    if (i >= n) return;
    float s = 0.f;
    for (int r = 0; r < NSLOT; ++r) s += raw[r * 256 + i];
    stats[i] = s;
}

// ---------------- y = relu(bn(x)), bf16 (node-enc bn2) ----------------
__global__ __launch_bounds__(256) void bn_act_kernel(const u16* __restrict__ x,
                                                     u16* __restrict__ y, long rows, int cols,
                                                     const float* __restrict__ acc,
                                                     const float* __restrict__ g,
                                                     const float* __restrict__ b,
                                                     float inv_rows) {
    long i = (long)blockIdx.x * 256 + threadIdx.x;
    long total8 = rows * (long)cols / 8;
    if (i >= total8) return;
    long base = i * 8;
    int c0 = (int)(base % cols);
    U16x8 xv = *(const U16x8*)&x[base];
    U16x8 o;
#pragma unroll
    for (int j = 0; j < 8; ++j) {
        int c = c0 + j;
        float mu = acc[c] * inv_rows;
        float var = acc[cols + c] * inv_rows - mu * mu;
        float al = g[c] * rsqrtf(fmaxf(var, 0.f) + EPS);
        float be = b[c] - mu * al;
        o.s[j] = f2b(fmaxf(al * b2f(xv.s[j]) + be, 0.f));
    }
    *(U16x8*)&y[base] = o;
}

// ---------------- EH = relu(bn_a(T2a)) + relu(bn_b(T2b)) ----------------
__global__ __launch_bounds__(256) void ee_merge_kernel(
    const u16* __restrict__ A, const u16* __restrict__ B, u16* __restrict__ EH,
    const float* __restrict__ Sa, const float* __restrict__ Sb, const float* __restrict__ g,
    const float* __restrict__ b, float inv_rows) {
    __shared__ float ala[64], bea[64], alb[64], beb[64];
    int tid = threadIdx.x;
    if (tid < 64) {
        float mu = Sa[tid] * inv_rows;
        float var = Sa[64 + tid] * inv_rows - mu * mu;
        float a = g[tid] * rsqrtf(fmaxf(var, 0.f) + EPS);
        ala[tid] = a; bea[tid] = b[tid] - mu * a;
        mu = Sb[tid] * inv_rows;
        var = Sb[64 + tid] * inv_rows - mu * mu;
        a = g[tid] * rsqrtf(fmaxf(var, 0.f) + EPS);
        alb[tid] = a; beb[tid] = b[tid] - mu * a;
    }
    __syncthreads();
    long i = (long)blockIdx.x * 256 + tid;  // over NE*8
    if (i >= (long)NE * 8) return;
    long base = i * 8;
    int c0 = (int)(base & 63);
    U16x8 xa = *(const U16x8*)&A[base];
    U16x8 xb = *(const U16x8*)&B[base];
    U16x8 o;
#pragma unroll
    for (int j = 0; j < 8; ++j) {
        int c = c0 + j;
        float va = fmaxf(ala[c] * b2f(xa.s[j]) + bea[c], 0.f);
        float vb = fmaxf(alb[c] * b2f(xb.s[j]) + beb[c], 0.f);
        o.s[j] = f2b(va + vb);
    }
    *(U16x8*)&EH[base] = o;
}

// ================= MFMA kernels =================
// Fragment layout (guide §3, m89/m91/m92 verified):
//   A: lane l holds A[row=l&15][k=(l>>4)*8+j]
//   B: lane l holds B[k=(l>>4)*8+j][col=l&15]  (8 contiguous bf16 from W^T row)
//   D: lane l reg r holds D[row=(l>>4)*4+r][col=l&15]
// Block = 4 waves = 64 rows. NE%64==0; NN%16==0 (tail waves skip).

// ---- generic: Y = preop(X) @ W (+bias)(+res), optional fused col-stats ----
// preop: 0 none, 1 bn, 2 bn+relu, 3 bn+prelu(scalar)
template <int K, int COLS, bool XBF, bool RBF, bool OBF, bool SOUT>
__global__ __launch_bounds__(256) void mfma_mm_kernel(
    const void* __restrict__ Xv, const u16* __restrict__ WT, const float* __restrict__ bias,
    const void* __restrict__ resv, void* __restrict__ Yv, int rows, int preop,
    const float* __restrict__ stats, const float* __restrict__ g, const float* __restrict__ b,
    float inv_rows, const float* __restrict__ prelu, int prelu_idx, float* __restrict__ raw) {
    constexpr int NCT = COLS / 16;
    constexpr int NKK = K / 32;
    __shared__ float al[K], be[K];
    __shared__ float ssum[SOUT ? COLS : 1], ssq[SOUT ? COLS : 1];
    const int tid = threadIdx.x;
    if (preop) {
        for (int k = tid; k < K; k += 256) {
            float mu = stats[k] * inv_rows;
            float var = stats[K + k] * inv_rows - mu * mu;
            float a = g[k] * rsqrtf(fmaxf(var, 0.f) + EPS);
            al[k] = a;
            be[k] = b[k] - mu * a;
        }
    }
    if (SOUT) {
        for (int i = tid; i < COLS; i += 256) { ssum[i] = 0.f; ssq[i] = 0.f; }
    }
    __syncthreads();
    const int lane = tid & 63, wv = tid >> 6;
    const int q = lane >> 4, rr = lane & 15;
    const long r0 = ((long)blockIdx.x * 4 + wv) * 16;
    const bool act = r0 < rows;
    const float pa = (preop == 3) ? prelu[prelu_idx] : 0.f;
    s16x8 afr[NKK];
    if (act) {
#pragma unroll
        for (int kk = 0; kk < NKK; ++kk) {
            float v[8];
            if (XBF) {
                U16x8 t = *(const U16x8*)((const u16*)Xv + (r0 + rr) * K + kk * 32 + q * 8);
#pragma unroll
                for (int j = 0; j < 8; ++j) v[j] = b2f(t.s[j]);
            } else {
                const float* xp = (const float*)Xv + (r0 + rr) * K + kk * 32 + q * 8;
                float4 t0 = *(const float4*)xp;
                float4 t1 = *(const float4*)(xp + 4);
                v[0] = t0.x; v[1] = t0.y; v[2] = t0.z; v[3] = t0.w;
                v[4] = t1.x; v[5] = t1.y; v[6] = t1.z; v[7] = t1.w;
            }
            union { u16 u[8]; s16x8 s; } o;
#pragma unroll
            for (int j = 0; j < 8; ++j) {
                float xx = v[j];
                if (preop) {
                    int k = kk * 32 + q * 8 + j;
                    xx = al[k] * xx + be[k];
                    if (preop == 2) xx = fmaxf(xx, 0.f);
                    else if (preop == 3) xx = (xx >= 0.f) ? xx : pa * xx;
                }
                o.u[j] = f2b(xx);
            }
            afr[kk] = o.s;
        }
#pragma unroll
        for (int ct = 0; ct < NCT; ++ct) {
            f32x4 acc = (f32x4){0.f, 0.f, 0.f, 0.f};
#pragma unroll
            for (int kk = 0; kk < NKK; ++kk) {
                s16x8 bfr = *(const s16x8*)&WT[(size_t)(ct * 16 + rr) * K + kk * 32 + q * 8];
                acc = __builtin_amdgcn_mfma_f32_16x16x32_bf16(afr[kk], bfr, acc, 0, 0, 0);
            }
            int col = ct * 16 + rr;
            float bb = bias ? bias[col] : 0.f;
            float fs = 0.f, fq = 0.f;
#pragma unroll
            for (int r = 0; r < 4; ++r) {
                long orr = r0 + q * 4 + r;
                float vv = acc[r] + bb;
                if (resv) {
                    if (RBF) vv += b2f(((const u16*)resv)[orr * COLS + col]);
                    else vv += ((const float*)resv)[orr * COLS + col];
                }
                if (OBF) ((u16*)Yv)[orr * COLS + col] = f2b(vv);
                else ((float*)Yv)[orr * COLS + col] = vv;
                if (SOUT) { fs += vv; fq += vv * vv; }
            }
            if (SOUT) {
                fs += __shfl_xor(fs, 16, 64); fs += __shfl_xor(fs, 32, 64);
                fq += __shfl_xor(fq, 16, 64); fq += __shfl_xor(fq, 32, 64);
                if (q == 0) {
                    atomicAdd(&ssum[col], fs);
                    atomicAdd(&ssq[col], fq);
                }
            }
        }
    }
    if (SOUT) {
        __syncthreads();
        float* slot = raw + (size_t)(blockIdx.x & (NSLOT - 1)) * 256;
        for (int i = tid; i < COLS; i += 256) {
            atomicAdd(&slot[i], ssum[i]);
            atomicAdd(&slot[COLS + i], ssq[i]);
        }
    }
}

// ---- 3 matmuls sharing the A operand: Y0 = X@W0, Y1 = X@W1, Y2 = X@W2 + bias2 ----
template <int COLS, bool XBF>
__global__ __launch_bounds__(256) void mfma_mm3_kernel(
    const void* __restrict__ Xv, const u16* __restrict__ WT0, const u16* __restrict__ WT1,
    const u16* __restrict__ WT2, const float* __restrict__ bias2, u16* __restrict__ Y0,
    u16* __restrict__ Y1, u16* __restrict__ Y2, int rows) {
    constexpr int NCT = COLS / 16;
    const int tid = threadIdx.x;
    const int lane = tid & 63, wv = tid >> 6;
    const int q = lane >> 4, rr = lane & 15;
    const long r0 = ((long)blockIdx.x * 4 + wv) * 16;
    if (r0 >= rows) return;
    s16x8 afr[2];
#pragma unroll
    for (int kk = 0; kk < 2; ++kk) {
        if (XBF) {
            afr[kk] = *(const s16x8*)((const u16*)Xv + (r0 + rr) * 64 + kk * 32 + q * 8);
        } else {
            const float* xp = (const float*)Xv + (r0 + rr) * 64 + kk * 32 + q * 8;
            float4 t0 = *(const float4*)xp;
            float4 t1 = *(const float4*)(xp + 4);
            union { u16 u[8]; s16x8 s; } o;
            o.u[0] = f2b(t0.x); o.u[1] = f2b(t0.y); o.u[2] = f2b(t0.z); o.u[3] = f2b(t0.w);
            o.u[4] = f2b(t1.x); o.u[5] = f2b(t1.y); o.u[6] = f2b(t1.z); o.u[7] = f2b(t1.w);
            afr[kk] = o.s;
        }
    }
    const u16* wts[3] = {WT0, WT1, WT2};
    u16* ys[3] = {Y0, Y1, Y2};
#pragma unroll
    for (int m = 0; m < 3; ++m) {
#pragma unroll
        for (int ct = 0; ct < NCT; ++ct) {
            f32x4 acc = (f32x4){0.f, 0.f, 0.f, 0.f};
#pragma unroll
            for (int kk = 0; kk < 2; ++kk) {
                s16x8 bfr = *(const s16x8*)&wts[m][(size_t)(ct * 16 + rr) * 64 + kk * 32 + q * 8];
                acc = __builtin_amdgcn_mfma_f32_16x16x32_bf16(afr[kk], bfr, acc, 0, 0, 0);
            }
            int col = ct * 16 + rr;
            float bb = (m == 2) ? bias2[col] : 0.f;
#pragma unroll
            for (int r = 0; r < 4; ++r) {
                long orr = r0 + q * 4 + r;
                ys[m][orr * COLS + col] = f2b(acc[r] + bb);
            }
        }
    }
}

// ---- T2 = relu(bn1(ef@RW + b1)) @ W2 + b2 (T1 generated in-register) + col-stats ----
__global__ __launch_bounds__(256) void mfma_ee_kernel(
    const float* __restrict__ ef, const float* __restrict__ RW, const float* __restrict__ b1v,
    const u16* __restrict__ W2T, const float* __restrict__ b2, u16* __restrict__ T2, int E,
    const float* __restrict__ stats, const float* __restrict__ g, const float* __restrict__ b,
    float inv_rows, float* __restrict__ raw) {
    __shared__ float rws[192];
    __shared__ float al[64], be[64];
    __shared__ float ssum[64], ssq[64];
    const int tid = threadIdx.x;
    if (tid < 192) rws[tid] = RW[tid];
    if (tid < 64) {
        float mu = stats[tid] * inv_rows;
        float var = stats[64 + tid] * inv_rows - mu * mu;
        float a = g[tid] * rsqrtf(fmaxf(var, 0.f) + EPS);
        al[tid] = a;
        be[tid] = b[tid] - mu * a + a * b1v[tid];  // fold b1 into affine
        ssum[tid] = 0.f;
        ssq[tid] = 0.f;
    }
    __syncthreads();
    const int lane = tid & 63, wv = tid >> 6;
    const int q = lane >> 4, rr = lane & 15;
    const long r0 = ((long)blockIdx.x * 4 + wv) * 16;
    const long ar = r0 + rr;
    float e0 = ef[ar * 3], e1 = ef[ar * 3 + 1], e2 = ef[ar * 3 + 2];
    s16x8 afr[2];
#pragma unroll
    for (int kk = 0; kk < 2; ++kk) {
        union { u16 u[8]; s16x8 v; } t;
#pragma unroll
        for (int j = 0; j < 8; ++j) {
            int k = kk * 32 + q * 8 + j;
            float tv = e0 * rws[k] + e1 * rws[64 + k] + e2 * rws[128 + k];
            t.u[j] = f2b(fmaxf(al[k] * tv + be[k], 0.f));
        }
        afr[kk] = t.v;
    }
    f32x4 acc[4];
#pragma unroll
    for (int ct = 0; ct < 4; ++ct) {
        acc[ct] = (f32x4){0.f, 0.f, 0.f, 0.f};
#pragma unroll
        for (int kk = 0; kk < 2; ++kk) {
            s16x8 bfr = *(const s16x8*)&W2T[(size_t)(ct * 16 + rr) * 64 + kk * 32 + q * 8];
            acc[ct] = __builtin_amdgcn_mfma_f32_16x16x32_bf16(afr[kk], bfr, acc[ct], 0, 0, 0);
        }
    }
#pragma unroll
    for (int ct = 0; ct < 4; ++ct) {
        int col = ct * 16 + rr;
        float bb = b2[col];
        float s = 0.f, qq = 0.f;
#pragma unroll
        for (int r = 0; r < 4; ++r) {
            long orr = r0 + q * 4 + r;
            float v = acc[ct][r] + bb;
            T2[orr * 64 + col] = f2b(v);
            s += v;
            qq += v * v;
        }
        s += __shfl_xor(s, 16, 64); s += __shfl_xor(s, 32, 64);
        qq += __shfl_xor(qq, 16, 64); qq += __shfl_xor(qq, 32, 64);
        if (q == 0) {
            atomicAdd(&ssum[col], s);
            atomicAdd(&ssq[col], qq);
        }
    }
    __syncthreads();
    if (tid < 64) {
        float* slot = raw + (size_t)(blockIdx.x & (NSLOT - 1)) * 256;
        atomicAdd(&slot[tid], ssum[tid]);
        atomicAdd(&slot[64 + tid], ssq[tid]);
    }
}

// ---- f = leaky(EH@Wfij + NI[src] + NJ[dst]); att scores -> CSR slots; opt col-stats ----
// WRITE_F path stages F through padded LDS for coalesced 256B-row stores.
template <int COLS, bool WRITE_F, bool SOUT>
__global__ __launch_bounds__(256) void mfma_egat_kernel(
    const u16* __restrict__ EH, const u16* __restrict__ WT, const u16* __restrict__ NI,
    const u16* __restrict__ NJ, const int* __restrict__ src, const int* __restrict__ dst,
    const int* __restrict__ epos, const float* __restrict__ attn, u16* __restrict__ Fout,
    float* __restrict__ eatt, int E, float* __restrict__ raw) {
    constexpr int H = COLS / 64;
    constexpr int NCT = COLS / 16;
    constexpr int FSTR = COLS + 8;  // padded LDS row stride (bank spread)
    __shared__ float ssum[SOUT ? COLS : 1];
    __shared__ float ssq[SOUT ? COLS : 1];
    __shared__ u16 fts[WRITE_F ? 64 * FSTR : 1];
    const int tid = threadIdx.x;
    if (SOUT) {
        for (int i = tid; i < COLS; i += 256) { ssum[i] = 0.f; ssq[i] = 0.f; }
        __syncthreads();
    }
    const int lane = tid & 63, wv = tid >> 6;
    const int q = lane >> 4, rr = lane & 15;
    const long r0 = ((long)blockIdx.x * 4 + wv) * 16;
    s16x8 afr[2];
#pragma unroll
    for (int kk = 0; kk < 2; ++kk)
        afr[kk] = *(const s16x8*)&EH[(r0 + rr) * 64 + kk * 32 + q * 8];
    int sidx[4], didx[4];
#pragma unroll
    for (int r = 0; r < 4; ++r) {
        long orr = r0 + q * 4 + r;
        sidx[r] = src[orr];
        didx[r] = dst[orr];
    }
    f32x4 acc[NCT];
#pragma unroll
    for (int ct = 0; ct < NCT; ++ct) {
        acc[ct] = (f32x4){0.f, 0.f, 0.f, 0.f};
#pragma unroll
        for (int kk = 0; kk < 2; ++kk) {
            s16x8 bfr = *(const s16x8*)&WT[(size_t)(ct * 16 + rr) * 64 + kk * 32 + q * 8];
            acc[ct] = __builtin_amdgcn_mfma_f32_16x16x32_bf16(afr[kk], bfr, acc[ct], 0, 0, 0);
        }
    }
    float part[H][4];
#pragma unroll
    for (int h = 0; h < H; ++h)
#pragma unroll
        for (int r = 0; r < 4; ++r) part[h][r] = 0.f;
#pragma unroll
    for (int ct = 0; ct < NCT; ++ct) {
        int col = ct * 16 + rr;
        float av = attn[col];
        const int h = (H == 2) ? (ct >> 2) : 0;
        float fs = 0.f, fq = 0.f;
#pragma unroll
        for (int r = 0; r < 4; ++r) {
            float f = acc[ct][r] + b2f(NI[(size_t)sidx[r] * COLS + col]) +
                      b2f(NJ[(size_t)didx[r] * COLS + col]);
            f = (f >= 0.f) ? f : 0.01f * f;
            if (WRITE_F) fts[(wv * 16 + q * 4 + r) * FSTR + col] = f2b(f);
            part[h][r] += f * av;
            if (SOUT) { fs += f; fq += f * f; }
        }
        if (SOUT) {
            fs += __shfl_xor(fs, 16, 64); fs += __shfl_xor(fs, 32, 64);
            fq += __shfl_xor(fq, 16, 64); fq += __shfl_xor(fq, 32, 64);
            if (q == 0) {
                atomicAdd(&ssum[col], fs);
                atomicAdd(&ssq[col], fq);
            }
        }
    }
#pragma unroll
    for (int h = 0; h < H; ++h)
#pragma unroll
        for (int r = 0; r < 4; ++r) {
            float p = part[h][r];
            p += __shfl_xor(p, 1, 64);
            p += __shfl_xor(p, 2, 64);
            p += __shfl_xor(p, 4, 64);
            p += __shfl_xor(p, 8, 64);
            part[h][r] = p;
        }
    if (rr == 0) {
#pragma unroll
        for (int r = 0; r < 4; ++r) {
            long pos = epos[r0 + q * 4 + r];
            if (H == 2) {
                eatt[pos * 2 + 0] = part[0][r];
                eatt[pos * 2 + 1] = part[1][r];
            } else {
                eatt[pos] = part[0][r];
            }
        }
    }
    if (WRITE_F) {
        __syncthreads();
        const long rb = (long)blockIdx.x * 64;
        constexpr int CH = COLS / 8;  // 8-u16 chunks per row
        for (int i = tid; i < 64 * CH; i += 256) {
            int row = i / CH, c8 = i % CH;
            U16x8 v = *(const U16x8*)&fts[row * FSTR + c8 * 8];
            *(U16x8*)&Fout[(rb + row) * COLS + c8 * 8] = v;
        }
    }
    if (SOUT) {
        __syncthreads();
        float* slot = raw + (size_t)(blockIdx.x & (NSLOT - 1)) * 256;
        for (int i = tid; i < COLS; i += 256) {
            atomicAdd(&slot[i], ssum[i]);
            atomicAdd(&slot[COLS + i], ssq[i]);
        }
    }
}

// ---- EH = bn(F128)@Wpe + bpe + EH (K=128, in-place residual) ----
__global__ __launch_bounds__(256) void mfma_pe_kernel(
    const u16* __restrict__ X, const u16* __restrict__ WT, const float* __restrict__ bias,
    u16* __restrict__ EHio, int E, const float* __restrict__ stats, const float* __restrict__ g,
    const float* __restrict__ b, float inv_rows) {
    __shared__ float al[128], be[128];
    const int tid = threadIdx.x;
    if (tid < 128) {
        float mu = stats[tid] * inv_rows;
        float var = stats[128 + tid] * inv_rows - mu * mu;
        float a = g[tid] * rsqrtf(fmaxf(var, 0.f) + EPS);
        al[tid] = a;
        be[tid] = b[tid] - mu * a;
    }
    __syncthreads();
    const int lane = tid & 63, wv = tid >> 6;
    const int q = lane >> 4, rr = lane & 15;
    const long r0 = ((long)blockIdx.x * 4 + wv) * 16;
    s16x8 afr[4];
#pragma unroll
    for (int kk = 0; kk < 4; ++kk) {
        U16x8 t = *(const U16x8*)&X[(r0 + rr) * 128 + kk * 32 + q * 8];
        union { u16 u[8]; s16x8 v; } o;
#pragma unroll
        for (int j = 0; j < 8; ++j) {
            int k = kk * 32 + q * 8 + j;
            o.u[j] = f2b(al[k] * b2f(t.s[j]) + be[k]);
        }
        afr[kk] = o.v;
    }
    f32x4 acc[4];
#pragma unroll
    for (int ct = 0; ct < 4; ++ct) {
        acc[ct] = (f32x4){0.f, 0.f, 0.f, 0.f};
#pragma unroll
        for (int kk = 0; kk < 4; ++kk) {
            s16x8 bfr = *(const s16x8*)&WT[(size_t)(ct * 16 + rr) * 128 + kk * 32 + q * 8];
            acc[ct] = __builtin_amdgcn_mfma_f32_16x16x32_bf16(afr[kk], bfr, acc[ct], 0, 0, 0);
        }
    }
#pragma unroll
    for (int ct = 0; ct < 4; ++ct) {
        int col = ct * 16 + rr;
        float bb = bias[col];
#pragma unroll
        for (int r = 0; r < 4; ++r) {
            long orr = r0 + q * 4 + r;
            float v = acc[ct][r] + bb + b2f(EHio[orr * 64 + col]);
            EHio[orr * 64 + col] = f2b(v);
        }
    }
}

// ---------------- CSR gather aggregate: per-node softmax + weighted sum (+col-stats) ----------------
template <int COLS, bool SOUT>
__global__ __launch_bounds__(256) void csr_aggregate_kernel(
    const int* __restrict__ rowptr, const int* __restrict__ esrc,
    const float* __restrict__ eatt, const u16* __restrict__ nodeh, float* __restrict__ hout,
    int n, float* __restrict__ raw) {
    constexpr int H = COLS / 64;
    constexpr int TPN = COLS / 2;
    constexpr int NPB = 256 / TPN;
    __shared__ float ssum[SOUT ? COLS : 1];
    __shared__ float ssq[SOUT ? COLS : 1];
    int tid = threadIdx.x;
    if (SOUT) {
        for (int i = tid; i < COLS; i += 256) { ssum[i] = 0.f; ssq[i] = 0.f; }
        __syncthreads();
    }
    int node = blockIdx.x * NPB + tid / TPN;
    bool act = node < n;
    int c = (tid % TPN) * 2;
    float a0 = 0.f, a1 = 0.f;
    if (act) {
        int h = (H == 2) ? (c >> 6) : 0;
        int p0 = rowptr[node], p1 = rowptr[node + 1];
        float m = -INFINITY, s = 0.f;
        for (int p = p0; p < p1; ++p) {
            float v = eatt[(long)p * H + h];
            float mn = fmaxf(m, v);
            s = s * expf(m - mn) + expf(v - mn);
            m = mn;
        }
        float inv = (s > 0.f) ? 1.f / s : 0.f;
        for (int p = p0; p < p1; ++p) {
            float w = expf(eatt[(long)p * H + h] - m) * inv;
            U16x2 v = *(const U16x2*)&nodeh[(long)esrc[p] * COLS + c];
            a0 += b2f(v.s[0]) * w;
            a1 += b2f(v.s[1]) * w;
        }
        *(float2*)&hout[(long)node * COLS + c] = make_float2(a0, a1);
    }
    if (SOUT) {
        if (act) {
            atomicAdd(&ssum[c], a0);
            atomicAdd(&ssum[c + 1], a1);
            atomicAdd(&ssq[c], a0 * a0);
            atomicAdd(&ssq[c + 1], a1 * a1);
        }
        __syncthreads();
        float* slot = raw + (size_t)(blockIdx.x & (NSLOT - 1)) * 256;
        for (int i = tid; i < COLS; i += 256) {
            atomicAdd(&slot[i], ssum[i]);
            atomicAdd(&slot[COLS + i], ssq[i]);
        }
    }
}

// ---------------- decoder tail: prelu(bn(t3)) @ Wout + bout -> pool by graph ----------------
__global__ __launch_bounds__(256) void decoder_out_kernel(
    const u16* __restrict__ t3, const float* __restrict__ stats, const float* __restrict__ g,
    const float* __restrict__ b, const float* __restrict__ prelu, const float* __restrict__ Wout,
    const float* __restrict__ bout, const int* __restrict__ gid, float* __restrict__ pool,
    int rows, float inv_rows) {
    int tid = threadIdx.x;
    long r = (long)blockIdx.x * 4 + (tid >> 6);
    if (r >= rows) return;
    int k = tid & 63;
    float mu = stats[k] * inv_rows;
    float var = stats[64 + k] * inv_rows - mu * mu;
    float al = g[k] * rsqrtf(fmaxf(var, 0.f) + EPS);
    float be = b[k] - mu * al;
    float a = prelu[3];
    float v = al * b2f(t3[r * 64 + k]) + be;
    v = (v >= 0.f) ? v : a * v;
    v *= Wout[k];
#pragma unroll
    for (int off = 1; off < 64; off <<= 1) v += __shfl_xor(v, off, 64);
    if (k == 0) atomicAdd(&pool[gid[r]], v + bout[0]);
}

// =====================================================================================
extern "C" void kernel_launch(void* const* d_in, const int* in_sizes, int n_in, void* d_out,
                              int out_size, void* d_ws, size_t ws_size, hipStream_t stream) {
    if (n_in < 57) return;
    const int* ntype = (const int*)d_in[0];
    const int* src = (const int*)d_in[1];
    const int* dst = (const int*)d_in[2];
    const int* gid = (const int*)d_in[3];
    const float* ang_rot = (const float*)d_in[4];
    const float* ang_ref = (const float*)d_in[5];
    const float* efeats = (const float*)d_in[6];
    const float* emb = (const float*)d_in[7];
    const float* enc_W = (const float*)d_in[8];
    const float* enc_b = (const float*)d_in[9];
    const float* ee_W1 = (const float*)d_in[10];
    const float* ee_b1 = (const float*)d_in[11];
    const float* ee_W2 = (const float*)d_in[12];
    const float* ee_b2 = (const float*)d_in[13];
    const float* enc_bn1_g = (const float*)d_in[14];
    const float* enc_bn1_b = (const float*)d_in[15];
    const float* enc_bn2_g = (const float*)d_in[16];
    const float* enc_bn2_b = (const float*)d_in[17];
    const float* ee_bn1_g = (const float*)d_in[18];
    const float* ee_bn1_b = (const float*)d_in[19];
    const float* ee_bn2_g = (const float*)d_in[20];
    const float* ee_bn2_b = (const float*)d_in[21];
    const float* l0_Wnode = (const float*)d_in[22];
    const float* l0_bnode = (const float*)d_in[23];
    const float* l0_Wni = (const float*)d_in[24];
    const float* l0_Wnj = (const float*)d_in[25];
    const float* l0_Wfij = (const float*)d_in[26];
    const float* l0_attn = (const float*)d_in[27];
    const float* l0_bnn_g = (const float*)d_in[28];
    const float* l0_bnn_b = (const float*)d_in[29];
    const float* l0_bne_g = (const float*)d_in[30];
    const float* l0_bne_b = (const float*)d_in[31];
    const float* l0_Wpn = (const float*)d_in[32];
    const float* l0_bpn = (const float*)d_in[33];
    const float* l0_Wpe = (const float*)d_in[34];
    const float* l0_bpe = (const float*)d_in[35];
    const float* l1_Wnode = (const float*)d_in[36];
    const float* l1_bnode = (const float*)d_in[37];
    const float* l1_Wni = (const float*)d_in[38];
    const float* l1_Wnj = (const float*)d_in[39];
    const float* l1_Wfij = (const float*)d_in[40];
    const float* l1_attn = (const float*)d_in[41];
    const float* l1_bnn_g = (const float*)d_in[42];
    const float* l1_bnn_b = (const float*)d_in[43];
    const float* l1_Wpn = (const float*)d_in[46];
    const float* l1_bpn = (const float*)d_in[47];
    const float* dec_W = (const float*)d_in[50];
    const float* dec_b = (const float*)d_in[51];
    const float* dec_bn_g = (const float*)d_in[52];
    const float* dec_bn_b = (const float*)d_in[53];
    const float* dec_prelu = (const float*)d_in[54];
    const float* dec_Wout = (const float*)d_in[55];
    const float* dec_bout = (const float*)d_in[56];

    float* out = (float*)d_out;
    float* H1 = out;                     // N x 64 (fp32)
    float* H2 = out + (long)NN * 64;     // N x 64 (fp32)
    float* POOL = out + (long)NN * 128;  // G x 1 (fp32)

    char* base = (char*)d_ws;
    size_t off = 0;
    auto alloc = [&](size_t bytes) -> void* {
        off = (off + 255) & ~(size_t)255;
        void* p = base + off;
        off += bytes;
        return p;
    };
    u16* EH = (u16*)alloc((size_t)NE * 64 * 2);
    u16* F128 = (u16*)alloc((size_t)NE * 128 * 2);
    float* EATT = (float*)alloc((size_t)NE * 2 * 4);
    u16* NX = (u16*)alloc((size_t)NN * 64 * 2);
    u16* NI = (u16*)alloc((size_t)NN * 128 * 2);
    u16* NJ = (u16*)alloc((size_t)NN * 128 * 2);
    u16* NHH = (u16*)alloc((size_t)NN * 128 * 2);
    float* HOUT0 = (float*)alloc((size_t)NN * 128 * 4);
    float* HOUT1 = (float*)alloc((size_t)NN * 64 * 4);
    int* ROWPTR = (int*)alloc((size_t)(NN + 1) * 4);
    int* CURS = (int*)alloc((size_t)NN * 4);
    int* EPOS = (int*)alloc((size_t)NE * 4);
    int* ESRC = (int*)alloc((size_t)NE * 4);
    int* BSUM = (int*)alloc((size_t)256 * 4);
    float* RWrot = (float*)alloc(256 * 4);
    float* RWref = (float*)alloc(256 * 4);
    // transposed bf16 weights
    u16* EncWT = (u16*)alloc(4096 * 2);
    u16* W2T = (u16*)alloc(4096 * 2);
    u16* Wni0T = (u16*)alloc(8192 * 2);
    u16* Wnj0T = (u16*)alloc(8192 * 2);
    u16* Wnd0T = (u16*)alloc(8192 * 2);
    u16* WfijT0 = (u16*)alloc(8192 * 2);
    u16* Wpn0T = (u16*)alloc(8192 * 2);
    u16* WpeT = (u16*)alloc(8192 * 2);
    u16* Wni1T = (u16*)alloc(4096 * 2);
    u16* Wnj1T = (u16*)alloc(4096 * 2);
    u16* Wnd1T = (u16*)alloc(4096 * 2);
    u16* WfijT1 = (u16*)alloc(4096 * 2);
    u16* Wpn1T = (u16*)alloc(4096 * 2);
    u16* DecT0 = (u16*)alloc(4096 * 2);
    u16* DecT1 = (u16*)alloc(4096 * 2);
    u16* DecT2 = (u16*)alloc(4096 * 2);
    u16* DecT3 = (u16*)alloc(4096 * 2);
    float* STATS = (float*)alloc((size_t)13 * 256 * 4);
    char* zstart = base + ((off + 255) & ~(size_t)255);
    int* DEG = (int*)alloc((size_t)NN * 4);
    float* STATS_RAW = (float*)alloc((size_t)13 * NSLOT * 256 * 4);
    float* RAWEF = (float*)alloc((size_t)NSLOT * 16 * 4);
    char* zend = base + off;
    if (ws_size < off) return;

    u16* T2a = F128;                    // NE x 64 bf16 (rot branch)
    u16* T2b = F128 + (size_t)NE * 64;  // NE x 64 bf16 (ref branch)
    u16* NX0 = F128;                    // NN x 64 bf16 (node-enc temp; done before edge-enc)
    u16* NT = F128 + (size_t)NE * 64;   // NN x 64 bf16 (node-enc temp)
    u16* DT0 = NI;
    u16* DT1 = NJ;

    auto RAW = [&](int idx) { return STATS_RAW + (size_t)idx * NSLOT * 256; };
    float* S_enc1 = STATS + 0 * 256;
    float* S_enc2 = STATS + 1 * 256;
    float* S_ee2r = STATS + 3 * 256;
    float* S_ee1r = STATS + 2 * 256;
    float* S_ee1f = STATS + 4 * 256;
    float* S_ee2f = STATS + 5 * 256;
    float* S_bnn0 = STATS + 6 * 256;
    float* S_bne0 = STATS + 7 * 256;
    float* S_bnn1 = STATS + 8 * 256;
    float* S_d0 = STATS + 9 * 256;
    float* S_d1 = STATS + 10 * 256;
    float* S_d2 = STATS + 11 * 256;
    float* S_d3 = STATS + 12 * 256;

    const float invN = 1.f / (float)NN;
    const float invE = 1.f / (float)NE;
    const int GS = 640;
    const int MFB = NE / 64;          // 6250 (exact)
    const int NNB = (NN + 63) / 64;   // 782 (tail waves skip)
    const int NB = (NN + 255) / 256;  // scan blocks

    hipMemsetAsync(zstart, 0, (size_t)(zend - zstart), stream);
    hipMemsetAsync(POOL, 0, (size_t)NG * 4, stream);

    setup_kernel<<<1, 64, 0, stream>>>(ang_rot, ang_ref, ee_W1, RWrot, RWref);
    {
        WtJobs j;
        const float* Ws[NWT] = {enc_W,  ee_W2,  l0_Wni, l0_Wnj, l0_Wnode, l0_Wfij,
                                l0_Wpn, l0_Wpe, l1_Wni, l1_Wnj, l1_Wnode, l1_Wfij,
                                l1_Wpn, dec_W,  dec_W + 4096, dec_W + 8192, dec_W + 12288};
        u16* Ts[NWT] = {EncWT, W2T, Wni0T, Wnj0T, Wnd0T, WfijT0, Wpn0T, WpeT, Wni1T,
                        Wnj1T, Wnd1T, WfijT1, Wpn1T, DecT0, DecT1, DecT2, DecT3};
        int Ks[NWT] = {64, 64, 64, 64, 64, 64, 128, 128, 64, 64, 64, 64, 64, 64, 64, 64, 64};
        int Cs[NWT] = {64, 64, 128, 128, 128, 128, 64, 64, 64, 64, 64, 64, 64, 64, 64, 64, 64};
        for (int i = 0; i < NWT; ++i) { j.W[i] = Ws[i]; j.WT[i] = Ts[i]; j.K[i] = Ks[i]; j.C[i] = Cs[i]; }
        wt_all_kernel<<<NWT * 32, 256, 0, stream>>>(j);
    }

    // ---- CSR build ----
    hist_kernel<<<(NE + 255) / 256, 256, 0, stream>>>(dst, NE, DEG);
    scan_part_kernel<<<NB, 256, 0, stream>>>(DEG, BSUM, NN);
    scan_top_kernel<<<1, 256, 0, stream>>>(BSUM, NB, ROWPTR, NN, NE);
    scan_fill_kernel<<<NB, 256, 0, stream>>>(DEG, BSUM, ROWPTR, CURS, NN);
    fill_kernel<<<(NE + 255) / 256, 256, 0, stream>>>(src, dst, NE, CURS, EPOS, ESRC);

    // ---- node encoder ----
    gather_emb_kernel<<<(NN * 8 + 255) / 256, 256, 0, stream>>>(ntype, emb, NX0, NN);
    colstats_kernel<64><<<GS, 256, 0, stream>>>(NX0, NN, RAW(0));
    finalize_stats_kernel<<<1, 256, 0, stream>>>(RAW(0), S_enc1, 128);
    mfma_mm_kernel<64, 64, true, false, true, true><<<NNB, 256, 0, stream>>>(
        NX0, EncWT, enc_b, nullptr, NT, NN, 2, S_enc1, enc_bn1_g, enc_bn1_b, invN, nullptr, 0,
        RAW(1));
    finalize_stats_kernel<<<1, 256, 0, stream>>>(RAW(1), S_enc2, 128);
    bn_act_kernel<<<(NN * 8 + 255) / 256, 256, 0, stream>>>(NT, NX, NN, 64, S_enc2, enc_bn2_g,
                                                            enc_bn2_b, invN);

    // ---- edge encoder: analytic T1 stats + MFMA both branches + single merge ----
    efstats_kernel<<<256, 256, 0, stream>>>(efeats, NE, RAWEF);
    ee_stats_kernel<<<1, 128, 0, stream>>>(RAWEF, RWrot, RWref, ee_b1, S_ee1r, S_ee1f, NE);
    mfma_ee_kernel<<<MFB, 256, 0, stream>>>(efeats, RWrot, ee_b1, W2T, ee_b2, T2a, NE, S_ee1r,
                                            ee_bn1_g, ee_bn1_b, invE, RAW(3));
    mfma_ee_kernel<<<MFB, 256, 0, stream>>>(efeats, RWref, ee_b1, W2T, ee_b2, T2b, NE, S_ee1f,
                                            ee_bn1_g, ee_bn1_b, invE, RAW(5));
    finalize_stats_kernel<<<1, 256, 0, stream>>>(RAW(3), S_ee2r, 128);
    finalize_stats_kernel<<<1, 256, 0, stream>>>(RAW(5), S_ee2f, 128);
    ee_merge_kernel<<<(int)(((long)NE * 8 + 255) / 256), 256, 0, stream>>>(
        T2a, T2b, EH, S_ee2r, S_ee2f, ee_bn2_g, ee_bn2_b, invE);

    // ---- layer 0 (H=2) ----
    mfma_mm3_kernel<128, true><<<NNB, 256, 0, stream>>>(NX, Wni0T, Wnj0T, Wnd0T, l0_bnode, NI,
                                                        NJ, NHH, NN);
    mfma_egat_kernel<128, true, true><<<MFB, 256, 0, stream>>>(
        EH, WfijT0, NI, NJ, src, dst, EPOS, l0_attn, F128, EATT, NE, RAW(7));
    finalize_stats_kernel<<<1, 256, 0, stream>>>(RAW(7), S_bne0, 256);
    csr_aggregate_kernel<128, true><<<(NN + 3) / 4, 256, 0, stream>>>(ROWPTR, ESRC, EATT, NHH,
                                                                      HOUT0, NN, RAW(6));
    finalize_stats_kernel<<<1, 256, 0, stream>>>(RAW(6), S_bnn0, 256);
    mfma_mm_kernel<128, 64, false, true, false, false><<<NNB, 256, 0, stream>>>(
        HOUT0, Wpn0T, l0_bpn, NX, H1, NN, 1, S_bnn0, l0_bnn_g, l0_bnn_b, invN, nullptr, 0,
        nullptr);
    mfma_pe_kernel<<<MFB, 256, 0, stream>>>(F128, WpeT, l0_bpe, EH, NE, S_bne0, l0_bne_g,
                                            l0_bne_b, invE);

    // ---- layer 1 (H=1; edge output dead -> skipped) ----
    mfma_mm3_kernel<64, false><<<NNB, 256, 0, stream>>>(H1, Wni1T, Wnj1T, Wnd1T, l1_bnode, NI,
                                                        NJ, NHH, NN);
    mfma_egat_kernel<64, false, false><<<MFB, 256, 0, stream>>>(
        EH, WfijT1, NI, NJ, src, dst, EPOS, l1_attn, nullptr, EATT, NE, nullptr);
    csr_aggregate_kernel<64, true><<<(NN + 7) / 8, 256, 0, stream>>>(ROWPTR, ESRC, EATT, NHH,
                                                                     HOUT1, NN, RAW(8));
    finalize_stats_kernel<<<1, 256, 0, stream>>>(RAW(8), S_bnn1, 128);
    mfma_mm_kernel<64, 64, false, false, false, false><<<NNB, 256, 0, stream>>>(
        HOUT1, Wpn1T, l1_bpn, H1, H2, NN, 1, S_bnn1, l1_bnn_g, l1_bnn_b, invN, nullptr, 0,
        nullptr);

    // ---- decoder ----
    mfma_mm_kernel<64, 64, false, false, true, true><<<NNB, 256, 0, stream>>>(
        H2, DecT0, dec_b, nullptr, DT0, NN, 0, nullptr, nullptr, nullptr, 0.f, nullptr, 0,
        RAW(9));
    finalize_stats_kernel<<<1, 256, 0, stream>>>(RAW(9), S_d0, 128);
    mfma_mm_kernel<64, 64, true, false, true, true><<<NNB, 256, 0, stream>>>(
        DT0, DecT1, dec_b + 64, nullptr, DT1, NN, 3, S_d0, dec_bn_g, dec_bn_b, invN, dec_prelu,
        0, RAW(10));
    finalize_stats_kernel<<<1, 256, 0, stream>>>(RAW(10), S_d1, 128);
    mfma_mm_kernel<64, 64, true, false, true, true><<<NNB, 256, 0, stream>>>(
        DT1, DecT2, dec_b + 128, nullptr, DT0, NN, 3, S_d1, dec_bn_g + 64, dec_bn_b + 64, invN,
        dec_prelu, 1, RAW(11));
    finalize_stats_kernel<<<1, 256, 0, stream>>>(RAW(11), S_d2, 128);
    mfma_mm_kernel<64, 64, true, false, true, true><<<NNB, 256, 0, stream>>>(
        DT0, DecT3, dec_b + 192, nullptr, DT1, NN, 3, S_d2, dec_bn_g + 128, dec_bn_b + 128,
        invN, dec_prelu, 2, RAW(12));
    finalize_stats_kernel<<<1, 256, 0, stream>>>(RAW(12), S_d3, 128);
    decoder_out_kernel<<<(NN + 3) / 4, 256, 0, stream>>>(DT1, S_d3, dec_bn_g + 192,
                                                         dec_bn_b + 192, dec_prelu, dec_Wout,
                                                         dec_bout, gid, POOL, NN, invN);
}